// Round 5
// baseline (338.373 us; speedup 1.0000x reference)
//
#include <hip/hip_runtime.h>
#include <hip/hip_bf16.h>

// Problem constants (B=2, S=2048, D=2048, NH=32, NKV=8, HD=64, NREP=4)
#define S_LEN 2048
#define DMODEL 2048
#define N_H 32
#define N_KV 8
#define H_D 64
#define ROWS 4096   // B*S
#define QKV_LD 3072 // fused qkv row stride: q[0:2048) k[2048:2560) v[2560:3072)

typedef __bf16 bf16x8 __attribute__((ext_vector_type(8)));
typedef float f32x4 __attribute__((ext_vector_type(4)));

// fp32 -> bf16 raw bits, round-to-nearest-even
static __device__ __forceinline__ unsigned short f2bf(float f) {
  unsigned int u = __float_as_uint(f);
  u += 0x7FFFu + ((u >> 16) & 1u);
  return (unsigned short)(u >> 16);
}
static __device__ __forceinline__ float bf2f(unsigned short s) {
  return __uint_as_float((unsigned int)s << 16);
}

// async global->LDS, 16 B per lane. LDS dest = wave-uniform base + lane*16.
static __device__ __forceinline__ void async16(const void* g, void* l) {
  __builtin_amdgcn_global_load_lds(
      (const __attribute__((address_space(1))) unsigned int*)g,
      (__attribute__((address_space(3))) unsigned int*)l, 16, 0, 0);
}

// ---------------------------------------------------------------------------
// fp32 -> bf16 bulk convert (8 elems/thread) — fallback path only
// ---------------------------------------------------------------------------
__global__ __launch_bounds__(256) void cvt_bf16_k(
    const float* __restrict__ in, unsigned short* __restrict__ out) {
  const size_t i = ((size_t)blockIdx.x * 256 + threadIdx.x) * 8;
  const float4 a = *(const float4*)&in[i];
  const float4 b = *(const float4*)&in[i + 4];
  union { unsigned short u[8]; uint4 v; } p;
  p.u[0] = f2bf(a.x); p.u[1] = f2bf(a.y); p.u[2] = f2bf(a.z); p.u[3] = f2bf(a.w);
  p.u[4] = f2bf(b.x); p.u[5] = f2bf(b.y); p.u[6] = f2bf(b.z); p.u[7] = f2bf(b.w);
  *(uint4*)&out[i] = p.v;
}

// ---------------------------------------------------------------------------
// Combined prep: z=0..3 transpose fp32 weights -> bf16 wqkvT/woT blocks;
// z=4: straight cvt x fp32 -> xb bf16 (64x64 blocks x 256 thr x 8 elems).
// ---------------------------------------------------------------------------
__global__ __launch_bounds__(256) void prep_all_k(
    const float* __restrict__ x, const float* __restrict__ wq,
    const float* __restrict__ wk, const float* __restrict__ wv,
    const float* __restrict__ wo, unsigned short* __restrict__ xb,
    unsigned short* __restrict__ wqkvT, unsigned short* __restrict__ woT) {
  const int z = blockIdx.z;
  if (z == 4) {
    const size_t i =
        (((size_t)blockIdx.y * 64 + blockIdx.x) * 256 + threadIdx.x) * 8;
    const float4 a = *(const float4*)&x[i];
    const float4 b = *(const float4*)&x[i + 4];
    union { unsigned short u[8]; uint4 v; } p;
    p.u[0] = f2bf(a.x); p.u[1] = f2bf(a.y); p.u[2] = f2bf(a.z); p.u[3] = f2bf(a.w);
    p.u[4] = f2bf(b.x); p.u[5] = f2bf(b.y); p.u[6] = f2bf(b.z); p.u[7] = f2bf(b.w);
    *(uint4*)&xb[i] = p.v;
    return;
  }
  const float* in;
  unsigned short* out;
  int C;
  if (z == 0)      { in = wq; out = wqkvT;                  C = 2048; }
  else if (z == 1) { in = wk; out = wqkvT + 2048ull * 2048; C = 512;  }
  else if (z == 2) { in = wv; out = wqkvT + 2560ull * 2048; C = 512;  }
  else             { in = wo; out = woT;                    C = 2048; }
  if (blockIdx.x * 32 >= C) return;

  __shared__ unsigned short tile[32][33];
  const int tx = threadIdx.x & 31;
  const int ty = threadIdx.x >> 5;
  const int r0 = blockIdx.y * 32;  // K rows of input
  const int c0 = blockIdx.x * 32;  // C cols of input
#pragma unroll
  for (int i = 0; i < 32; i += 8)
    tile[ty + i][tx] = f2bf(in[(size_t)(r0 + ty + i) * C + c0 + tx]);
  __syncthreads();
#pragma unroll
  for (int i = 0; i < 32; i += 8)
    out[(size_t)(c0 + ty + i) * 2048 + r0 + tx] = tile[tx][ty + i];
}

// log2(e) / sqrt(HD): softmax base-2 conversion + 1/sqrt(d), folded into q
#define SCALE_LOG2E 0.18033688011112042f

// ---------------------------------------------------------------------------
// Fused RoPE (blocks 0..20479) + v->vT transpose (blocks 20480..22527).
// rope: in-place on qkv views; q is additionally PRE-SCALED by SCALE_LOG2E
// so attention's QK^T comes out directly in base-2 exponent units.
// vT: qkv cols 2560..3071 ([4096][512] view, ld QKV_LD) -> vT [512][4096].
// ---------------------------------------------------------------------------
__global__ __launch_bounds__(256) void rope_vt_k(
    unsigned short* __restrict__ qkv, unsigned short* __restrict__ vT,
    const float* __restrict__ fc, const float* __restrict__ fs) {
  const int blk = blockIdx.x;
  if (blk < 20480) {
    const int PQ = ROWS * N_H * (H_D / 2);   // 4194304
    const int PK = ROWS * N_KV * (H_D / 2);  // 1048576
    const int idx = blk * 256 + threadIdx.x;
    if (idx >= PQ + PK) return;
    unsigned short* base;
    float c, sn;
    bool isq;
    if (idx < PQ) {
      const int i = idx & 31;
      const int h = (idx >> 5) & 31;
      const int row = idx >> 10;
      const int s = row & (S_LEN - 1);
      c = fc[s * 32 + i];
      sn = fs[s * 32 + i];
      base = qkv + (size_t)row * QKV_LD + h * H_D + 2 * i;
      isq = true;
    } else {
      const int p = idx - PQ;
      const int i = p & 31;
      const int h = (p >> 5) & 7;
      const int row = p >> 8;
      const int s = row & (S_LEN - 1);
      c = fc[s * 32 + i];
      sn = fs[s * 32 + i];
      base = qkv + (size_t)row * QKV_LD + 2048 + h * H_D + 2 * i;
      isq = false;
    }
    const float x0 = bf2f(base[0]);
    const float x1 = bf2f(base[1]);
    const float sc = isq ? SCALE_LOG2E : 1.0f;
    base[0] = f2bf((x0 * c - x1 * sn) * sc);
    base[1] = f2bf((x0 * sn + x1 * c) * sc);
  } else {
    __shared__ unsigned short tile[32][33];
    const int t = blk - 20480;        // 0..2047
    const int bx = t & 15;            // C/32 = 16
    const int by = t >> 4;            // R/32 = 128
    const unsigned short* in = qkv + 2560;
    const int tx = threadIdx.x & 31;
    const int ty = threadIdx.x >> 5;
    const int r0 = by * 32;
    const int c0 = bx * 32;
#pragma unroll
    for (int i = 0; i < 32; i += 8)
      tile[ty + i][tx] = in[(size_t)(r0 + ty + i) * QKV_LD + c0 + tx];
    __syncthreads();
#pragma unroll
    for (int i = 0; i < 32; i += 8)
      vT[(size_t)(c0 + ty + i) * ROWS + r0 + tx] = tile[tx][ty + i];
  }
}

// ---------------------------------------------------------------------------
// m97-style MFMA GEMM: C[M][N] = A[M][K] @ BT[N][K]^T, both bf16,
// global_load_lds(16B) staging, unpadded LDS (lane-ordered), 128x128 tile.
// A row stride = lda (supports strided views of the fused qkv buffer).
// XCD-aware bijective chunked block swizzle (T1): requires nwg % 8 == 0
// (QKV: 768, WO: 512 — both divisible). Each XCD gets a contiguous chunk of
// x-major flat ids -> consecutive blocks on one XCD share the same B panel
// (L2-resident) instead of re-fetching it on all 8 XCD L2s.
// ---------------------------------------------------------------------------
template <int STORE_BF16>
__global__ __launch_bounds__(256) void gemm_bt_k(
    const unsigned short* __restrict__ A, const unsigned short* __restrict__ BT,
    void* __restrict__ Cp, int M, int N, int K, int lda) {
  __shared__ __align__(16) unsigned short As[128 * 32];
  __shared__ __align__(16) unsigned short Bs[128 * 32];
  const int tid = threadIdx.x;
  const int wave = tid >> 6;
  const int lane = tid & 63;
  const int quad = lane >> 4;
  const int l16 = lane & 15;
  // XCD swizzle: flat hardware id -> chunked work id (bijective, nwg%8==0)
  const int nwg = gridDim.x * gridDim.y;
  const int flat = blockIdx.y * gridDim.x + blockIdx.x;
  const int swz = (flat & 7) * (nwg >> 3) + (flat >> 3);
  const int m0 = (swz % gridDim.x) * 128;
  const int n0 = (swz / gridDim.x) * 128;
  const int wm = (wave >> 1) * 64;
  const int wn = (wave & 1) * 64;
  const int rsub = lane >> 2;       // 0..15
  const int coff = (lane & 3) * 8;  // elem offset of 16B chunk
  f32x4 acc[4][4] = {};

  for (int kt = 0; kt < K; kt += 32) {
    __syncthreads();
#pragma unroll
    for (int t = 0; t < 2; t++) {
      const int row = wave * 32 + t * 16 + rsub;
      async16(&A[(size_t)(m0 + row) * lda + kt + coff],
              &As[(wave * 32 + t * 16) * 32]);
      async16(&BT[(size_t)(n0 + row) * K + kt + coff],
              &Bs[(wave * 32 + t * 16) * 32]);
    }
    __syncthreads();
    bf16x8 af[4], bfr[4];
#pragma unroll
    for (int i = 0; i < 4; i++)
      af[i] = *(const bf16x8*)&As[(wm + i * 16 + l16) * 32 + quad * 8];
#pragma unroll
    for (int j = 0; j < 4; j++)
      bfr[j] = *(const bf16x8*)&Bs[(wn + j * 16 + l16) * 32 + quad * 8];
#pragma unroll
    for (int i = 0; i < 4; i++)
#pragma unroll
      for (int j = 0; j < 4; j++)
        acc[i][j] =
            __builtin_amdgcn_mfma_f32_16x16x32_bf16(af[i], bfr[j], acc[i][j], 0, 0, 0);
  }

  // Epilogue: C/D layout col = lane&15, row = quad*4 + reg  [m89/m91 verified]
#pragma unroll
  for (int i = 0; i < 4; i++) {
#pragma unroll
    for (int e = 0; e < 4; e++) {
      const int mrow = m0 + wm + i * 16 + quad * 4 + e;
#pragma unroll
      for (int j = 0; j < 4; j++) {
        const int ncol = n0 + wn + j * 16 + l16;
        const float val = acc[i][j][e];
        if (STORE_BF16) {
          ((unsigned short*)Cp)[(size_t)mrow * N + ncol] = f2bf(val);
        } else {
          ((float*)Cp)[(size_t)mrow * N + ncol] = val;
        }
      }
    }
  }
}

// ---------------------------------------------------------------------------
// Fallback MFMA GEMM (round-4): C[M][N] = A[M][K] @ B[K][N], B fp32 native.
// ---------------------------------------------------------------------------
template <int AF32, int STORE_BF16>
__global__ __launch_bounds__(256) void gemm_k(
    const void* __restrict__ Ap, const float* __restrict__ B,
    void* __restrict__ Cp, int M, int N, int K) {
  constexpr int LDP = 40;
  __shared__ __align__(16) unsigned short As[128 * LDP];
  __shared__ __align__(16) unsigned short Bs[128 * LDP];
  const int tid = threadIdx.x;
  const int wave = tid >> 6;
  const int lane = tid & 63;
  const int quad = lane >> 4;
  const int l16 = lane & 15;
  const int m0 = blockIdx.x * 128;
  const int n0 = blockIdx.y * 128;
  const int wm = (wave >> 1) * 64;
  const int wn = (wave & 1) * 64;
  f32x4 acc[4][4] = {};

  for (int kt = 0; kt < K; kt += 32) {
    __syncthreads();
    if (AF32) {
      const float* A = (const float*)Ap;
      for (int c = tid; c < 1024; c += 256) {
        const int r = c >> 3;
        const int cc = (c & 7) << 2;
        const float4 w = *(const float4*)&A[(size_t)(m0 + r) * K + kt + cc];
        union { unsigned short u[4]; uint2 v; } p;
        p.u[0] = f2bf(w.x); p.u[1] = f2bf(w.y);
        p.u[2] = f2bf(w.z); p.u[3] = f2bf(w.w);
        *(uint2*)&As[r * LDP + cc] = p.v;
      }
    } else {
      const unsigned short* A = (const unsigned short*)Ap;
      for (int c = tid; c < 512; c += 256) {
        const int r = c >> 2;
        const int cc = (c & 3) << 3;
        *(uint4*)&As[r * LDP + cc] =
            *(const uint4*)&A[(size_t)(m0 + r) * K + kt + cc];
      }
    }
    for (int c = tid; c < 1024; c += 256) {
      const int kr = c >> 5;
      const int nc = (c & 31) << 2;
      const float4 w = *(const float4*)&B[(size_t)(kt + kr) * N + n0 + nc];
      Bs[(nc + 0) * LDP + kr] = f2bf(w.x);
      Bs[(nc + 1) * LDP + kr] = f2bf(w.y);
      Bs[(nc + 2) * LDP + kr] = f2bf(w.z);
      Bs[(nc + 3) * LDP + kr] = f2bf(w.w);
    }
    __syncthreads();
    bf16x8 af[4], bfr[4];
#pragma unroll
    for (int i = 0; i < 4; i++)
      af[i] = *(const bf16x8*)&As[(wm + i * 16 + l16) * LDP + quad * 8];
#pragma unroll
    for (int j = 0; j < 4; j++)
      bfr[j] = *(const bf16x8*)&Bs[(wn + j * 16 + l16) * LDP + quad * 8];
#pragma unroll
    for (int i = 0; i < 4; i++)
#pragma unroll
      for (int j = 0; j < 4; j++)
        acc[i][j] =
            __builtin_amdgcn_mfma_f32_16x16x32_bf16(af[i], bfr[j], acc[i][j], 0, 0, 0);
  }
#pragma unroll
  for (int i = 0; i < 4; i++) {
#pragma unroll
    for (int e = 0; e < 4; e++) {
      const int mrow = m0 + wm + i * 16 + quad * 4 + e;
#pragma unroll
      for (int j = 0; j < 4; j++) {
        const int ncol = n0 + wn + j * 16 + l16;
        const float val = acc[i][j][e];
        if (STORE_BF16) {
          ((unsigned short*)Cp)[(size_t)mrow * N + ncol] = f2bf(val);
        } else {
          ((float*)Cp)[(size_t)mrow * N + ncol] = val;
        }
      }
    }
  }
}

// ---------------------------------------------------------------------------
// Fallback RoPE (separate q/k buffers)
// ---------------------------------------------------------------------------
__global__ __launch_bounds__(256) void rope_k(
    unsigned short* __restrict__ q, unsigned short* __restrict__ kk,
    const float* __restrict__ fc, const float* __restrict__ fs,
    int qstride, int kstride) {
  const int PQ = ROWS * N_H * (H_D / 2);
  const int PK = ROWS * N_KV * (H_D / 2);
  const int idx = blockIdx.x * 256 + threadIdx.x;
  if (idx >= PQ + PK) return;
  unsigned short* base;
  float c, sn;
  if (idx < PQ) {
    const int i = idx & 31;
    const int h = (idx >> 5) & 31;
    const int row = idx >> 10;
    const int s = row & (S_LEN - 1);
    c = fc[s * 32 + i];
    sn = fs[s * 32 + i];
    base = q + (size_t)row * qstride + h * H_D + 2 * i;
  } else {
    const int p = idx - PQ;
    const int i = p & 31;
    const int h = (p >> 5) & 7;
    const int row = p >> 8;
    const int s = row & (S_LEN - 1);
    c = fc[s * 32 + i];
    sn = fs[s * 32 + i];
    base = kk + (size_t)row * kstride + h * H_D + 2 * i;
  }
  const float x0 = bf2f(base[0]);
  const float x1 = bf2f(base[1]);
  base[0] = f2bf(x0 * c - x1 * sn);
  base[1] = f2bf(x0 * sn + x1 * c);
}

// ---------------------------------------------------------------------------
// attn v11: split-k wave groups (v10 structure, VERIFIED CORRECT in round 4)
// with the spill fixed: __launch_bounds__(512, 2). Round-4 evidence showed
// (512,4) acts as a 4-block/CU occupancy target on this compiler -> 64-VGPR
// cap -> scratch spills (WRITE_SIZE 16->54 MB, both pipes idle). (512,2)
// caps at 128 VGPR (need ~95); LDS (64 KB) still gives 2 blocks/CU and
// grid=512 fills it: 16 waves/CU with 32 q-rows/wave — v8's residency plus
// v9's per-q LDS-read amortization.
//   waves 0-3 = even k-tiles, waves 4-7 = odd k-tiles, same 128 q-rows.
//   Non-online softmax => group partials (o,l) merge with one LDS exchange.
//   Per-wave body (swapped-operand S^T QK, XOR swizzle, packed b64 P stores,
//   ones-MFMA l-sum, masking) verbatim from verified v9/v10.
//   paired {p, 15-p}: exactly 36 k-tiles per block, uniform work.
// ---------------------------------------------------------------------------
__global__ __launch_bounds__(512, 2) void attn_mfma11_k(
    const unsigned short* __restrict__ qkv, const unsigned short* __restrict__ vT,
    unsigned short* __restrict__ ao) {
  const int pair = blockIdx.x, h = blockIdx.y, b = blockIdx.z;
  const int hk = h >> 2;
  const int tid = threadIdx.x;
  const int wave = tid >> 6;      // 0..7
  const int g = wave >> 2;        // k-parity group
  const int w4 = wave & 3;        // wave-in-group = q-strip owner
  const int lane = tid & 63;
  const int l16 = tid & 15;
  const int quad = (tid & 63) >> 4;
  const int rr = tid >> 3;        // 0..63 staging row
  const int dc = (tid & 7) * 8;   // staging 16B chunk (elem units)
  const int rx = (l16 & 7) << 3;  // read/P-side XOR (elem units)
  const int sx = (rr & 7) << 3;   // stage-side XOR

  __shared__ __align__(16) unsigned short Ks[2][64 * 64];  // [key][d] swz
  __shared__ __align__(16) unsigned short Vt[2][64 * 64];  // [d][key] swz
  __shared__ __align__(16) unsigned short Ps[8][32 * 64];  // wave-private swz

  // group-local LDS bases (loop-invariant)
  const unsigned short* Kb = &Ks[g][0];
  const unsigned short* Vb = &Vt[g][0];

  // reduction-exchange aliases (used only after the final tile barrier)
  f32x4* Ored = (f32x4*)&Ps[0][0];  // 4 waves x 8 frag x 64 lanes x 16B = 32KB
  f32x4* Lred = (f32x4*)&Ks[0][0];  // 4 waves x 2 strip x 64 lanes x 16B = 8KB

  bf16x8 ones;
#pragma unroll
  for (int j = 0; j < 8; j++) ones[j] = (__bf16)1.0f;

  const size_t kbase =
      (size_t)(b * S_LEN) * QKV_LD + 2048 + hk * H_D + dc;  // k cols
  const size_t vbase = (size_t)(hk * H_D + rr) * ROWS + b * S_LEN + dc;

  for (int sel = 0; sel < 2; ++sel) {
    const int qb = sel ? (15 - pair) : pair;  // q-block of 128 rows
    const int row0 = qb * 128;
    const int ktiles = 2 * qb + 2;  // always even; >= 2

    // Q fragments: two 16-row strips per wave; both groups load same rows.
    bf16x8 af[2][2];
#pragma unroll
    for (int r = 0; r < 2; r++) {
      const size_t qrow =
          (size_t)(b * S_LEN + row0 + w4 * 32 + r * 16 + l16);
#pragma unroll
      for (int c = 0; c < 2; c++)
        af[r][c] =
            *(const bf16x8*)&qkv[qrow * QKV_LD + h * H_D + c * 32 + quad * 8];
    }

    f32x4 o_acc[2][4] = {};
    f32x4 l_acc[2] = {};

    // Prologue: prefetch tiles 0,1 into regs; stage into buffers 0,1.
    uint4 rk0, rk1, rv0, rv1;
    rk0 = *(const uint4*)&qkv[kbase + (size_t)(0 * 64 + rr) * QKV_LD];
    rk1 = *(const uint4*)&qkv[kbase + (size_t)(1 * 64 + rr) * QKV_LD];
    rv0 = *(const uint4*)&vT[vbase + (size_t)0 * 64];
    rv1 = *(const uint4*)&vT[vbase + (size_t)1 * 64];
    __syncthreads();  // prior-sel epilogue reads of Ored/Lred/bufs complete
    *(uint4*)&Ks[0][rr * 64 + (dc ^ sx)] = rk0;
    *(uint4*)&Ks[1][rr * 64 + (dc ^ sx)] = rk1;
    *(uint4*)&Vt[0][rr * 64 + (dc ^ sx)] = rv0;
    *(uint4*)&Vt[1][rr * 64 + (dc ^ sx)] = rv1;

    for (int kt = 0; kt < ktiles; kt += 2) {
      // Prefetch the next tile pair while this pair computes.
      if (kt + 2 < ktiles) {
        rk0 = *(const uint4*)&qkv[kbase + (size_t)((kt + 2) * 64 + rr) * QKV_LD];
        rk1 = *(const uint4*)&qkv[kbase + (size_t)((kt + 3) * 64 + rr) * QKV_LD];
        rv0 = *(const uint4*)&vT[vbase + (size_t)(kt + 2) * 64];
        rv1 = *(const uint4*)&vT[vbase + (size_t)(kt + 3) * 64];
      }
      __syncthreads();  // buffers staged & visible

      const int kcur = kt + g;  // this group's tile

      // S^T strips: D[row=k(quad*4+e), col=q(l16)] = mfma(K-frag, Q-frag).
      f32x4 sacc[2][4];
#pragma unroll
      for (int n = 0; n < 4; n++) {
        f32x4 z0 = {}, z1 = {};
#pragma unroll
        for (int c = 0; c < 2; c++) {
          const bf16x8 bk = *(const bf16x8*)&Kb[(n * 16 + l16) * 64 +
                                               ((c * 32 + quad * 8) ^ rx)];
          z0 = __builtin_amdgcn_mfma_f32_16x16x32_bf16(bk, af[0][c], z0, 0, 0, 0);
          z1 = __builtin_amdgcn_mfma_f32_16x16x32_bf16(bk, af[1][c], z1, 0, 0, 0);
        }
        sacc[0][n] = z0;
        sacc[1][n] = z1;
      }

      // pe = exp2(s); truncate to bf16 (v_perm pack); masked -> 0.
      const bool maybe_mask = (kcur >= 2 * qb);
      const int krel0 = (kcur - 2 * qb) * 64;  // valid when maybe_mask
#pragma unroll
      for (int r = 0; r < 2; r++) {
        const int qn = w4 * 32 + r * 16 + l16;  // relative q row of this lane
        const int prow = (r * 16 + l16) * 64;
#pragma unroll
        for (int n = 0; n < 4; n++) {
          const int kb0 = krel0 + n * 16 + quad * 4;  // relative k of e=0
          float pe[4];
#pragma unroll
          for (int e = 0; e < 4; e++) {
            float v = exp2f(sacc[r][n][e]);
            if (maybe_mask && (kb0 + e > qn)) v = 0.f;
            pe[e] = v;
          }
          uint2 u;
          u.x = __builtin_amdgcn_perm(__float_as_uint(pe[1]),
                                      __float_as_uint(pe[0]), 0x07060302u);
          u.y = __builtin_amdgcn_perm(__float_as_uint(pe[3]),
                                      __float_as_uint(pe[2]), 0x07060302u);
          *(uint2*)&Ps[wave][prow + ((n * 16 + quad * 4) ^ rx)] = u;
        }
      }
      // wave-private Ps: compiler inserts lgkmcnt wait; no barrier needed

      bf16x8 pf[2][2];
#pragma unroll
      for (int r = 0; r < 2; r++)
#pragma unroll
        for (int c = 0; c < 2; c++)
          pf[r][c] = *(const bf16x8*)&Ps[wave][(r * 16 + l16) * 64 +
                                              ((c * 32 + quad * 8) ^ rx)];
      // l row-sums via MFMA against ones (replicated over cols).
#pragma unroll
      for (int c = 0; c < 2; c++) {
        l_acc[0] = __builtin_amdgcn_mfma_f32_16x16x32_bf16(pf[0][c], ones,
                                                           l_acc[0], 0, 0, 0);
        l_acc[1] = __builtin_amdgcn_mfma_f32_16x16x32_bf16(pf[1][c], ones,
                                                           l_acc[1], 0, 0, 0);
      }
#pragma unroll
      for (int n = 0; n < 4; n++)
#pragma unroll
        for (int c = 0; c < 2; c++) {
          const bf16x8 bv = *(const bf16x8*)&Vb[(n * 16 + l16) * 64 +
                                               ((c * 32 + quad * 8) ^ rx)];
          o_acc[0][n] = __builtin_amdgcn_mfma_f32_16x16x32_bf16(
              pf[0][c], bv, o_acc[0][n], 0, 0, 0);
          o_acc[1][n] = __builtin_amdgcn_mfma_f32_16x16x32_bf16(
              pf[1][c], bv, o_acc[1][n], 0, 0, 0);
        }

      __syncthreads();  // both groups done reading buffers
      if (kt + 2 < ktiles) {
        *(uint4*)&Ks[0][rr * 64 + (dc ^ sx)] = rk0;
        *(uint4*)&Ks[1][rr * 64 + (dc ^ sx)] = rk1;
        *(uint4*)&Vt[0][rr * 64 + (dc ^ sx)] = rv0;
        *(uint4*)&Vt[1][rr * 64 + (dc ^ sx)] = rv1;
      }
    }

    // Cross-group reduction: group 1 publishes partials into dead LDS
    // (all tile computes completed at the loop's final barrier).
    if (g == 1) {
#pragma unroll
      for (int r = 0; r < 2; r++) {
#pragma unroll
        for (int n = 0; n < 4; n++)
          Ored[(w4 * 8 + r * 4 + n) * 64 + lane] = o_acc[r][n];
        Lred[(w4 * 2 + r) * 64 + lane] = l_acc[r];
      }
    }
    __syncthreads();
    if (g == 0) {
#pragma unroll
      for (int r = 0; r < 2; r++) {
#pragma unroll
        for (int n = 0; n < 4; n++)
          o_acc[r][n] += Ored[(w4 * 8 + r * 4 + n) * 64 + lane];
        l_acc[r] += Lred[(w4 * 2 + r) * 64 + lane];
      }
      // Epilogue: normalize, store bf16 (in-place q cols).
#pragma unroll
      for (int r = 0; r < 2; r++)
#pragma unroll
        for (int e = 0; e < 4; e++) {
          const float inv = 1.f / l_acc[r][e];
          const size_t row =
              (size_t)(b * S_LEN + row0 + w4 * 32 + r * 16 + quad * 4 + e);
#pragma unroll
          for (int n = 0; n < 4; n++)
            ao[row * QKV_LD + h * H_D + n * 16 + l16] =
                f2bf(o_acc[r][n][e] * inv);
        }
    }
    // next sel's prologue barrier guards Ored/Lred/buffer reuse
  }
}

#define LK 72  // padded inner stride for fallback attention

// ---------------------------------------------------------------------------
// Round-4 attention (fallback path only): k/v separate buffers stride 512.
// ---------------------------------------------------------------------------
__global__ __launch_bounds__(256) void attn_mfma_k(
    const unsigned short* __restrict__ q, const unsigned short* __restrict__ k,
    const unsigned short* __restrict__ v, unsigned short* __restrict__ ao) {
  const int qt = blockIdx.x, h = blockIdx.y, b = blockIdx.z;
  const int hk = h >> 2;
  const int tid = threadIdx.x;
  const int wave = tid >> 6;
  const int l16 = tid & 15;
  const int quad = (tid & 63) >> 4;

  __shared__ __align__(16) unsigned short Ks[64 * LK];
  __shared__ __align__(16) unsigned short Vt[64 * LK];
  __shared__ __align__(16) unsigned short Ps[64 * LK];

  bf16x8 af[2];
  {
    const size_t qrow = (size_t)(b * S_LEN + qt * 64 + wave * 16 + l16);
#pragma unroll
    for (int c = 0; c < 2; c++)
      af[c] = *(const bf16x8*)&q[qrow * DMODEL + h * H_D + c * 32 + quad * 8];
  }

  f32x4 o_acc[4] = {};
  float m_i[4], l_i[4];
#pragma unroll
  for (int e = 0; e < 4; e++) { m_i[e] = -INFINITY; l_i[e] = 0.f; }

  for (int kt = 0; kt <= qt; ++kt) {
    const int kb = kt * 64;
    __syncthreads();
    {
      const int kr = tid >> 2;
      const int dc = (tid & 3) * 16;
      const size_t gro = (size_t)(b * S_LEN + kb + kr) * (N_KV * H_D) + hk * H_D + dc;
      *(uint4*)&Ks[kr * LK + dc] = *(const uint4*)&k[gro];
      *(uint4*)&Ks[kr * LK + dc + 8] = *(const uint4*)&k[gro + 8];
      union { unsigned short u[8]; uint4 v; } w0, w1;
      w0.v = *(const uint4*)&v[gro];
      w1.v = *(const uint4*)&v[gro + 8];
#pragma unroll
      for (int j = 0; j < 8; j++) Vt[(dc + j) * LK + kr] = w0.u[j];
#pragma unroll
      for (int j = 0; j < 8; j++) Vt[(dc + 8 + j) * LK + kr] = w1.u[j];
    }
    __syncthreads();

    f32x4 sacc[4];
#pragma unroll
    for (int n = 0; n < 4; n++) {
      f32x4 z = {};
#pragma unroll
      for (int c = 0; c < 2; c++) {
        const bf16x8 bk = *(const bf16x8*)&Ks[(n * 16 + l16) * LK + c * 32 + quad * 8];
        z = __builtin_amdgcn_mfma_f32_16x16x32_bf16(af[c], bk, z, 0, 0, 0);
      }
      sacc[n] = z;
    }

    float p[4][4], mnew[4];
#pragma unroll
    for (int e = 0; e < 4; e++) mnew[e] = m_i[e];
#pragma unroll
    for (int n = 0; n < 4; n++)
#pragma unroll
      for (int e = 0; e < 4; e++) {
        float s = sacc[n][e] * 0.125f;
        if (kt == qt && (n * 16 + l16) > (wave * 16 + quad * 4 + e))
          s = -INFINITY;
        p[n][e] = s;
        mnew[e] = fmaxf(mnew[e], s);
      }
#pragma unroll
    for (int e = 0; e < 4; e++) {
      mnew[e] = fmaxf(mnew[e], __shfl_xor(mnew[e], 1));
      mnew[e] = fmaxf(mnew[e], __shfl_xor(mnew[e], 2));
      mnew[e] = fmaxf(mnew[e], __shfl_xor(mnew[e], 4));
      mnew[e] = fmaxf(mnew[e], __shfl_xor(mnew[e], 8));
      const float alpha = __expf(m_i[e] - mnew[e]);
      m_i[e] = mnew[e];
      l_i[e] *= alpha;
#pragma unroll
      for (int n = 0; n < 4; n++) o_acc[n][e] *= alpha;
    }
#pragma unroll
    for (int n = 0; n < 4; n++)
#pragma unroll
      for (int e = 0; e < 4; e++) {
        const float pe = __expf(p[n][e] - m_i[e]);
        p[n][e] = pe;
        l_i[e] += pe;
      }

#pragma unroll
    for (int n = 0; n < 4; n++)
#pragma unroll
      for (int e = 0; e < 4; e++)
        Ps[(wave * 16 + quad * 4 + e) * LK + n * 16 + l16] = f2bf(p[n][e]);
    __syncthreads();

    bf16x8 pf[2];
#pragma unroll
    for (int c = 0; c < 2; c++)
      pf[c] = *(const bf16x8*)&Ps[(wave * 16 + l16) * LK + c * 32 + quad * 8];
#pragma unroll
    for (int n = 0; n < 4; n++)
#pragma unroll
      for (int c = 0; c < 2; c++) {
        const bf16x8 bv = *(const bf16x8*)&Vt[(n * 16 + l16) * LK + c * 32 + quad * 8];
        o_acc[n] = __builtin_amdgcn_mfma_f32_16x16x32_bf16(pf[c], bv, o_acc[n], 0, 0, 0);
      }
  }

#pragma unroll
  for (int e = 0; e < 4; e++) {
    l_i[e] += __shfl_xor(l_i[e], 1);
    l_i[e] += __shfl_xor(l_i[e], 2);
    l_i[e] += __shfl_xor(l_i[e], 4);
    l_i[e] += __shfl_xor(l_i[e], 8);
    const float inv = 1.f / l_i[e];
    const size_t row = (size_t)(b * S_LEN + qt * 64 + wave * 16 + quad * 4 + e);
#pragma unroll
    for (int n = 0; n < 4; n++)
      ao[row * DMODEL + h * H_D + n * 16 + l16] = f2bf(o_acc[n][e] * inv);
  }
}

// ---------------------------------------------------------------------------
extern "C" void kernel_launch(void* const* d_in, const int* in_sizes, int n_in,
                              void* d_out, int out_size, void* d_ws, size_t ws_size,
                              hipStream_t stream) {
  const float* x = (const float*)d_in[0];
  const float* fc = (const float*)d_in[1];
  const float* fs = (const float*)d_in[2];
  const float* wq = (const float*)d_in[3];
  const float* wk = (const float*)d_in[4];
  const float* wv = (const float*)d_in[5];
  const float* wo = (const float*)d_in[6];

  char* ws = (char*)d_ws;
  const dim3 b256(256);

  if (ws_size >= (64ull << 20)) {
    // Fast path (64 MB):
    //   qkv   bf16 [4096][3072] @ 0     (24 MB)  q|k|v fused; attn out in q cols
    //   xb    bf16 [4096][2048] @ 24 MB (16 MB)
    //   wqkvT bf16 [3072][2048] @ 40 MB (12 MB)
    //   woT   bf16 [2048][2048] @ 52 MB ( 8 MB)
    //   vT    bf16 [ 512][4096] @ 60 MB ( 4 MB)
    unsigned short* qkv = (unsigned short*)(ws);
    unsigned short* xb = (unsigned short*)(ws + (24ull << 20));
    unsigned short* wqkvT = (unsigned short*)(ws + (40ull << 20));
    unsigned short* woT = (unsigned short*)(ws + (52ull << 20));
    unsigned short* vT = (unsigned short*)(ws + (60ull << 20));

    prep_all_k<<<dim3(64, 64, 5), b256, 0, stream>>>(x, wq, wk, wv, wo, xb,
                                                     wqkvT, woT);

    // One fused QKV projection: [4096][2048] @ [3072][2048]^T -> [4096][3072]
    gemm_bt_k<1><<<dim3(32, 24), b256, 0, stream>>>(xb, wqkvT, qkv, 4096, 3072,
                                                    2048, 2048);

    // RoPE (q pre-scaled by log2e/8, k plain) + v -> vT transpose, fused
    rope_vt_k<<<dim3(20480 + 2048), b256, 0, stream>>>(qkv, vT, fc, fs);

    // Split-k wave-group attention (spill-fixed): 512 blocks x 512 thr.
    attn_mfma11_k<<<dim3(8, N_H, 2), dim3(512), 0, stream>>>(qkv, vT, qkv);

    // Output projection reads attn output (qkv q-cols, lda=3072) -> fp32 d_out
    gemm_bt_k<0><<<dim3(32, 16), b256, 0, stream>>>(qkv, woT, d_out, 4096, 2048,
                                                    2048, QKV_LD);
  } else {
    // Round-4 fallback (<= 40 MB)
    unsigned short* q = (unsigned short*)(ws);
    unsigned short* k = (unsigned short*)(ws + (16ull << 20));
    unsigned short* v = (unsigned short*)(ws + (20ull << 20));
    unsigned short* xb = (unsigned short*)(ws + (24ull << 20));
    const bool have_xb = ws_size >= (40ull << 20);

    if (have_xb) {
      cvt_bf16_k<<<dim3(ROWS * DMODEL / (256 * 8)), b256, 0, stream>>>(x, xb);
      gemm_k<0, 1><<<dim3(32, 16), b256, 0, stream>>>(xb, wq, q, 4096, 2048, 2048);
      gemm_k<0, 1><<<dim3(32, 4), b256, 0, stream>>>(xb, wk, k, 4096, 512, 2048);
      gemm_k<0, 1><<<dim3(32, 4), b256, 0, stream>>>(xb, wv, v, 4096, 512, 2048);
    } else {
      gemm_k<1, 1><<<dim3(32, 16), b256, 0, stream>>>(x, wq, q, 4096, 2048, 2048);
      gemm_k<1, 1><<<dim3(32, 4), b256, 0, stream>>>(x, wk, k, 4096, 512, 2048);
      gemm_k<1, 1><<<dim3(32, 4), b256, 0, stream>>>(x, wv, v, 4096, 512, 2048);
    }

    rope_k<<<dim3(20480), b256, 0, stream>>>(q, k, fc, fs, N_H * H_D, N_KV * H_D);
    attn_mfma_k<<<dim3(S_LEN / 64, N_H, 2), b256, 0, stream>>>(q, k, v, q);
    gemm_k<0, 0><<<dim3(32, 16), b256, 0, stream>>>(q, wo, d_out, 4096, 2048, 2048);
  }
}

// Round 6
// 325.105 us; speedup vs baseline: 1.0408x; 1.0408x over previous
//
#include <hip/hip_runtime.h>
#include <hip/hip_bf16.h>

// Problem constants (B=2, S=2048, D=2048, NH=32, NKV=8, HD=64, NREP=4)
#define S_LEN 2048
#define DMODEL 2048
#define N_H 32
#define N_KV 8
#define H_D 64
#define ROWS 4096   // B*S
#define QKV_LD 3072 // fused qkv row stride: q[0:2048) k[2048:2560) v[2560:3072)

typedef __bf16 bf16x8 __attribute__((ext_vector_type(8)));
typedef float f32x4 __attribute__((ext_vector_type(4)));

// fp32 -> bf16 raw bits, round-to-nearest-even
static __device__ __forceinline__ unsigned short f2bf(float f) {
  unsigned int u = __float_as_uint(f);
  u += 0x7FFFu + ((u >> 16) & 1u);
  return (unsigned short)(u >> 16);
}
static __device__ __forceinline__ float bf2f(unsigned short s) {
  return __uint_as_float((unsigned int)s << 16);
}

// async global->LDS, 16 B per lane. LDS dest = wave-uniform base + lane*16.
static __device__ __forceinline__ void async16(const void* g, void* l) {
  __builtin_amdgcn_global_load_lds(
      (const __attribute__((address_space(1))) unsigned int*)g,
      (__attribute__((address_space(3))) unsigned int*)l, 16, 0, 0);
}

// ---------------------------------------------------------------------------
// fp32 -> bf16 bulk convert (8 elems/thread) — fallback path only
// ---------------------------------------------------------------------------
__global__ __launch_bounds__(256) void cvt_bf16_k(
    const float* __restrict__ in, unsigned short* __restrict__ out) {
  const size_t i = ((size_t)blockIdx.x * 256 + threadIdx.x) * 8;
  const float4 a = *(const float4*)&in[i];
  const float4 b = *(const float4*)&in[i + 4];
  union { unsigned short u[8]; uint4 v; } p;
  p.u[0] = f2bf(a.x); p.u[1] = f2bf(a.y); p.u[2] = f2bf(a.z); p.u[3] = f2bf(a.w);
  p.u[4] = f2bf(b.x); p.u[5] = f2bf(b.y); p.u[6] = f2bf(b.z); p.u[7] = f2bf(b.w);
  *(uint4*)&out[i] = p.v;
}

// ---------------------------------------------------------------------------
// Combined prep: z=0..3 transpose fp32 weights -> bf16 wqkvT/woT blocks;
// z=4: straight cvt x fp32 -> xb bf16 (64x64 blocks x 256 thr x 8 elems).
// ---------------------------------------------------------------------------
__global__ __launch_bounds__(256) void prep_all_k(
    const float* __restrict__ x, const float* __restrict__ wq,
    const float* __restrict__ wk, const float* __restrict__ wv,
    const float* __restrict__ wo, unsigned short* __restrict__ xb,
    unsigned short* __restrict__ wqkvT, unsigned short* __restrict__ woT) {
  const int z = blockIdx.z;
  if (z == 4) {
    const size_t i =
        (((size_t)blockIdx.y * 64 + blockIdx.x) * 256 + threadIdx.x) * 8;
    const float4 a = *(const float4*)&x[i];
    const float4 b = *(const float4*)&x[i + 4];
    union { unsigned short u[8]; uint4 v; } p;
    p.u[0] = f2bf(a.x); p.u[1] = f2bf(a.y); p.u[2] = f2bf(a.z); p.u[3] = f2bf(a.w);
    p.u[4] = f2bf(b.x); p.u[5] = f2bf(b.y); p.u[6] = f2bf(b.z); p.u[7] = f2bf(b.w);
    *(uint4*)&xb[i] = p.v;
    return;
  }
  const float* in;
  unsigned short* out;
  int C;
  if (z == 0)      { in = wq; out = wqkvT;                  C = 2048; }
  else if (z == 1) { in = wk; out = wqkvT + 2048ull * 2048; C = 512;  }
  else if (z == 2) { in = wv; out = wqkvT + 2560ull * 2048; C = 512;  }
  else             { in = wo; out = woT;                    C = 2048; }
  if (blockIdx.x * 32 >= C) return;

  __shared__ unsigned short tile[32][33];
  const int tx = threadIdx.x & 31;
  const int ty = threadIdx.x >> 5;
  const int r0 = blockIdx.y * 32;  // K rows of input
  const int c0 = blockIdx.x * 32;  // C cols of input
#pragma unroll
  for (int i = 0; i < 32; i += 8)
    tile[ty + i][tx] = f2bf(in[(size_t)(r0 + ty + i) * C + c0 + tx]);
  __syncthreads();
#pragma unroll
  for (int i = 0; i < 32; i += 8)
    out[(size_t)(c0 + ty + i) * 2048 + r0 + tx] = tile[tx][ty + i];
}

// log2(e) / sqrt(HD): softmax base-2 conversion + 1/sqrt(d), folded into q
#define SCALE_LOG2E 0.18033688011112042f

// ---------------------------------------------------------------------------
// Fused RoPE (blocks 0..20479) + v->vT transpose (blocks 20480..22527).
// rope: in-place on qkv views; q is additionally PRE-SCALED by SCALE_LOG2E
// so attention's QK^T comes out directly in base-2 exponent units.
// vT: qkv cols 2560..3071 ([4096][512] view, ld QKV_LD) -> vT [512][4096].
// ---------------------------------------------------------------------------
__global__ __launch_bounds__(256) void rope_vt_k(
    unsigned short* __restrict__ qkv, unsigned short* __restrict__ vT,
    const float* __restrict__ fc, const float* __restrict__ fs) {
  const int blk = blockIdx.x;
  if (blk < 20480) {
    const int PQ = ROWS * N_H * (H_D / 2);   // 4194304
    const int PK = ROWS * N_KV * (H_D / 2);  // 1048576
    const int idx = blk * 256 + threadIdx.x;
    if (idx >= PQ + PK) return;
    unsigned short* base;
    float c, sn;
    bool isq;
    if (idx < PQ) {
      const int i = idx & 31;
      const int h = (idx >> 5) & 31;
      const int row = idx >> 10;
      const int s = row & (S_LEN - 1);
      c = fc[s * 32 + i];
      sn = fs[s * 32 + i];
      base = qkv + (size_t)row * QKV_LD + h * H_D + 2 * i;
      isq = true;
    } else {
      const int p = idx - PQ;
      const int i = p & 31;
      const int h = (p >> 5) & 7;
      const int row = p >> 8;
      const int s = row & (S_LEN - 1);
      c = fc[s * 32 + i];
      sn = fs[s * 32 + i];
      base = qkv + (size_t)row * QKV_LD + 2048 + h * H_D + 2 * i;
      isq = false;
    }
    const float x0 = bf2f(base[0]);
    const float x1 = bf2f(base[1]);
    const float sc = isq ? SCALE_LOG2E : 1.0f;
    base[0] = f2bf((x0 * c - x1 * sn) * sc);
    base[1] = f2bf((x0 * sn + x1 * c) * sc);
  } else {
    __shared__ unsigned short tile[32][33];
    const int t = blk - 20480;        // 0..2047
    const int bx = t & 15;            // C/32 = 16
    const int by = t >> 4;            // R/32 = 128
    const unsigned short* in = qkv + 2560;
    const int tx = threadIdx.x & 31;
    const int ty = threadIdx.x >> 5;
    const int r0 = by * 32;
    const int c0 = bx * 32;
#pragma unroll
    for (int i = 0; i < 32; i += 8)
      tile[ty + i][tx] = in[(size_t)(r0 + ty + i) * QKV_LD + c0 + tx];
    __syncthreads();
#pragma unroll
    for (int i = 0; i < 32; i += 8)
      vT[(size_t)(c0 + ty + i) * ROWS + r0 + tx] = tile[tx][ty + i];
  }
}

// ---------------------------------------------------------------------------
// m97-style MFMA GEMM: C[M][N] = A[M][K] @ BT[N][K]^T, both bf16,
// global_load_lds(16B) staging, unpadded LDS (lane-ordered), 128x128 tile.
// A row stride = lda (supports strided views of the fused qkv buffer).
// XCD-aware bijective chunked block swizzle (T1): requires nwg % 8 == 0
// (QKV: 768, WO: 512 — both divisible). Each XCD gets a contiguous chunk of
// x-major flat ids -> consecutive blocks on one XCD share the same B panel
// (L2-resident) instead of re-fetching it on all 8 XCD L2s.
// Ran correct in rounds 4-5 (passed, absmax unchanged).
// ---------------------------------------------------------------------------
template <int STORE_BF16>
__global__ __launch_bounds__(256) void gemm_bt_k(
    const unsigned short* __restrict__ A, const unsigned short* __restrict__ BT,
    void* __restrict__ Cp, int M, int N, int K, int lda) {
  __shared__ __align__(16) unsigned short As[128 * 32];
  __shared__ __align__(16) unsigned short Bs[128 * 32];
  const int tid = threadIdx.x;
  const int wave = tid >> 6;
  const int lane = tid & 63;
  const int quad = lane >> 4;
  const int l16 = lane & 15;
  // XCD swizzle: flat hardware id -> chunked work id (bijective, nwg%8==0)
  const int nwg = gridDim.x * gridDim.y;
  const int flat = blockIdx.y * gridDim.x + blockIdx.x;
  const int swz = (flat & 7) * (nwg >> 3) + (flat >> 3);
  const int m0 = (swz % gridDim.x) * 128;
  const int n0 = (swz / gridDim.x) * 128;
  const int wm = (wave >> 1) * 64;
  const int wn = (wave & 1) * 64;
  const int rsub = lane >> 2;       // 0..15
  const int coff = (lane & 3) * 8;  // elem offset of 16B chunk
  f32x4 acc[4][4] = {};

  for (int kt = 0; kt < K; kt += 32) {
    __syncthreads();
#pragma unroll
    for (int t = 0; t < 2; t++) {
      const int row = wave * 32 + t * 16 + rsub;
      async16(&A[(size_t)(m0 + row) * lda + kt + coff],
              &As[(wave * 32 + t * 16) * 32]);
      async16(&BT[(size_t)(n0 + row) * K + kt + coff],
              &Bs[(wave * 32 + t * 16) * 32]);
    }
    __syncthreads();
    bf16x8 af[4], bfr[4];
#pragma unroll
    for (int i = 0; i < 4; i++)
      af[i] = *(const bf16x8*)&As[(wm + i * 16 + l16) * 32 + quad * 8];
#pragma unroll
    for (int j = 0; j < 4; j++)
      bfr[j] = *(const bf16x8*)&Bs[(wn + j * 16 + l16) * 32 + quad * 8];
#pragma unroll
    for (int i = 0; i < 4; i++)
#pragma unroll
      for (int j = 0; j < 4; j++)
        acc[i][j] =
            __builtin_amdgcn_mfma_f32_16x16x32_bf16(af[i], bfr[j], acc[i][j], 0, 0, 0);
  }

  // Epilogue: C/D layout col = lane&15, row = quad*4 + reg  [m89/m91 verified]
#pragma unroll
  for (int i = 0; i < 4; i++) {
#pragma unroll
    for (int e = 0; e < 4; e++) {
      const int mrow = m0 + wm + i * 16 + quad * 4 + e;
#pragma unroll
      for (int j = 0; j < 4; j++) {
        const int ncol = n0 + wn + j * 16 + l16;
        const float val = acc[i][j][e];
        if (STORE_BF16) {
          ((unsigned short*)Cp)[(size_t)mrow * N + ncol] = f2bf(val);
        } else {
          ((float*)Cp)[(size_t)mrow * N + ncol] = val;
        }
      }
    }
  }
}

// ---------------------------------------------------------------------------
// Fallback MFMA GEMM (round-4): C[M][N] = A[M][K] @ B[K][N], B fp32 native.
// ---------------------------------------------------------------------------
template <int AF32, int STORE_BF16>
__global__ __launch_bounds__(256) void gemm_k(
    const void* __restrict__ Ap, const float* __restrict__ B,
    void* __restrict__ Cp, int M, int N, int K) {
  constexpr int LDP = 40;
  __shared__ __align__(16) unsigned short As[128 * LDP];
  __shared__ __align__(16) unsigned short Bs[128 * LDP];
  const int tid = threadIdx.x;
  const int wave = tid >> 6;
  const int lane = tid & 63;
  const int quad = lane >> 4;
  const int l16 = lane & 15;
  const int m0 = blockIdx.x * 128;
  const int n0 = blockIdx.y * 128;
  const int wm = (wave >> 1) * 64;
  const int wn = (wave & 1) * 64;
  f32x4 acc[4][4] = {};

  for (int kt = 0; kt < K; kt += 32) {
    __syncthreads();
    if (AF32) {
      const float* A = (const float*)Ap;
      for (int c = tid; c < 1024; c += 256) {
        const int r = c >> 3;
        const int cc = (c & 7) << 2;
        const float4 w = *(const float4*)&A[(size_t)(m0 + r) * K + kt + cc];
        union { unsigned short u[4]; uint2 v; } p;
        p.u[0] = f2bf(w.x); p.u[1] = f2bf(w.y);
        p.u[2] = f2bf(w.z); p.u[3] = f2bf(w.w);
        *(uint2*)&As[r * LDP + cc] = p.v;
      }
    } else {
      const unsigned short* A = (const unsigned short*)Ap;
      for (int c = tid; c < 512; c += 256) {
        const int r = c >> 2;
        const int cc = (c & 3) << 3;
        *(uint4*)&As[r * LDP + cc] =
            *(const uint4*)&A[(size_t)(m0 + r) * K + kt + cc];
      }
    }
    for (int c = tid; c < 1024; c += 256) {
      const int kr = c >> 5;
      const int nc = (c & 31) << 2;
      const float4 w = *(const float4*)&B[(size_t)(kt + kr) * N + n0 + nc];
      Bs[(nc + 0) * LDP + kr] = f2bf(w.x);
      Bs[(nc + 1) * LDP + kr] = f2bf(w.y);
      Bs[(nc + 2) * LDP + kr] = f2bf(w.z);
      Bs[(nc + 3) * LDP + kr] = f2bf(w.w);
    }
    __syncthreads();
    bf16x8 af[4], bfr[4];
#pragma unroll
    for (int i = 0; i < 4; i++)
      af[i] = *(const bf16x8*)&As[(wm + i * 16 + l16) * LDP + quad * 8];
#pragma unroll
    for (int j = 0; j < 4; j++)
      bfr[j] = *(const bf16x8*)&Bs[(wn + j * 16 + l16) * LDP + quad * 8];
#pragma unroll
    for (int i = 0; i < 4; i++)
#pragma unroll
      for (int j = 0; j < 4; j++)
        acc[i][j] =
            __builtin_amdgcn_mfma_f32_16x16x32_bf16(af[i], bfr[j], acc[i][j], 0, 0, 0);
  }
#pragma unroll
  for (int i = 0; i < 4; i++) {
#pragma unroll
    for (int e = 0; e < 4; e++) {
      const int mrow = m0 + wm + i * 16 + quad * 4 + e;
#pragma unroll
      for (int j = 0; j < 4; j++) {
        const int ncol = n0 + wn + j * 16 + l16;
        const float val = acc[i][j][e];
        if (STORE_BF16) {
          ((unsigned short*)Cp)[(size_t)mrow * N + ncol] = f2bf(val);
        } else {
          ((float*)Cp)[(size_t)mrow * N + ncol] = val;
        }
      }
    }
  }
}

// ---------------------------------------------------------------------------
// Fallback RoPE (separate q/k buffers)
// ---------------------------------------------------------------------------
__global__ __launch_bounds__(256) void rope_k(
    unsigned short* __restrict__ q, unsigned short* __restrict__ kk,
    const float* __restrict__ fc, const float* __restrict__ fs,
    int qstride, int kstride) {
  const int PQ = ROWS * N_H * (H_D / 2);
  const int PK = ROWS * N_KV * (H_D / 2);
  const int idx = blockIdx.x * 256 + threadIdx.x;
  if (idx >= PQ + PK) return;
  unsigned short* base;
  float c, sn;
  if (idx < PQ) {
    const int i = idx & 31;
    const int h = (idx >> 5) & 31;
    const int row = idx >> 10;
    const int s = row & (S_LEN - 1);
    c = fc[s * 32 + i];
    sn = fs[s * 32 + i];
    base = q + (size_t)row * qstride + h * H_D + 2 * i;
  } else {
    const int p = idx - PQ;
    const int i = p & 31;
    const int h = (p >> 5) & 7;
    const int row = p >> 8;
    const int s = row & (S_LEN - 1);
    c = fc[s * 32 + i];
    sn = fs[s * 32 + i];
    base = kk + (size_t)row * kstride + h * H_D + 2 * i;
  }
  const float x0 = bf2f(base[0]);
  const float x1 = bf2f(base[1]);
  base[0] = f2bf(x0 * c - x1 * sn);
  base[1] = f2bf(x0 * sn + x1 * c);
}

// ---------------------------------------------------------------------------
// attn v12 = v8 (round-2 verified, 79.5 us) + T5 s_setprio around MFMA
// clusters. v8 structure: 8-wave (512-thr) paired flash attention, 16 q-rows
// per wave, swapped-operand S^T, XOR-swizzled LDS, packed b64 P stores,
// NON-ONLINE softmax, l row-sums via ones-MFMA.
// Round-5 lesson: split-k variants (v9/v10/v11) all lose to this config —
// the register+LDS cost of 32-q-rows/wave structures kills the residency
// that makes v8 fast (16 waves/CU). Branch abandoned.
// T5: waves here run phase-skewed between per-tile barriers (exp2/pack VALU
// vs MFMA), the regime where setprio measured +4-7% on attention (m191).
// ---------------------------------------------------------------------------
__global__ __launch_bounds__(512, 4) void attn_mfma12_k(
    const unsigned short* __restrict__ qkv, const unsigned short* __restrict__ vT,
    unsigned short* __restrict__ ao) {
  const int pair = blockIdx.x, h = blockIdx.y, b = blockIdx.z;
  const int hk = h >> 2;
  const int tid = threadIdx.x;
  const int wave = tid >> 6;      // 0..7
  const int l16 = tid & 15;
  const int quad = (tid & 63) >> 4;
  const int rr = tid >> 3;        // 0..63 staging row
  const int dc = (tid & 7) * 8;   // staging 8-elem (16B) chunk
  const int rx = (l16 & 7) << 3;  // read/P-side XOR (elem units)
  const int sx = (rr & 7) << 3;   // stage-side XOR

  __shared__ __align__(16) unsigned short Ks[2][64 * 64];  // [key][d] swz
  __shared__ __align__(16) unsigned short Vt[2][64 * 64];  // [d][key] swz
  __shared__ __align__(16) unsigned short Ps[8][16 * 64];  // wave-private swz

  bf16x8 ones;
#pragma unroll
  for (int j = 0; j < 8; j++) ones[j] = (__bf16)1.0f;

  const size_t kbase =
      (size_t)(b * S_LEN) * QKV_LD + 2048 + hk * H_D + dc;  // k cols
  const size_t vbase = (size_t)(hk * H_D + rr) * ROWS + b * S_LEN + dc;

  for (int sel = 0; sel < 2; ++sel) {
    const int qb = sel ? (15 - pair) : pair;  // q-block of 128 rows
    const int row0 = qb * 128;
    const int ktiles = 2 * qb + 2;

    // Q fragments: A/B-frag layout lane holds [l16][quad*8+j]; 16 rows/wave
    bf16x8 af[2];
    {
      const size_t qrow = (size_t)(b * S_LEN + row0 + wave * 16 + l16);
#pragma unroll
      for (int c = 0; c < 2; c++)
        af[c] =
            *(const bf16x8*)&qkv[qrow * QKV_LD + h * H_D + c * 32 + quad * 8];
    }

    f32x4 o_acc[4] = {};
    f32x4 l_acc = {};

    // Prefetch tile 0 into registers, then stage into LDS buffer 0.
    uint4 rk, rv;
    {
      rk = *(const uint4*)&qkv[kbase + (size_t)rr * QKV_LD];
      rv = *(const uint4*)&vT[vbase];
    }
    __syncthreads();  // prior-sel readers of LDS done before overwrite
    *(uint4*)&Ks[0][rr * 64 + (dc ^ sx)] = rk;
    *(uint4*)&Vt[0][rr * 64 + (dc ^ sx)] = rv;

    int cur = 0;
    for (int kt = 0; kt < ktiles; ++kt) {
      // Prefetch next tile while this tile computes.
      if (kt + 1 < ktiles) {
        rk = *(const uint4*)&qkv[kbase + (size_t)((kt + 1) * 64 + rr) * QKV_LD];
        rv = *(const uint4*)&vT[vbase + (size_t)(kt + 1) * 64];
      }
      __syncthreads();  // LDS[cur] fully staged by all waves

      // S^T strips: D[row=k(quad*4+e), col=q(l16)] = mfma(K-frag, Q-frag).
      f32x4 sacc[4];
      __builtin_amdgcn_s_setprio(1);
#pragma unroll
      for (int n = 0; n < 4; n++) {
        f32x4 z = {};
#pragma unroll
        for (int c = 0; c < 2; c++) {
          const bf16x8 bk = *(const bf16x8*)&Ks[cur][(n * 16 + l16) * 64 +
                                                     ((c * 32 + quad * 8) ^ rx)];
          z = __builtin_amdgcn_mfma_f32_16x16x32_bf16(bk, af[c], z, 0, 0, 0);
        }
        sacc[n] = z;
      }
      __builtin_amdgcn_s_setprio(0);

      // pe = exp2(s); truncate to bf16; masked -> 0; packed b64 store to Ps.
      const bool maybe_mask = (kt >= 2 * qb);
      const int krel0 = (kt - 2 * qb) * 64;  // valid only when maybe_mask
      {
        const int qn = wave * 16 + l16;  // relative q row of this lane
        const int prow = l16 * 64;
#pragma unroll
        for (int n = 0; n < 4; n++) {
          const int kb0 = krel0 + n * 16 + quad * 4;  // relative k of e=0
          float pe[4];
#pragma unroll
          for (int e = 0; e < 4; e++) {
            float v = exp2f(sacc[n][e]);
            if (maybe_mask && (kb0 + e > qn)) v = 0.f;
            pe[e] = v;
          }
          uint2 u;
          u.x = (__float_as_uint(pe[0]) >> 16) |
                (__float_as_uint(pe[1]) & 0xFFFF0000u);
          u.y = (__float_as_uint(pe[2]) >> 16) |
                (__float_as_uint(pe[3]) & 0xFFFF0000u);
          *(uint2*)&Ps[wave][prow + ((n * 16 + quad * 4) ^ rx)] = u;
        }
      }
      // wave-private Ps: compiler inserts lgkmcnt wait; no barrier needed

      bf16x8 pf[2];
#pragma unroll
      for (int c = 0; c < 2; c++)
        pf[c] = *(const bf16x8*)&Ps[wave][l16 * 64 +
                                          ((c * 32 + quad * 8) ^ rx)];
      // l row-sums via MFMA against ones (replicated over cols) + PV.
      __builtin_amdgcn_s_setprio(1);
#pragma unroll
      for (int c = 0; c < 2; c++)
        l_acc = __builtin_amdgcn_mfma_f32_16x16x32_bf16(pf[c], ones, l_acc,
                                                        0, 0, 0);
#pragma unroll
      for (int n = 0; n < 4; n++)
#pragma unroll
        for (int c = 0; c < 2; c++) {
          const bf16x8 bv = *(const bf16x8*)&Vt[cur][(n * 16 + l16) * 64 +
                                                     ((c * 32 + quad * 8) ^ rx)];
          o_acc[n] = __builtin_amdgcn_mfma_f32_16x16x32_bf16(pf[c], bv,
                                                             o_acc[n], 0, 0, 0);
        }
      __builtin_amdgcn_s_setprio(0);

      // Stage prefetched tile into the other buffer (swizzled writes).
      if (kt + 1 < ktiles) {
        const int nxt = cur ^ 1;
        *(uint4*)&Ks[nxt][rr * 64 + (dc ^ sx)] = rk;
        *(uint4*)&Vt[nxt][rr * 64 + (dc ^ sx)] = rv;
      }
      cur ^= 1;
    }

    // Epilogue: l already reduced by MFMA; normalize, store bf16 (in-place q).
#pragma unroll
    for (int e = 0; e < 4; e++) {
      const float inv = 1.f / l_acc[e];
      const size_t row =
          (size_t)(b * S_LEN + row0 + wave * 16 + quad * 4 + e);
#pragma unroll
      for (int n = 0; n < 4; n++)
        ao[row * QKV_LD + h * H_D + n * 16 + l16] = f2bf(o_acc[n][e] * inv);
    }
  }
}

#define LK 72  // padded inner stride for fallback attention

// ---------------------------------------------------------------------------
// Round-4 attention (fallback path only): k/v separate buffers stride 512.
// ---------------------------------------------------------------------------
__global__ __launch_bounds__(256) void attn_mfma_k(
    const unsigned short* __restrict__ q, const unsigned short* __restrict__ k,
    const unsigned short* __restrict__ v, unsigned short* __restrict__ ao) {
  const int qt = blockIdx.x, h = blockIdx.y, b = blockIdx.z;
  const int hk = h >> 2;
  const int tid = threadIdx.x;
  const int wave = tid >> 6;
  const int l16 = tid & 15;
  const int quad = (tid & 63) >> 4;

  __shared__ __align__(16) unsigned short Ks[64 * LK];
  __shared__ __align__(16) unsigned short Vt[64 * LK];
  __shared__ __align__(16) unsigned short Ps[64 * LK];

  bf16x8 af[2];
  {
    const size_t qrow = (size_t)(b * S_LEN + qt * 64 + wave * 16 + l16);
#pragma unroll
    for (int c = 0; c < 2; c++)
      af[c] = *(const bf16x8*)&q[qrow * DMODEL + h * H_D + c * 32 + quad * 8];
  }

  f32x4 o_acc[4] = {};
  float m_i[4], l_i[4];
#pragma unroll
  for (int e = 0; e < 4; e++) { m_i[e] = -INFINITY; l_i[e] = 0.f; }

  for (int kt = 0; kt <= qt; ++kt) {
    const int kb = kt * 64;
    __syncthreads();
    {
      const int kr = tid >> 2;
      const int dc = (tid & 3) * 16;
      const size_t gro = (size_t)(b * S_LEN + kb + kr) * (N_KV * H_D) + hk * H_D + dc;
      *(uint4*)&Ks[kr * LK + dc] = *(const uint4*)&k[gro];
      *(uint4*)&Ks[kr * LK + dc + 8] = *(const uint4*)&k[gro + 8];
      union { unsigned short u[8]; uint4 v; } w0, w1;
      w0.v = *(const uint4*)&v[gro];
      w1.v = *(const uint4*)&v[gro + 8];
#pragma unroll
      for (int j = 0; j < 8; j++) Vt[(dc + j) * LK + kr] = w0.u[j];
#pragma unroll
      for (int j = 0; j < 8; j++) Vt[(dc + 8 + j) * LK + kr] = w1.u[j];
    }
    __syncthreads();

    f32x4 sacc[4];
#pragma unroll
    for (int n = 0; n < 4; n++) {
      f32x4 z = {};
#pragma unroll
      for (int c = 0; c < 2; c++) {
        const bf16x8 bk = *(const bf16x8*)&Ks[(n * 16 + l16) * LK + c * 32 + quad * 8];
        z = __builtin_amdgcn_mfma_f32_16x16x32_bf16(af[c], bk, z, 0, 0, 0);
      }
      sacc[n] = z;
    }

    float p[4][4], mnew[4];
#pragma unroll
    for (int e = 0; e < 4; e++) mnew[e] = m_i[e];
#pragma unroll
    for (int n = 0; n < 4; n++)
#pragma unroll
      for (int e = 0; e < 4; e++) {
        float s = sacc[n][e] * 0.125f;
        if (kt == qt && (n * 16 + l16) > (wave * 16 + quad * 4 + e))
          s = -INFINITY;
        p[n][e] = s;
        mnew[e] = fmaxf(mnew[e], s);
      }
#pragma unroll
    for (int e = 0; e < 4; e++) {
      mnew[e] = fmaxf(mnew[e], __shfl_xor(mnew[e], 1));
      mnew[e] = fmaxf(mnew[e], __shfl_xor(mnew[e], 2));
      mnew[e] = fmaxf(mnew[e], __shfl_xor(mnew[e], 4));
      mnew[e] = fmaxf(mnew[e], __shfl_xor(mnew[e], 8));
      const float alpha = __expf(m_i[e] - mnew[e]);
      m_i[e] = mnew[e];
      l_i[e] *= alpha;
#pragma unroll
      for (int n = 0; n < 4; n++) o_acc[n][e] *= alpha;
    }
#pragma unroll
    for (int n = 0; n < 4; n++)
#pragma unroll
      for (int e = 0; e < 4; e++) {
        const float pe = __expf(p[n][e] - m_i[e]);
        p[n][e] = pe;
        l_i[e] += pe;
      }

#pragma unroll
    for (int n = 0; n < 4; n++)
#pragma unroll
      for (int e = 0; e < 4; e++)
        Ps[(wave * 16 + quad * 4 + e) * LK + n * 16 + l16] = f2bf(p[n][e]);
    __syncthreads();

    bf16x8 pf[2];
#pragma unroll
    for (int c = 0; c < 2; c++)
      pf[c] = *(const bf16x8*)&Ps[(wave * 16 + l16) * LK + c * 32 + quad * 8];
#pragma unroll
    for (int n = 0; n < 4; n++)
#pragma unroll
      for (int c = 0; c < 2; c++) {
        const bf16x8 bv = *(const bf16x8*)&Vt[(n * 16 + l16) * LK + c * 32 + quad * 8];
        o_acc[n] = __builtin_amdgcn_mfma_f32_16x16x32_bf16(pf[c], bv, o_acc[n], 0, 0, 0);
      }
  }

#pragma unroll
  for (int e = 0; e < 4; e++) {
    l_i[e] += __shfl_xor(l_i[e], 1);
    l_i[e] += __shfl_xor(l_i[e], 2);
    l_i[e] += __shfl_xor(l_i[e], 4);
    l_i[e] += __shfl_xor(l_i[e], 8);
    const float inv = 1.f / l_i[e];
    const size_t row = (size_t)(b * S_LEN + qt * 64 + wave * 16 + quad * 4 + e);
#pragma unroll
    for (int n = 0; n < 4; n++)
      ao[row * DMODEL + h * H_D + n * 16 + l16] = f2bf(o_acc[n][e] * inv);
  }
}

// ---------------------------------------------------------------------------
extern "C" void kernel_launch(void* const* d_in, const int* in_sizes, int n_in,
                              void* d_out, int out_size, void* d_ws, size_t ws_size,
                              hipStream_t stream) {
  const float* x = (const float*)d_in[0];
  const float* fc = (const float*)d_in[1];
  const float* fs = (const float*)d_in[2];
  const float* wq = (const float*)d_in[3];
  const float* wk = (const float*)d_in[4];
  const float* wv = (const float*)d_in[5];
  const float* wo = (const float*)d_in[6];

  char* ws = (char*)d_ws;
  const dim3 b256(256);

  if (ws_size >= (64ull << 20)) {
    // Fast path (64 MB):
    //   qkv   bf16 [4096][3072] @ 0     (24 MB)  q|k|v fused; attn out in q cols
    //   xb    bf16 [4096][2048] @ 24 MB (16 MB)
    //   wqkvT bf16 [3072][2048] @ 40 MB (12 MB)
    //   woT   bf16 [2048][2048] @ 52 MB ( 8 MB)
    //   vT    bf16 [ 512][4096] @ 60 MB ( 4 MB)
    unsigned short* qkv = (unsigned short*)(ws);
    unsigned short* xb = (unsigned short*)(ws + (24ull << 20));
    unsigned short* wqkvT = (unsigned short*)(ws + (40ull << 20));
    unsigned short* woT = (unsigned short*)(ws + (52ull << 20));
    unsigned short* vT = (unsigned short*)(ws + (60ull << 20));

    prep_all_k<<<dim3(64, 64, 5), b256, 0, stream>>>(x, wq, wk, wv, wo, xb,
                                                     wqkvT, woT);

    // One fused QKV projection: [4096][2048] @ [3072][2048]^T -> [4096][3072]
    gemm_bt_k<1><<<dim3(32, 24), b256, 0, stream>>>(xb, wqkvT, qkv, 4096, 3072,
                                                    2048, 2048);

    // RoPE (q pre-scaled by log2e/8, k plain) + v -> vT transpose, fused
    rope_vt_k<<<dim3(20480 + 2048), b256, 0, stream>>>(qkv, vT, fc, fs);

    // Paired 8-wave attention (v8 + setprio): 512 blocks x 512 thr.
    attn_mfma12_k<<<dim3(8, N_H, 2), dim3(512), 0, stream>>>(qkv, vT, qkv);

    // Output projection reads attn output (qkv q-cols, lda=3072) -> fp32 d_out
    gemm_bt_k<0><<<dim3(32, 16), b256, 0, stream>>>(qkv, woT, d_out, 4096, 2048,
                                                    2048, QKV_LD);
  } else {
    // Round-4 fallback (<= 40 MB)
    unsigned short* q = (unsigned short*)(ws);
    unsigned short* k = (unsigned short*)(ws + (16ull << 20));
    unsigned short* v = (unsigned short*)(ws + (20ull << 20));
    unsigned short* xb = (unsigned short*)(ws + (24ull << 20));
    const bool have_xb = ws_size >= (40ull << 20);

    if (have_xb) {
      cvt_bf16_k<<<dim3(ROWS * DMODEL / (256 * 8)), b256, 0, stream>>>(x, xb);
      gemm_k<0, 1><<<dim3(32, 16), b256, 0, stream>>>(xb, wq, q, 4096, 2048, 2048);
      gemm_k<0, 1><<<dim3(32, 4), b256, 0, stream>>>(xb, wk, k, 4096, 512, 2048);
      gemm_k<0, 1><<<dim3(32, 4), b256, 0, stream>>>(xb, wv, v, 4096, 512, 2048);
    } else {
      gemm_k<1, 1><<<dim3(32, 16), b256, 0, stream>>>(x, wq, q, 4096, 2048, 2048);
      gemm_k<1, 1><<<dim3(32, 4), b256, 0, stream>>>(x, wk, k, 4096, 512, 2048);
      gemm_k<1, 1><<<dim3(32, 4), b256, 0, stream>>>(x, wv, v, 4096, 512, 2048);
    }

    rope_k<<<dim3(20480), b256, 0, stream>>>(q, k, fc, fs, N_H * H_D, N_KV * H_D);
    attn_mfma_k<<<dim3(S_LEN / 64, N_H, 2), b256, 0, stream>>>(q, k, v, q);
    gemm_k<0, 0><<<dim3(32, 16), b256, 0, stream>>>(q, wo, d_out, 4096, 2048, 2048);
  }
}

// Round 7
// 302.408 us; speedup vs baseline: 1.1189x; 1.0751x over previous
//
#include <hip/hip_runtime.h>
#include <hip/hip_bf16.h>

// Problem constants (B=2, S=2048, D=2048, NH=32, NKV=8, HD=64, NREP=4)
#define S_LEN 2048
#define DMODEL 2048
#define N_H 32
#define N_KV 8
#define H_D 64
#define ROWS 4096   // B*S
#define QKV_LD 3072 // fused qkv row stride: q[0:2048) k[2048:2560) v[2560:3072)

typedef __bf16 bf16x8 __attribute__((ext_vector_type(8)));
typedef float f32x4 __attribute__((ext_vector_type(4)));

// fp32 -> bf16 raw bits, round-to-nearest-even
static __device__ __forceinline__ unsigned short f2bf(float f) {
  unsigned int u = __float_as_uint(f);
  u += 0x7FFFu + ((u >> 16) & 1u);
  return (unsigned short)(u >> 16);
}
static __device__ __forceinline__ float bf2f(unsigned short s) {
  return __uint_as_float((unsigned int)s << 16);
}

// async global->LDS, 16 B per lane. LDS dest = wave-uniform base + lane*16.
static __device__ __forceinline__ void async16(const void* g, void* l) {
  __builtin_amdgcn_global_load_lds(
      (const __attribute__((address_space(1))) unsigned int*)g,
      (__attribute__((address_space(3))) unsigned int*)l, 16, 0, 0);
}

// counted vmcnt + raw barrier (T4): loads stay in flight across the barrier.
// memory clobbers pin ds_read/global_load_lds ordering around it.
#define VMB(N)                                                    \
  do {                                                            \
    asm volatile("s_waitcnt vmcnt(" #N ")" ::: "memory");         \
    __builtin_amdgcn_s_barrier();                                 \
    asm volatile("" ::: "memory");                                \
  } while (0)

// ---------------------------------------------------------------------------
// fp32 -> bf16 bulk convert (8 elems/thread) — fallback path only
// ---------------------------------------------------------------------------
__global__ __launch_bounds__(256) void cvt_bf16_k(
    const float* __restrict__ in, unsigned short* __restrict__ out) {
  const size_t i = ((size_t)blockIdx.x * 256 + threadIdx.x) * 8;
  const float4 a = *(const float4*)&in[i];
  const float4 b = *(const float4*)&in[i + 4];
  union { unsigned short u[8]; uint4 v; } p;
  p.u[0] = f2bf(a.x); p.u[1] = f2bf(a.y); p.u[2] = f2bf(a.z); p.u[3] = f2bf(a.w);
  p.u[4] = f2bf(b.x); p.u[5] = f2bf(b.y); p.u[6] = f2bf(b.z); p.u[7] = f2bf(b.w);
  *(uint4*)&out[i] = p.v;
}

// ---------------------------------------------------------------------------
// Combined prep: z=0..3 transpose fp32 weights -> bf16 wqkvT/woT blocks;
// z=4: straight cvt x fp32 -> xb bf16 (64x64 blocks x 256 thr x 8 elems).
// ---------------------------------------------------------------------------
__global__ __launch_bounds__(256) void prep_all_k(
    const float* __restrict__ x, const float* __restrict__ wq,
    const float* __restrict__ wk, const float* __restrict__ wv,
    const float* __restrict__ wo, unsigned short* __restrict__ xb,
    unsigned short* __restrict__ wqkvT, unsigned short* __restrict__ woT) {
  const int z = blockIdx.z;
  if (z == 4) {
    const size_t i =
        (((size_t)blockIdx.y * 64 + blockIdx.x) * 256 + threadIdx.x) * 8;
    const float4 a = *(const float4*)&x[i];
    const float4 b = *(const float4*)&x[i + 4];
    union { unsigned short u[8]; uint4 v; } p;
    p.u[0] = f2bf(a.x); p.u[1] = f2bf(a.y); p.u[2] = f2bf(a.z); p.u[3] = f2bf(a.w);
    p.u[4] = f2bf(b.x); p.u[5] = f2bf(b.y); p.u[6] = f2bf(b.z); p.u[7] = f2bf(b.w);
    *(uint4*)&xb[i] = p.v;
    return;
  }
  const float* in;
  unsigned short* out;
  int C;
  if (z == 0)      { in = wq; out = wqkvT;                  C = 2048; }
  else if (z == 1) { in = wk; out = wqkvT + 2048ull * 2048; C = 512;  }
  else if (z == 2) { in = wv; out = wqkvT + 2560ull * 2048; C = 512;  }
  else             { in = wo; out = woT;                    C = 2048; }
  if (blockIdx.x * 32 >= C) return;

  __shared__ unsigned short tile[32][33];
  const int tx = threadIdx.x & 31;
  const int ty = threadIdx.x >> 5;
  const int r0 = blockIdx.y * 32;  // K rows of input
  const int c0 = blockIdx.x * 32;  // C cols of input
#pragma unroll
  for (int i = 0; i < 32; i += 8)
    tile[ty + i][tx] = f2bf(in[(size_t)(r0 + ty + i) * C + c0 + tx]);
  __syncthreads();
#pragma unroll
  for (int i = 0; i < 32; i += 8)
    out[(size_t)(c0 + ty + i) * 2048 + r0 + tx] = tile[tx][ty + i];
}

// log2(e) / sqrt(HD): softmax base-2 conversion + 1/sqrt(d), folded into q
#define SCALE_LOG2E 0.18033688011112042f

// ---------------------------------------------------------------------------
// Fused RoPE (blocks 0..20479) + v->vT transpose (blocks 20480..22527).
// rope: in-place on qkv views; q is additionally PRE-SCALED by SCALE_LOG2E
// so attention's QK^T comes out directly in base-2 exponent units.
// vT: qkv cols 2560..3071 ([4096][512] view, ld QKV_LD) -> vT [512][4096].
// ---------------------------------------------------------------------------
__global__ __launch_bounds__(256) void rope_vt_k(
    unsigned short* __restrict__ qkv, unsigned short* __restrict__ vT,
    const float* __restrict__ fc, const float* __restrict__ fs) {
  const int blk = blockIdx.x;
  if (blk < 20480) {
    const int PQ = ROWS * N_H * (H_D / 2);   // 4194304
    const int PK = ROWS * N_KV * (H_D / 2);  // 1048576
    const int idx = blk * 256 + threadIdx.x;
    if (idx >= PQ + PK) return;
    unsigned short* base;
    float c, sn;
    bool isq;
    if (idx < PQ) {
      const int i = idx & 31;
      const int h = (idx >> 5) & 31;
      const int row = idx >> 10;
      const int s = row & (S_LEN - 1);
      c = fc[s * 32 + i];
      sn = fs[s * 32 + i];
      base = qkv + (size_t)row * QKV_LD + h * H_D + 2 * i;
      isq = true;
    } else {
      const int p = idx - PQ;
      const int i = p & 31;
      const int h = (p >> 5) & 7;
      const int row = p >> 8;
      const int s = row & (S_LEN - 1);
      c = fc[s * 32 + i];
      sn = fs[s * 32 + i];
      base = qkv + (size_t)row * QKV_LD + 2048 + h * H_D + 2 * i;
      isq = false;
    }
    const float x0 = bf2f(base[0]);
    const float x1 = bf2f(base[1]);
    const float sc = isq ? SCALE_LOG2E : 1.0f;
    base[0] = f2bf((x0 * c - x1 * sn) * sc);
    base[1] = f2bf((x0 * sn + x1 * c) * sc);
  } else {
    __shared__ unsigned short tile[32][33];
    const int t = blk - 20480;        // 0..2047
    const int bx = t & 15;            // C/32 = 16
    const int by = t >> 4;            // R/32 = 128
    const unsigned short* in = qkv + 2560;
    const int tx = threadIdx.x & 31;
    const int ty = threadIdx.x >> 5;
    const int r0 = by * 32;
    const int c0 = bx * 32;
#pragma unroll
    for (int i = 0; i < 32; i += 8)
      tile[ty + i][tx] = in[(size_t)(r0 + ty + i) * QKV_LD + c0 + tx];
    __syncthreads();
#pragma unroll
    for (int i = 0; i < 32; i += 8)
      vT[(size_t)(c0 + ty + i) * ROWS + r0 + tx] = tile[tx][ty + i];
  }
}

// ---------------------------------------------------------------------------
// gemm8: 8-phase deep-pipelined 256x256 MFMA GEMM (T2+T3+T4+T5).
// C[M][N] = A[M][K] @ BT[N][K]^T, bf16 in, BK=64, 8 waves (2M x 4N),
// per-wave output 128x64, LDS 128 KiB (2 dbuf x {A,B} x 256x64 bf16).
//
// Pipeline (per wave, per K-tile): 8 global_load_lds issues in fixed order
// [B0,B1,B2,B3,A0,A1,A2,A3] (2 per phase), staging the NEXT tile. A-instr j
// stages exactly the 32 M-rows consumed by phase j. Phase-top waits:
//   ph0: queue [B0..B3,A0..A3](8)       vmcnt(3) -> B all + A0 landed
//   ph1: [A1,A2,A3,B0',B1'](5)          vmcnt(4) -> A1
//   ph2: [A2,A3,B0'..B3'](6)            vmcnt(5) -> A2
//   ph3: [A3,B0'..B3',A0',A1'](7)       vmcnt(6) -> A3
// Counted vmcnt + raw s_barrier: 2-7 loads stay in flight across every
// barrier (the T4 lever; never vmcnt(0) in the loop). Cross-wave safety:
// every wave executes the same wait before the shared barrier, so all
// portions of a half-tile are landed once the barrier is passed. Last tile
// issues dummy prefetches (kt=0) to keep the ledger uniform.
// T2: 16B-chunk XOR swizzle keyed on (row&7) — pre-swizzled GLOBAL source +
// linear gload_lds dest + swizzled ds_read (both-sides involution, rule 21).
// Numerics: same sequential K accumulation order as the 128-tile kernel.
// ---------------------------------------------------------------------------
template <int STORE_BF16>
__global__ __launch_bounds__(512, 2) void gemm8_bt_k(
    const unsigned short* __restrict__ A, const unsigned short* __restrict__ BT,
    void* __restrict__ Cp, int M, int N, int K, int lda) {
  __shared__ __align__(16) unsigned short As[2][2][128 * 64];
  __shared__ __align__(16) unsigned short Bs[2][2][128 * 64];
  const int tid = threadIdx.x;
  const int wave = tid >> 6;
  const int lane = tid & 63;
  const int quad = lane >> 4;
  const int l16 = lane & 15;
  // XCD-aware bijective chunked swizzle (nwg % 8 == 0 for both uses)
  const int nwg = gridDim.x * gridDim.y;
  const int flat = blockIdx.y * gridDim.x + blockIdx.x;
  const int swz = (flat & 7) * (nwg >> 3) + (flat >> 3);
  const int m0 = (swz % gridDim.x) * 256;
  const int n0 = (swz / gridDim.x) * 256;
  // wave roles: M-half + stage slot; N(B)-half + stage slot
  const int ah = wave & 1;   // A half this wave computes on (M rows)
  const int ag = wave >> 1;  // stage slot within A-group (4 waves/half)
  const int bh = wave >> 2;  // B half this wave computes on (N rows)
  const int bg = wave & 3;   // stage slot within B-group
  const int bl = (ag & 1) * 64;       // local N offset inside B half
  const int rx = (l16 & 7) << 3;      // ds_read swizzle (elem units)
  // per-lane pre-swizzled source column (elem units), j-independent
  const int scol = ((lane & 7) * 8) ^ ((lane >> 3) << 3);
  const int srA = 8 * ag + (lane >> 3);  // + 32*j = source row in half
  const int srB = 8 * bg + (lane >> 3);
  const size_t abase = (size_t)(m0 + ah * 128) * lda;
  const size_t bbase = (size_t)(n0 + bh * 128) * K;
  f32x4 acc[8][4] = {};

#define STG_B(j, buf, kt)                                             \
  async16(&BT[bbase + (size_t)(32 * (j) + srB) * K + (kt) + scol],    \
          &Bs[buf][bh][(32 * (j) + 8 * bg) * 64])
#define STG_A(j, buf, kt)                                             \
  async16(&A[abase + (size_t)(32 * (j) + srA) * lda + (kt) + scol],   \
          &As[buf][ah][(32 * (j) + 8 * ag) * 64])

  // prologue: stage tile 0 into buf 0 in ledger order
  STG_B(0, 0, 0); STG_B(1, 0, 0); STG_B(2, 0, 0); STG_B(3, 0, 0);
  STG_A(0, 0, 0); STG_A(1, 0, 0); STG_A(2, 0, 0); STG_A(3, 0, 0);

  const int NT = K >> 6;
  for (int t = 0; t < NT; ++t) {
    const int cur = t & 1, nxt = cur ^ 1;
    const int ktn = (t + 1 < NT) ? ((t + 1) << 6) : 0;  // dummy tail issues
    const unsigned short* Ac = &As[cur][ah][0];
    const unsigned short* Bc = &Bs[cur][bh][0];
    bf16x8 bf[4][2];

    // ---- phase 0: B frags + A frags 0,1 ----
    VMB(3);
    {
      bf16x8 af[2][2];
#pragma unroll
      for (int n = 0; n < 4; n++)
#pragma unroll
        for (int kk = 0; kk < 2; kk++)
          bf[n][kk] = *(const bf16x8*)&Bc[(bl + n * 16 + l16) * 64 +
                                          ((kk * 32 + quad * 8) ^ rx)];
#pragma unroll
      for (int i = 0; i < 2; i++)
#pragma unroll
        for (int kk = 0; kk < 2; kk++)
          af[i][kk] = *(const bf16x8*)&Ac[((0 + i) * 16 + l16) * 64 +
                                          ((kk * 32 + quad * 8) ^ rx)];
      STG_B(0, nxt, ktn); STG_B(1, nxt, ktn);
      __builtin_amdgcn_s_setprio(1);
#pragma unroll
      for (int i = 0; i < 2; i++)
#pragma unroll
        for (int n = 0; n < 4; n++)
#pragma unroll
          for (int kk = 0; kk < 2; kk++)
            acc[0 + i][n] = __builtin_amdgcn_mfma_f32_16x16x32_bf16(
                af[i][kk], bf[n][kk], acc[0 + i][n], 0, 0, 0);
      __builtin_amdgcn_s_setprio(0);
    }

    // ---- phase 1: A frags 2,3 ----
    VMB(4);
    {
      bf16x8 af[2][2];
#pragma unroll
      for (int i = 0; i < 2; i++)
#pragma unroll
        for (int kk = 0; kk < 2; kk++)
          af[i][kk] = *(const bf16x8*)&Ac[((2 + i) * 16 + l16) * 64 +
                                          ((kk * 32 + quad * 8) ^ rx)];
      STG_B(2, nxt, ktn); STG_B(3, nxt, ktn);
      __builtin_amdgcn_s_setprio(1);
#pragma unroll
      for (int i = 0; i < 2; i++)
#pragma unroll
        for (int n = 0; n < 4; n++)
#pragma unroll
          for (int kk = 0; kk < 2; kk++)
            acc[2 + i][n] = __builtin_amdgcn_mfma_f32_16x16x32_bf16(
                af[i][kk], bf[n][kk], acc[2 + i][n], 0, 0, 0);
      __builtin_amdgcn_s_setprio(0);
    }

    // ---- phase 2: A frags 4,5 ----
    VMB(5);
    {
      bf16x8 af[2][2];
#pragma unroll
      for (int i = 0; i < 2; i++)
#pragma unroll
        for (int kk = 0; kk < 2; kk++)
          af[i][kk] = *(const bf16x8*)&Ac[((4 + i) * 16 + l16) * 64 +
                                          ((kk * 32 + quad * 8) ^ rx)];
      STG_A(0, nxt, ktn); STG_A(1, nxt, ktn);
      __builtin_amdgcn_s_setprio(1);
#pragma unroll
      for (int i = 0; i < 2; i++)
#pragma unroll
        for (int n = 0; n < 4; n++)
#pragma unroll
          for (int kk = 0; kk < 2; kk++)
            acc[4 + i][n] = __builtin_amdgcn_mfma_f32_16x16x32_bf16(
                af[i][kk], bf[n][kk], acc[4 + i][n], 0, 0, 0);
      __builtin_amdgcn_s_setprio(0);
    }

    // ---- phase 3: A frags 6,7 ----
    VMB(6);
    {
      bf16x8 af[2][2];
#pragma unroll
      for (int i = 0; i < 2; i++)
#pragma unroll
        for (int kk = 0; kk < 2; kk++)
          af[i][kk] = *(const bf16x8*)&Ac[((6 + i) * 16 + l16) * 64 +
                                          ((kk * 32 + quad * 8) ^ rx)];
      STG_A(2, nxt, ktn); STG_A(3, nxt, ktn);
      __builtin_amdgcn_s_setprio(1);
#pragma unroll
      for (int i = 0; i < 2; i++)
#pragma unroll
        for (int n = 0; n < 4; n++)
#pragma unroll
          for (int kk = 0; kk < 2; kk++)
            acc[6 + i][n] = __builtin_amdgcn_mfma_f32_16x16x32_bf16(
                af[i][kk], bf[n][kk], acc[6 + i][n], 0, 0, 0);
      __builtin_amdgcn_s_setprio(0);
    }
  }
#undef STG_A
#undef STG_B

  // Epilogue: C/D layout col = lane&15, row = quad*4 + reg  [m89/m91]
  const int wn = (wave >> 1) * 64;  // == bh*128 + bl
#pragma unroll
  for (int f = 0; f < 8; f++) {
#pragma unroll
    for (int e = 0; e < 4; e++) {
      const int mrow = m0 + ah * 128 + f * 16 + quad * 4 + e;
#pragma unroll
      for (int n = 0; n < 4; n++) {
        const int ncol = n0 + wn + n * 16 + l16;
        const float val = acc[f][n][e];
        if (STORE_BF16) {
          ((unsigned short*)Cp)[(size_t)mrow * N + ncol] = f2bf(val);
        } else {
          ((float*)Cp)[(size_t)mrow * N + ncol] = val;
        }
      }
    }
  }
}

// ---------------------------------------------------------------------------
// m97-style 128x128 MFMA GEMM (kept for easy revert; unused in fast path).
// ---------------------------------------------------------------------------
template <int STORE_BF16>
__global__ __launch_bounds__(256) void gemm_bt_k(
    const unsigned short* __restrict__ A, const unsigned short* __restrict__ BT,
    void* __restrict__ Cp, int M, int N, int K, int lda) {
  __shared__ __align__(16) unsigned short As[128 * 32];
  __shared__ __align__(16) unsigned short Bs[128 * 32];
  const int tid = threadIdx.x;
  const int wave = tid >> 6;
  const int lane = tid & 63;
  const int quad = lane >> 4;
  const int l16 = lane & 15;
  const int nwg = gridDim.x * gridDim.y;
  const int flat = blockIdx.y * gridDim.x + blockIdx.x;
  const int swz = (flat & 7) * (nwg >> 3) + (flat >> 3);
  const int m0 = (swz % gridDim.x) * 128;
  const int n0 = (swz / gridDim.x) * 128;
  const int wm = (wave >> 1) * 64;
  const int wn = (wave & 1) * 64;
  const int rsub = lane >> 2;
  const int coff = (lane & 3) * 8;
  f32x4 acc[4][4] = {};

  for (int kt = 0; kt < K; kt += 32) {
    __syncthreads();
#pragma unroll
    for (int t = 0; t < 2; t++) {
      const int row = wave * 32 + t * 16 + rsub;
      async16(&A[(size_t)(m0 + row) * lda + kt + coff],
              &As[(wave * 32 + t * 16) * 32]);
      async16(&BT[(size_t)(n0 + row) * K + kt + coff],
              &Bs[(wave * 32 + t * 16) * 32]);
    }
    __syncthreads();
    bf16x8 af[4], bfr[4];
#pragma unroll
    for (int i = 0; i < 4; i++)
      af[i] = *(const bf16x8*)&As[(wm + i * 16 + l16) * 32 + quad * 8];
#pragma unroll
    for (int j = 0; j < 4; j++)
      bfr[j] = *(const bf16x8*)&Bs[(wn + j * 16 + l16) * 32 + quad * 8];
#pragma unroll
    for (int i = 0; i < 4; i++)
#pragma unroll
      for (int j = 0; j < 4; j++)
        acc[i][j] =
            __builtin_amdgcn_mfma_f32_16x16x32_bf16(af[i], bfr[j], acc[i][j], 0, 0, 0);
  }
#pragma unroll
  for (int i = 0; i < 4; i++) {
#pragma unroll
    for (int e = 0; e < 4; e++) {
      const int mrow = m0 + wm + i * 16 + quad * 4 + e;
#pragma unroll
      for (int j = 0; j < 4; j++) {
        const int ncol = n0 + wn + j * 16 + l16;
        const float val = acc[i][j][e];
        if (STORE_BF16) {
          ((unsigned short*)Cp)[(size_t)mrow * N + ncol] = f2bf(val);
        } else {
          ((float*)Cp)[(size_t)mrow * N + ncol] = val;
        }
      }
    }
  }
}

// ---------------------------------------------------------------------------
// Fallback MFMA GEMM (round-4): C[M][N] = A[M][K] @ B[K][N], B fp32 native.
// ---------------------------------------------------------------------------
template <int AF32, int STORE_BF16>
__global__ __launch_bounds__(256) void gemm_k(
    const void* __restrict__ Ap, const float* __restrict__ B,
    void* __restrict__ Cp, int M, int N, int K) {
  constexpr int LDP = 40;
  __shared__ __align__(16) unsigned short As[128 * LDP];
  __shared__ __align__(16) unsigned short Bs[128 * LDP];
  const int tid = threadIdx.x;
  const int wave = tid >> 6;
  const int lane = tid & 63;
  const int quad = lane >> 4;
  const int l16 = lane & 15;
  const int m0 = blockIdx.x * 128;
  const int n0 = blockIdx.y * 128;
  const int wm = (wave >> 1) * 64;
  const int wn = (wave & 1) * 64;
  f32x4 acc[4][4] = {};

  for (int kt = 0; kt < K; kt += 32) {
    __syncthreads();
    if (AF32) {
      const float* A = (const float*)Ap;
      for (int c = tid; c < 1024; c += 256) {
        const int r = c >> 3;
        const int cc = (c & 7) << 2;
        const float4 w = *(const float4*)&A[(size_t)(m0 + r) * K + kt + cc];
        union { unsigned short u[4]; uint2 v; } p;
        p.u[0] = f2bf(w.x); p.u[1] = f2bf(w.y);
        p.u[2] = f2bf(w.z); p.u[3] = f2bf(w.w);
        *(uint2*)&As[r * LDP + cc] = p.v;
      }
    } else {
      const unsigned short* A = (const unsigned short*)Ap;
      for (int c = tid; c < 512; c += 256) {
        const int r = c >> 2;
        const int cc = (c & 3) << 3;
        *(uint4*)&As[r * LDP + cc] =
            *(const uint4*)&A[(size_t)(m0 + r) * K + kt + cc];
      }
    }
    for (int c = tid; c < 1024; c += 256) {
      const int kr = c >> 5;
      const int nc = (c & 31) << 2;
      const float4 w = *(const float4*)&B[(size_t)(kt + kr) * N + n0 + nc];
      Bs[(nc + 0) * LDP + kr] = f2bf(w.x);
      Bs[(nc + 1) * LDP + kr] = f2bf(w.y);
      Bs[(nc + 2) * LDP + kr] = f2bf(w.z);
      Bs[(nc + 3) * LDP + kr] = f2bf(w.w);
    }
    __syncthreads();
    bf16x8 af[4], bfr[4];
#pragma unroll
    for (int i = 0; i < 4; i++)
      af[i] = *(const bf16x8*)&As[(wm + i * 16 + l16) * LDP + quad * 8];
#pragma unroll
    for (int j = 0; j < 4; j++)
      bfr[j] = *(const bf16x8*)&Bs[(wn + j * 16 + l16) * LDP + quad * 8];
#pragma unroll
    for (int i = 0; i < 4; i++)
#pragma unroll
      for (int j = 0; j < 4; j++)
        acc[i][j] =
            __builtin_amdgcn_mfma_f32_16x16x32_bf16(af[i], bfr[j], acc[i][j], 0, 0, 0);
  }
#pragma unroll
  for (int i = 0; i < 4; i++) {
#pragma unroll
    for (int e = 0; e < 4; e++) {
      const int mrow = m0 + wm + i * 16 + quad * 4 + e;
#pragma unroll
      for (int j = 0; j < 4; j++) {
        const int ncol = n0 + wn + j * 16 + l16;
        const float val = acc[i][j][e];
        if (STORE_BF16) {
          ((unsigned short*)Cp)[(size_t)mrow * N + ncol] = f2bf(val);
        } else {
          ((float*)Cp)[(size_t)mrow * N + ncol] = val;
        }
      }
    }
  }
}

// ---------------------------------------------------------------------------
// Fallback RoPE (separate q/k buffers)
// ---------------------------------------------------------------------------
__global__ __launch_bounds__(256) void rope_k(
    unsigned short* __restrict__ q, unsigned short* __restrict__ kk,
    const float* __restrict__ fc, const float* __restrict__ fs,
    int qstride, int kstride) {
  const int PQ = ROWS * N_H * (H_D / 2);
  const int PK = ROWS * N_KV * (H_D / 2);
  const int idx = blockIdx.x * 256 + threadIdx.x;
  if (idx >= PQ + PK) return;
  unsigned short* base;
  float c, sn;
  if (idx < PQ) {
    const int i = idx & 31;
    const int h = (idx >> 5) & 31;
    const int row = idx >> 10;
    const int s = row & (S_LEN - 1);
    c = fc[s * 32 + i];
    sn = fs[s * 32 + i];
    base = q + (size_t)row * qstride + h * H_D + 2 * i;
  } else {
    const int p = idx - PQ;
    const int i = p & 31;
    const int h = (p >> 5) & 7;
    const int row = p >> 8;
    const int s = row & (S_LEN - 1);
    c = fc[s * 32 + i];
    sn = fs[s * 32 + i];
    base = kk + (size_t)row * kstride + h * H_D + 2 * i;
  }
  const float x0 = bf2f(base[0]);
  const float x1 = bf2f(base[1]);
  base[0] = f2bf(x0 * c - x1 * sn);
  base[1] = f2bf(x0 * sn + x1 * c);
}

// ---------------------------------------------------------------------------
// attn v8 (round-2 verified, 79.5 us — best config; setprio reverted, it
// measured -3 us in round 6). 8-wave (512-thr) paired flash attention,
// 16 q-rows/wave, swapped-operand S^T, XOR-swizzled LDS, packed b64 P
// stores, NON-ONLINE softmax, l row-sums via ones-MFMA. 2 blocks/CU.
// ---------------------------------------------------------------------------
__global__ __launch_bounds__(512, 4) void attn_mfma8_k(
    const unsigned short* __restrict__ qkv, const unsigned short* __restrict__ vT,
    unsigned short* __restrict__ ao) {
  const int pair = blockIdx.x, h = blockIdx.y, b = blockIdx.z;
  const int hk = h >> 2;
  const int tid = threadIdx.x;
  const int wave = tid >> 6;      // 0..7
  const int l16 = tid & 15;
  const int quad = (tid & 63) >> 4;
  const int rr = tid >> 3;        // 0..63 staging row
  const int dc = (tid & 7) * 8;   // staging 8-elem (16B) chunk
  const int rx = (l16 & 7) << 3;  // read/P-side XOR (elem units)
  const int sx = (rr & 7) << 3;   // stage-side XOR

  __shared__ __align__(16) unsigned short Ks[2][64 * 64];  // [key][d] swz
  __shared__ __align__(16) unsigned short Vt[2][64 * 64];  // [d][key] swz
  __shared__ __align__(16) unsigned short Ps[8][16 * 64];  // wave-private swz

  bf16x8 ones;
#pragma unroll
  for (int j = 0; j < 8; j++) ones[j] = (__bf16)1.0f;

  const size_t kbase =
      (size_t)(b * S_LEN) * QKV_LD + 2048 + hk * H_D + dc;  // k cols
  const size_t vbase = (size_t)(hk * H_D + rr) * ROWS + b * S_LEN + dc;

  for (int sel = 0; sel < 2; ++sel) {
    const int qb = sel ? (15 - pair) : pair;  // q-block of 128 rows
    const int row0 = qb * 128;
    const int ktiles = 2 * qb + 2;

    // Q fragments: A/B-frag layout lane holds [l16][quad*8+j]; 16 rows/wave
    bf16x8 af[2];
    {
      const size_t qrow = (size_t)(b * S_LEN + row0 + wave * 16 + l16);
#pragma unroll
      for (int c = 0; c < 2; c++)
        af[c] =
            *(const bf16x8*)&qkv[qrow * QKV_LD + h * H_D + c * 32 + quad * 8];
    }

    f32x4 o_acc[4] = {};
    f32x4 l_acc = {};

    // Prefetch tile 0 into registers, then stage into LDS buffer 0.
    uint4 rk, rv;
    {
      rk = *(const uint4*)&qkv[kbase + (size_t)rr * QKV_LD];
      rv = *(const uint4*)&vT[vbase];
    }
    __syncthreads();  // prior-sel readers of LDS done before overwrite
    *(uint4*)&Ks[0][rr * 64 + (dc ^ sx)] = rk;
    *(uint4*)&Vt[0][rr * 64 + (dc ^ sx)] = rv;

    int cur = 0;
    for (int kt = 0; kt < ktiles; ++kt) {
      // Prefetch next tile while this tile computes.
      if (kt + 1 < ktiles) {
        rk = *(const uint4*)&qkv[kbase + (size_t)((kt + 1) * 64 + rr) * QKV_LD];
        rv = *(const uint4*)&vT[vbase + (size_t)(kt + 1) * 64];
      }
      __syncthreads();  // LDS[cur] fully staged by all waves

      // S^T strips: D[row=k(quad*4+e), col=q(l16)] = mfma(K-frag, Q-frag).
      f32x4 sacc[4];
#pragma unroll
      for (int n = 0; n < 4; n++) {
        f32x4 z = {};
#pragma unroll
        for (int c = 0; c < 2; c++) {
          const bf16x8 bk = *(const bf16x8*)&Ks[cur][(n * 16 + l16) * 64 +
                                                     ((c * 32 + quad * 8) ^ rx)];
          z = __builtin_amdgcn_mfma_f32_16x16x32_bf16(bk, af[c], z, 0, 0, 0);
        }
        sacc[n] = z;
      }

      // pe = exp2(s); truncate to bf16; masked -> 0; packed b64 store to Ps.
      const bool maybe_mask = (kt >= 2 * qb);
      const int krel0 = (kt - 2 * qb) * 64;  // valid only when maybe_mask
      {
        const int qn = wave * 16 + l16;  // relative q row of this lane
        const int prow = l16 * 64;
#pragma unroll
        for (int n = 0; n < 4; n++) {
          const int kb0 = krel0 + n * 16 + quad * 4;  // relative k of e=0
          float pe[4];
#pragma unroll
          for (int e = 0; e < 4; e++) {
            float v = exp2f(sacc[n][e]);
            if (maybe_mask && (kb0 + e > qn)) v = 0.f;
            pe[e] = v;
          }
          uint2 u;
          u.x = (__float_as_uint(pe[0]) >> 16) |
                (__float_as_uint(pe[1]) & 0xFFFF0000u);
          u.y = (__float_as_uint(pe[2]) >> 16) |
                (__float_as_uint(pe[3]) & 0xFFFF0000u);
          *(uint2*)&Ps[wave][prow + ((n * 16 + quad * 4) ^ rx)] = u;
        }
      }
      // wave-private Ps: compiler inserts lgkmcnt wait; no barrier needed

      bf16x8 pf[2];
#pragma unroll
      for (int c = 0; c < 2; c++)
        pf[c] = *(const bf16x8*)&Ps[wave][l16 * 64 +
                                          ((c * 32 + quad * 8) ^ rx)];
      // l row-sums via MFMA against ones (replicated over cols).
#pragma unroll
      for (int c = 0; c < 2; c++)
        l_acc = __builtin_amdgcn_mfma_f32_16x16x32_bf16(pf[c], ones, l_acc,
                                                        0, 0, 0);
#pragma unroll
      for (int n = 0; n < 4; n++)
#pragma unroll
        for (int c = 0; c < 2; c++) {
          const bf16x8 bv = *(const bf16x8*)&Vt[cur][(n * 16 + l16) * 64 +
                                                     ((c * 32 + quad * 8) ^ rx)];
          o_acc[n] = __builtin_amdgcn_mfma_f32_16x16x32_bf16(pf[c], bv,
                                                             o_acc[n], 0, 0, 0);
        }

      // Stage prefetched tile into the other buffer (swizzled writes).
      if (kt + 1 < ktiles) {
        const int nxt = cur ^ 1;
        *(uint4*)&Ks[nxt][rr * 64 + (dc ^ sx)] = rk;
        *(uint4*)&Vt[nxt][rr * 64 + (dc ^ sx)] = rv;
      }
      cur ^= 1;
    }

    // Epilogue: l already reduced by MFMA; normalize, store bf16 (in-place q).
#pragma unroll
    for (int e = 0; e < 4; e++) {
      const float inv = 1.f / l_acc[e];
      const size_t row =
          (size_t)(b * S_LEN + row0 + wave * 16 + quad * 4 + e);
#pragma unroll
      for (int n = 0; n < 4; n++)
        ao[row * QKV_LD + h * H_D + n * 16 + l16] = f2bf(o_acc[n][e] * inv);
    }
  }
}

#define LK 72  // padded inner stride for fallback attention

// ---------------------------------------------------------------------------
// Round-4 attention (fallback path only): k/v separate buffers stride 512.
// ---------------------------------------------------------------------------
__global__ __launch_bounds__(256) void attn_mfma_k(
    const unsigned short* __restrict__ q, const unsigned short* __restrict__ k,
    const unsigned short* __restrict__ v, unsigned short* __restrict__ ao) {
  const int qt = blockIdx.x, h = blockIdx.y, b = blockIdx.z;
  const int hk = h >> 2;
  const int tid = threadIdx.x;
  const int wave = tid >> 6;
  const int l16 = tid & 15;
  const int quad = (tid & 63) >> 4;

  __shared__ __align__(16) unsigned short Ks[64 * LK];
  __shared__ __align__(16) unsigned short Vt[64 * LK];
  __shared__ __align__(16) unsigned short Ps[64 * LK];

  bf16x8 af[2];
  {
    const size_t qrow = (size_t)(b * S_LEN + qt * 64 + wave * 16 + l16);
#pragma unroll
    for (int c = 0; c < 2; c++)
      af[c] = *(const bf16x8*)&q[qrow * DMODEL + h * H_D + c * 32 + quad * 8];
  }

  f32x4 o_acc[4] = {};
  float m_i[4], l_i[4];
#pragma unroll
  for (int e = 0; e < 4; e++) { m_i[e] = -INFINITY; l_i[e] = 0.f; }

  for (int kt = 0; kt <= qt; ++kt) {
    const int kb = kt * 64;
    __syncthreads();
    {
      const int kr = tid >> 2;
      const int dc = (tid & 3) * 16;
      const size_t gro = (size_t)(b * S_LEN + kb + kr) * (N_KV * H_D) + hk * H_D + dc;
      *(uint4*)&Ks[kr * LK + dc] = *(const uint4*)&k[gro];
      *(uint4*)&Ks[kr * LK + dc + 8] = *(const uint4*)&k[gro + 8];
      union { unsigned short u[8]; uint4 v; } w0, w1;
      w0.v = *(const uint4*)&v[gro];
      w1.v = *(const uint4*)&v[gro + 8];
#pragma unroll
      for (int j = 0; j < 8; j++) Vt[(dc + j) * LK + kr] = w0.u[j];
#pragma unroll
      for (int j = 0; j < 8; j++) Vt[(dc + 8 + j) * LK + kr] = w1.u[j];
    }
    __syncthreads();

    f32x4 sacc[4];
#pragma unroll
    for (int n = 0; n < 4; n++) {
      f32x4 z = {};
#pragma unroll
      for (int c = 0; c < 2; c++) {
        const bf16x8 bk = *(const bf16x8*)&Ks[(n * 16 + l16) * LK + c * 32 + quad * 8];
        z = __builtin_amdgcn_mfma_f32_16x16x32_bf16(af[c], bk, z, 0, 0, 0);
      }
      sacc[n] = z;
    }

    float p[4][4], mnew[4];
#pragma unroll
    for (int e = 0; e < 4; e++) mnew[e] = m_i[e];
#pragma unroll
    for (int n = 0; n < 4; n++)
#pragma unroll
      for (int e = 0; e < 4; e++) {
        float s = sacc[n][e] * 0.125f;
        if (kt == qt && (n * 16 + l16) > (wave * 16 + quad * 4 + e))
          s = -INFINITY;
        p[n][e] = s;
        mnew[e] = fmaxf(mnew[e], s);
      }
#pragma unroll
    for (int e = 0; e < 4; e++) {
      mnew[e] = fmaxf(mnew[e], __shfl_xor(mnew[e], 1));
      mnew[e] = fmaxf(mnew[e], __shfl_xor(mnew[e], 2));
      mnew[e] = fmaxf(mnew[e], __shfl_xor(mnew[e], 4));
      mnew[e] = fmaxf(mnew[e], __shfl_xor(mnew[e], 8));
      const float alpha = __expf(m_i[e] - mnew[e]);
      m_i[e] = mnew[e];
      l_i[e] *= alpha;
#pragma unroll
      for (int n = 0; n < 4; n++) o_acc[n][e] *= alpha;
    }
#pragma unroll
    for (int n = 0; n < 4; n++)
#pragma unroll
      for (int e = 0; e < 4; e++) {
        const float pe = __expf(p[n][e] - m_i[e]);
        p[n][e] = pe;
        l_i[e] += pe;
      }

#pragma unroll
    for (int n = 0; n < 4; n++)
#pragma unroll
      for (int e = 0; e < 4; e++)
        Ps[(wave * 16 + quad * 4 + e) * LK + n * 16 + l16] = f2bf(p[n][e]);
    __syncthreads();

    bf16x8 pf[2];
#pragma unroll
    for (int c = 0; c < 2; c++)
      pf[c] = *(const bf16x8*)&Ps[(wave * 16 + l16) * LK + c * 32 + quad * 8];
#pragma unroll
    for (int n = 0; n < 4; n++)
#pragma unroll
      for (int c = 0; c < 2; c++) {
        const bf16x8 bv = *(const bf16x8*)&Vt[(n * 16 + l16) * LK + c * 32 + quad * 8];
        o_acc[n] = __builtin_amdgcn_mfma_f32_16x16x32_bf16(pf[c], bv, o_acc[n], 0, 0, 0);
      }
  }

#pragma unroll
  for (int e = 0; e < 4; e++) {
    l_i[e] += __shfl_xor(l_i[e], 1);
    l_i[e] += __shfl_xor(l_i[e], 2);
    l_i[e] += __shfl_xor(l_i[e], 4);
    l_i[e] += __shfl_xor(l_i[e], 8);
    const float inv = 1.f / l_i[e];
    const size_t row = (size_t)(b * S_LEN + qt * 64 + wave * 16 + quad * 4 + e);
#pragma unroll
    for (int n = 0; n < 4; n++)
      ao[row * DMODEL + h * H_D + n * 16 + l16] = f2bf(o_acc[n][e] * inv);
  }
}

// ---------------------------------------------------------------------------
extern "C" void kernel_launch(void* const* d_in, const int* in_sizes, int n_in,
                              void* d_out, int out_size, void* d_ws, size_t ws_size,
                              hipStream_t stream) {
  const float* x = (const float*)d_in[0];
  const float* fc = (const float*)d_in[1];
  const float* fs = (const float*)d_in[2];
  const float* wq = (const float*)d_in[3];
  const float* wk = (const float*)d_in[4];
  const float* wv = (const float*)d_in[5];
  const float* wo = (const float*)d_in[6];

  char* ws = (char*)d_ws;
  const dim3 b256(256);

  if (ws_size >= (64ull << 20)) {
    // Fast path (64 MB):
    //   qkv   bf16 [4096][3072] @ 0     (24 MB)  q|k|v fused; attn out in q cols
    //   xb    bf16 [4096][2048] @ 24 MB (16 MB)
    //   wqkvT bf16 [3072][2048] @ 40 MB (12 MB)
    //   woT   bf16 [2048][2048] @ 52 MB ( 8 MB)
    //   vT    bf16 [ 512][4096] @ 60 MB ( 4 MB)
    unsigned short* qkv = (unsigned short*)(ws);
    unsigned short* xb = (unsigned short*)(ws + (24ull << 20));
    unsigned short* wqkvT = (unsigned short*)(ws + (40ull << 20));
    unsigned short* woT = (unsigned short*)(ws + (52ull << 20));
    unsigned short* vT = (unsigned short*)(ws + (60ull << 20));

    prep_all_k<<<dim3(64, 64, 5), b256, 0, stream>>>(x, wq, wk, wv, wo, xb,
                                                     wqkvT, woT);

    // Fused QKV projection, 8-phase 256^2: [4096][2048]@[3072][2048]^T
    gemm8_bt_k<1><<<dim3(16, 12), dim3(512), 0, stream>>>(xb, wqkvT, qkv, 4096,
                                                          3072, 2048, 2048);

    // RoPE (q pre-scaled by log2e/8, k plain) + v -> vT transpose, fused
    rope_vt_k<<<dim3(20480 + 2048), b256, 0, stream>>>(qkv, vT, fc, fs);

    // Paired 8-wave attention (v8): 512 blocks x 512 thr, 2 blocks/CU.
    attn_mfma8_k<<<dim3(8, N_H, 2), dim3(512), 0, stream>>>(qkv, vT, qkv);

    // Output projection, 8-phase 256^2 (A = qkv q-cols, lda=3072) -> fp32
    gemm8_bt_k<0><<<dim3(16, 8), dim3(512), 0, stream>>>(qkv, woT, d_out, 4096,
                                                         2048, 2048, QKV_LD);
  } else {
    // Round-4 fallback (<= 40 MB)
    unsigned short* q = (unsigned short*)(ws);
    unsigned short* k = (unsigned short*)(ws + (16ull << 20));
    unsigned short* v = (unsigned short*)(ws + (20ull << 20));
    unsigned short* xb = (unsigned short*)(ws + (24ull << 20));
    const bool have_xb = ws_size >= (40ull << 20);

    if (have_xb) {
      cvt_bf16_k<<<dim3(ROWS * DMODEL / (256 * 8)), b256, 0, stream>>>(x, xb);
      gemm_k<0, 1><<<dim3(32, 16), b256, 0, stream>>>(xb, wq, q, 4096, 2048, 2048);
      gemm_k<0, 1><<<dim3(32, 4), b256, 0, stream>>>(xb, wk, k, 4096, 512, 2048);
      gemm_k<0, 1><<<dim3(32, 4), b256, 0, stream>>>(xb, wv, v, 4096, 512, 2048);
    } else {
      gemm_k<1, 1><<<dim3(32, 16), b256, 0, stream>>>(x, wq, q, 4096, 2048, 2048);
      gemm_k<1, 1><<<dim3(32, 4), b256, 0, stream>>>(x, wk, k, 4096, 512, 2048);
      gemm_k<1, 1><<<dim3(32, 4), b256, 0, stream>>>(x, wv, v, 4096, 512, 2048);
    }

    rope_k<<<dim3(20480), b256, 0, stream>>>(q, k, fc, fs, N_H * H_D, N_KV * H_D);
    attn_mfma_k<<<dim3(S_LEN / 64, N_H, 2), b256, 0, stream>>>(q, k, v, q);
    gemm_k<0, 0><<<dim3(32, 16), b256, 0, stream>>>(q, wo, d_out, 4096, 2048, 2048);
  }
}

// Round 8
// 296.908 us; speedup vs baseline: 1.1397x; 1.0185x over previous
//
#include <hip/hip_runtime.h>
#include <hip/hip_bf16.h>

// Problem constants (B=2, S=2048, D=2048, NH=32, NKV=8, HD=64, NREP=4)
#define S_LEN 2048
#define DMODEL 2048
#define N_H 32
#define N_KV 8
#define H_D 64
#define ROWS 4096   // B*S
#define QKV_LD 3072 // fused qkv row stride: q[0:2048) k[2048:2560) v[2560:3072)

typedef __bf16 bf16x8 __attribute__((ext_vector_type(8)));
typedef float f32x4 __attribute__((ext_vector_type(4)));

// fp32 -> bf16 raw bits, round-to-nearest-even
static __device__ __forceinline__ unsigned short f2bf(float f) {
  unsigned int u = __float_as_uint(f);
  u += 0x7FFFu + ((u >> 16) & 1u);
  return (unsigned short)(u >> 16);
}
static __device__ __forceinline__ float bf2f(unsigned short s) {
  return __uint_as_float((unsigned int)s << 16);
}

// async global->LDS, 16 B per lane. LDS dest = wave-uniform base + lane*16.
static __device__ __forceinline__ void async16(const void* g, void* l) {
  __builtin_amdgcn_global_load_lds(
      (const __attribute__((address_space(1))) unsigned int*)g,
      (__attribute__((address_space(3))) unsigned int*)l, 16, 0, 0);
}

// counted vmcnt + raw barrier (T4): loads stay in flight across the barrier.
#define VMB(N)                                                    \
  do {                                                            \
    asm volatile("s_waitcnt vmcnt(" #N ")" ::: "memory");         \
    __builtin_amdgcn_s_barrier();                                 \
    asm volatile("" ::: "memory");                                \
  } while (0)

// ---------------------------------------------------------------------------
// fp32 -> bf16 bulk convert (8 elems/thread) — fallback path only
// ---------------------------------------------------------------------------
__global__ __launch_bounds__(256) void cvt_bf16_k(
    const float* __restrict__ in, unsigned short* __restrict__ out) {
  const size_t i = ((size_t)blockIdx.x * 256 + threadIdx.x) * 8;
  const float4 a = *(const float4*)&in[i];
  const float4 b = *(const float4*)&in[i + 4];
  union { unsigned short u[8]; uint4 v; } p;
  p.u[0] = f2bf(a.x); p.u[1] = f2bf(a.y); p.u[2] = f2bf(a.z); p.u[3] = f2bf(a.w);
  p.u[4] = f2bf(b.x); p.u[5] = f2bf(b.y); p.u[6] = f2bf(b.z); p.u[7] = f2bf(b.w);
  *(uint4*)&out[i] = p.v;
}

// ---------------------------------------------------------------------------
// Combined prep: z=0..3 transpose fp32 weights -> bf16 wqkvT/woT blocks;
// z=4: straight cvt x fp32 -> xb bf16 (64x64 blocks x 256 thr x 8 elems).
// ---------------------------------------------------------------------------
__global__ __launch_bounds__(256) void prep_all_k(
    const float* __restrict__ x, const float* __restrict__ wq,
    const float* __restrict__ wk, const float* __restrict__ wv,
    const float* __restrict__ wo, unsigned short* __restrict__ xb,
    unsigned short* __restrict__ wqkvT, unsigned short* __restrict__ woT) {
  const int z = blockIdx.z;
  if (z == 4) {
    const size_t i =
        (((size_t)blockIdx.y * 64 + blockIdx.x) * 256 + threadIdx.x) * 8;
    const float4 a = *(const float4*)&x[i];
    const float4 b = *(const float4*)&x[i + 4];
    union { unsigned short u[8]; uint4 v; } p;
    p.u[0] = f2bf(a.x); p.u[1] = f2bf(a.y); p.u[2] = f2bf(a.z); p.u[3] = f2bf(a.w);
    p.u[4] = f2bf(b.x); p.u[5] = f2bf(b.y); p.u[6] = f2bf(b.z); p.u[7] = f2bf(b.w);
    *(uint4*)&xb[i] = p.v;
    return;
  }
  const float* in;
  unsigned short* out;
  int C;
  if (z == 0)      { in = wq; out = wqkvT;                  C = 2048; }
  else if (z == 1) { in = wk; out = wqkvT + 2048ull * 2048; C = 512;  }
  else if (z == 2) { in = wv; out = wqkvT + 2560ull * 2048; C = 512;  }
  else             { in = wo; out = woT;                    C = 2048; }
  if (blockIdx.x * 32 >= C) return;

  __shared__ unsigned short tile[32][33];
  const int tx = threadIdx.x & 31;
  const int ty = threadIdx.x >> 5;
  const int r0 = blockIdx.y * 32;  // K rows of input
  const int c0 = blockIdx.x * 32;  // C cols of input
#pragma unroll
  for (int i = 0; i < 32; i += 8)
    tile[ty + i][tx] = f2bf(in[(size_t)(r0 + ty + i) * C + c0 + tx]);
  __syncthreads();
#pragma unroll
  for (int i = 0; i < 32; i += 8)
    out[(size_t)(c0 + ty + i) * 2048 + r0 + tx] = tile[tx][ty + i];
}

// log2(e) / sqrt(HD): softmax base-2 conversion + 1/sqrt(d), folded into q
#define SCALE_LOG2E 0.18033688011112042f

// ---------------------------------------------------------------------------
// Fused RoPE (blocks 0..20479) + v->vT transpose (blocks 20480..22527).
// ---------------------------------------------------------------------------
__global__ __launch_bounds__(256) void rope_vt_k(
    unsigned short* __restrict__ qkv, unsigned short* __restrict__ vT,
    const float* __restrict__ fc, const float* __restrict__ fs) {
  const int blk = blockIdx.x;
  if (blk < 20480) {
    const int PQ = ROWS * N_H * (H_D / 2);   // 4194304
    const int PK = ROWS * N_KV * (H_D / 2);  // 1048576
    const int idx = blk * 256 + threadIdx.x;
    if (idx >= PQ + PK) return;
    unsigned short* base;
    float c, sn;
    bool isq;
    if (idx < PQ) {
      const int i = idx & 31;
      const int h = (idx >> 5) & 31;
      const int row = idx >> 10;
      const int s = row & (S_LEN - 1);
      c = fc[s * 32 + i];
      sn = fs[s * 32 + i];
      base = qkv + (size_t)row * QKV_LD + h * H_D + 2 * i;
      isq = true;
    } else {
      const int p = idx - PQ;
      const int i = p & 31;
      const int h = (p >> 5) & 7;
      const int row = p >> 8;
      const int s = row & (S_LEN - 1);
      c = fc[s * 32 + i];
      sn = fs[s * 32 + i];
      base = qkv + (size_t)row * QKV_LD + 2048 + h * H_D + 2 * i;
      isq = false;
    }
    const float x0 = bf2f(base[0]);
    const float x1 = bf2f(base[1]);
    const float sc = isq ? SCALE_LOG2E : 1.0f;
    base[0] = f2bf((x0 * c - x1 * sn) * sc);
    base[1] = f2bf((x0 * sn + x1 * c) * sc);
  } else {
    __shared__ unsigned short tile[32][33];
    const int t = blk - 20480;        // 0..2047
    const int bx = t & 15;            // C/32 = 16
    const int by = t >> 4;            // R/32 = 128
    const unsigned short* in = qkv + 2560;
    const int tx = threadIdx.x & 31;
    const int ty = threadIdx.x >> 5;
    const int r0 = by * 32;
    const int c0 = bx * 32;
#pragma unroll
    for (int i = 0; i < 32; i += 8)
      tile[ty + i][tx] = in[(size_t)(r0 + ty + i) * QKV_LD + c0 + tx];
    __syncthreads();
#pragma unroll
    for (int i = 0; i < 32; i += 8)
      vT[(size_t)(c0 + ty + i) * ROWS + r0 + tx] = tile[tx][ty + i];
  }
}

// ---------------------------------------------------------------------------
// gemm8: 8-phase deep-pipelined 256x256 MFMA GEMM (T2+T3+T4+T5).
// Verified correct + faster in round 7. See ledger comments below.
// ---------------------------------------------------------------------------
template <int STORE_BF16>
__global__ __launch_bounds__(512, 2) void gemm8_bt_k(
    const unsigned short* __restrict__ A, const unsigned short* __restrict__ BT,
    void* __restrict__ Cp, int M, int N, int K, int lda) {
  __shared__ __align__(16) unsigned short As[2][2][128 * 64];
  __shared__ __align__(16) unsigned short Bs[2][2][128 * 64];
  const int tid = threadIdx.x;
  const int wave = tid >> 6;
  const int lane = tid & 63;
  const int quad = lane >> 4;
  const int l16 = lane & 15;
  const int nwg = gridDim.x * gridDim.y;
  const int flat = blockIdx.y * gridDim.x + blockIdx.x;
  const int swz = (flat & 7) * (nwg >> 3) + (flat >> 3);
  const int m0 = (swz % gridDim.x) * 256;
  const int n0 = (swz / gridDim.x) * 256;
  const int ah = wave & 1;
  const int ag = wave >> 1;
  const int bh = wave >> 2;
  const int bg = wave & 3;
  const int bl = (ag & 1) * 64;
  const int rx = (l16 & 7) << 3;
  const int scol = ((lane & 7) * 8) ^ ((lane >> 3) << 3);
  const int srA = 8 * ag + (lane >> 3);
  const int srB = 8 * bg + (lane >> 3);
  const size_t abase = (size_t)(m0 + ah * 128) * lda;
  const size_t bbase = (size_t)(n0 + bh * 128) * K;
  f32x4 acc[8][4] = {};

#define STG_B(j, buf, kt)                                             \
  async16(&BT[bbase + (size_t)(32 * (j) + srB) * K + (kt) + scol],    \
          &Bs[buf][bh][(32 * (j) + 8 * bg) * 64])
#define STG_A(j, buf, kt)                                             \
  async16(&A[abase + (size_t)(32 * (j) + srA) * lda + (kt) + scol],   \
          &As[buf][ah][(32 * (j) + 8 * ag) * 64])

  STG_B(0, 0, 0); STG_B(1, 0, 0); STG_B(2, 0, 0); STG_B(3, 0, 0);
  STG_A(0, 0, 0); STG_A(1, 0, 0); STG_A(2, 0, 0); STG_A(3, 0, 0);

  const int NT = K >> 6;
  for (int t = 0; t < NT; ++t) {
    const int cur = t & 1, nxt = cur ^ 1;
    const int ktn = (t + 1 < NT) ? ((t + 1) << 6) : 0;
    const unsigned short* Ac = &As[cur][ah][0];
    const unsigned short* Bc = &Bs[cur][bh][0];
    bf16x8 bf[4][2];

    VMB(3);
    {
      bf16x8 af[2][2];
#pragma unroll
      for (int n = 0; n < 4; n++)
#pragma unroll
        for (int kk = 0; kk < 2; kk++)
          bf[n][kk] = *(const bf16x8*)&Bc[(bl + n * 16 + l16) * 64 +
                                          ((kk * 32 + quad * 8) ^ rx)];
#pragma unroll
      for (int i = 0; i < 2; i++)
#pragma unroll
        for (int kk = 0; kk < 2; kk++)
          af[i][kk] = *(const bf16x8*)&Ac[((0 + i) * 16 + l16) * 64 +
                                          ((kk * 32 + quad * 8) ^ rx)];
      STG_B(0, nxt, ktn); STG_B(1, nxt, ktn);
      __builtin_amdgcn_s_setprio(1);
#pragma unroll
      for (int i = 0; i < 2; i++)
#pragma unroll
        for (int n = 0; n < 4; n++)
#pragma unroll
          for (int kk = 0; kk < 2; kk++)
            acc[0 + i][n] = __builtin_amdgcn_mfma_f32_16x16x32_bf16(
                af[i][kk], bf[n][kk], acc[0 + i][n], 0, 0, 0);
      __builtin_amdgcn_s_setprio(0);
    }

    VMB(4);
    {
      bf16x8 af[2][2];
#pragma unroll
      for (int i = 0; i < 2; i++)
#pragma unroll
        for (int kk = 0; kk < 2; kk++)
          af[i][kk] = *(const bf16x8*)&Ac[((2 + i) * 16 + l16) * 64 +
                                          ((kk * 32 + quad * 8) ^ rx)];
      STG_B(2, nxt, ktn); STG_B(3, nxt, ktn);
      __builtin_amdgcn_s_setprio(1);
#pragma unroll
      for (int i = 0; i < 2; i++)
#pragma unroll
        for (int n = 0; n < 4; n++)
#pragma unroll
          for (int kk = 0; kk < 2; kk++)
            acc[2 + i][n] = __builtin_amdgcn_mfma_f32_16x16x32_bf16(
                af[i][kk], bf[n][kk], acc[2 + i][n], 0, 0, 0);
      __builtin_amdgcn_s_setprio(0);
    }

    VMB(5);
    {
      bf16x8 af[2][2];
#pragma unroll
      for (int i = 0; i < 2; i++)
#pragma unroll
        for (int kk = 0; kk < 2; kk++)
          af[i][kk] = *(const bf16x8*)&Ac[((4 + i) * 16 + l16) * 64 +
                                          ((kk * 32 + quad * 8) ^ rx)];
      STG_A(0, nxt, ktn); STG_A(1, nxt, ktn);
      __builtin_amdgcn_s_setprio(1);
#pragma unroll
      for (int i = 0; i < 2; i++)
#pragma unroll
        for (int n = 0; n < 4; n++)
#pragma unroll
          for (int kk = 0; kk < 2; kk++)
            acc[4 + i][n] = __builtin_amdgcn_mfma_f32_16x16x32_bf16(
                af[i][kk], bf[n][kk], acc[4 + i][n], 0, 0, 0);
      __builtin_amdgcn_s_setprio(0);
    }

    VMB(6);
    {
      bf16x8 af[2][2];
#pragma unroll
      for (int i = 0; i < 2; i++)
#pragma unroll
        for (int kk = 0; kk < 2; kk++)
          af[i][kk] = *(const bf16x8*)&Ac[((6 + i) * 16 + l16) * 64 +
                                          ((kk * 32 + quad * 8) ^ rx)];
      STG_A(2, nxt, ktn); STG_A(3, nxt, ktn);
      __builtin_amdgcn_s_setprio(1);
#pragma unroll
      for (int i = 0; i < 2; i++)
#pragma unroll
        for (int n = 0; n < 4; n++)
#pragma unroll
          for (int kk = 0; kk < 2; kk++)
            acc[6 + i][n] = __builtin_amdgcn_mfma_f32_16x16x32_bf16(
                af[i][kk], bf[n][kk], acc[6 + i][n], 0, 0, 0);
      __builtin_amdgcn_s_setprio(0);
    }
  }
#undef STG_A
#undef STG_B

  const int wn = (wave >> 1) * 64;
#pragma unroll
  for (int f = 0; f < 8; f++) {
#pragma unroll
    for (int e = 0; e < 4; e++) {
      const int mrow = m0 + ah * 128 + f * 16 + quad * 4 + e;
#pragma unroll
      for (int n = 0; n < 4; n++) {
        const int ncol = n0 + wn + n * 16 + l16;
        const float val = acc[f][n][e];
        if (STORE_BF16) {
          ((unsigned short*)Cp)[(size_t)mrow * N + ncol] = f2bf(val);
        } else {
          ((float*)Cp)[(size_t)mrow * N + ncol] = val;
        }
      }
    }
  }
}

// ---------------------------------------------------------------------------
// gemm8n: 8-phase GEMM, BM=256 x BN=128 variant — full-CU grids for shapes
// where 256^2 underfills (WO: (16,16)=256 blocks = 1/CU vs 128 = 50% idle).
// Per wave: 6 issues [B0,B1,A0..A3] (B panel 128 rows = 2 stage-instrs).
// Ledger (per wave; identical vmcnt constants to gemm8_bt_k):
//   ph0: [B0,B1,A0,A1,A2,A3](6)       vmcnt(3) -> B all + A0
//   ph1: [A1,A2,A3,B0',B1'](5)        vmcnt(4) -> A1
//   ph2: [A2,A3,B0',B1',A0',A1'](6)   vmcnt(5) -> A2
//   ph3: [A3,B0'..A3'](7)             vmcnt(6) -> A3
// Cross-wave safety: same wait+barrier argument as gemm8_bt_k.
// Per-wave output 128x32 (acc[8][2]); wn=(wave>>1)*32, ah=wave&1.
// LDS 96 KiB. T2 swizzle identical (same involution both sides).
// ---------------------------------------------------------------------------
template <int STORE_BF16>
__global__ __launch_bounds__(512, 2) void gemm8n_bt_k(
    const unsigned short* __restrict__ A, const unsigned short* __restrict__ BT,
    void* __restrict__ Cp, int M, int N, int K, int lda) {
  __shared__ __align__(16) unsigned short As[2][2][128 * 64];
  __shared__ __align__(16) unsigned short Bs[2][128 * 64];
  const int tid = threadIdx.x;
  const int wave = tid >> 6;
  const int lane = tid & 63;
  const int quad = lane >> 4;
  const int l16 = lane & 15;
  const int nwg = gridDim.x * gridDim.y;
  const int flat = blockIdx.y * gridDim.x + blockIdx.x;
  const int swz = (flat & 7) * (nwg >> 3) + (flat >> 3);
  const int m0 = (swz % gridDim.x) * 256;
  const int n0 = (swz / gridDim.x) * 128;
  const int ah = wave & 1;
  const int ag = wave >> 1;
  const int wn = (wave >> 1) * 32;    // per-wave N strip (0,32,64,96)
  const int rx = (l16 & 7) << 3;
  const int scol = ((lane & 7) * 8) ^ ((lane >> 3) << 3);
  const int srA = 8 * ag + (lane >> 3);
  const int srB = 8 * wave + (lane >> 3);  // B row within 64-row group
  const size_t abase = (size_t)(m0 + ah * 128) * lda;
  const size_t bbase = (size_t)n0 * K;
  f32x4 acc[8][2] = {};

#define STG_B(j, buf, kt)                                             \
  async16(&BT[bbase + (size_t)(64 * (j) + srB) * K + (kt) + scol],    \
          &Bs[buf][(64 * (j) + 8 * wave) * 64])
#define STG_A(j, buf, kt)                                             \
  async16(&A[abase + (size_t)(32 * (j) + srA) * lda + (kt) + scol],   \
          &As[buf][ah][(32 * (j) + 8 * ag) * 64])

  STG_B(0, 0, 0); STG_B(1, 0, 0);
  STG_A(0, 0, 0); STG_A(1, 0, 0); STG_A(2, 0, 0); STG_A(3, 0, 0);

  const int NT = K >> 6;
  for (int t = 0; t < NT; ++t) {
    const int cur = t & 1, nxt = cur ^ 1;
    const int ktn = (t + 1 < NT) ? ((t + 1) << 6) : 0;
    const unsigned short* Ac = &As[cur][ah][0];
    const unsigned short* Bc = &Bs[cur][0];
    bf16x8 bf[2][2];

    VMB(3);
    {
      bf16x8 af[2][2];
#pragma unroll
      for (int n = 0; n < 2; n++)
#pragma unroll
        for (int kk = 0; kk < 2; kk++)
          bf[n][kk] = *(const bf16x8*)&Bc[(wn + n * 16 + l16) * 64 +
                                          ((kk * 32 + quad * 8) ^ rx)];
#pragma unroll
      for (int i = 0; i < 2; i++)
#pragma unroll
        for (int kk = 0; kk < 2; kk++)
          af[i][kk] = *(const bf16x8*)&Ac[((0 + i) * 16 + l16) * 64 +
                                          ((kk * 32 + quad * 8) ^ rx)];
      STG_B(0, nxt, ktn); STG_B(1, nxt, ktn);
      __builtin_amdgcn_s_setprio(1);
#pragma unroll
      for (int i = 0; i < 2; i++)
#pragma unroll
        for (int n = 0; n < 2; n++)
#pragma unroll
          for (int kk = 0; kk < 2; kk++)
            acc[0 + i][n] = __builtin_amdgcn_mfma_f32_16x16x32_bf16(
                af[i][kk], bf[n][kk], acc[0 + i][n], 0, 0, 0);
      __builtin_amdgcn_s_setprio(0);
    }

    VMB(4);
    {
      bf16x8 af[2][2];
#pragma unroll
      for (int i = 0; i < 2; i++)
#pragma unroll
        for (int kk = 0; kk < 2; kk++)
          af[i][kk] = *(const bf16x8*)&Ac[((2 + i) * 16 + l16) * 64 +
                                          ((kk * 32 + quad * 8) ^ rx)];
      STG_A(0, nxt, ktn); STG_A(1, nxt, ktn);
      __builtin_amdgcn_s_setprio(1);
#pragma unroll
      for (int i = 0; i < 2; i++)
#pragma unroll
        for (int n = 0; n < 2; n++)
#pragma unroll
          for (int kk = 0; kk < 2; kk++)
            acc[2 + i][n] = __builtin_amdgcn_mfma_f32_16x16x32_bf16(
                af[i][kk], bf[n][kk], acc[2 + i][n], 0, 0, 0);
      __builtin_amdgcn_s_setprio(0);
    }

    VMB(5);
    {
      bf16x8 af[2][2];
#pragma unroll
      for (int i = 0; i < 2; i++)
#pragma unroll
        for (int kk = 0; kk < 2; kk++)
          af[i][kk] = *(const bf16x8*)&Ac[((4 + i) * 16 + l16) * 64 +
                                          ((kk * 32 + quad * 8) ^ rx)];
      STG_A(2, nxt, ktn); STG_A(3, nxt, ktn);
      __builtin_amdgcn_s_setprio(1);
#pragma unroll
      for (int i = 0; i < 2; i++)
#pragma unroll
        for (int n = 0; n < 2; n++)
#pragma unroll
          for (int kk = 0; kk < 2; kk++)
            acc[4 + i][n] = __builtin_amdgcn_mfma_f32_16x16x32_bf16(
                af[i][kk], bf[n][kk], acc[4 + i][n], 0, 0, 0);
      __builtin_amdgcn_s_setprio(0);
    }

    VMB(6);
    {
      bf16x8 af[2][2];
#pragma unroll
      for (int i = 0; i < 2; i++)
#pragma unroll
        for (int kk = 0; kk < 2; kk++)
          af[i][kk] = *(const bf16x8*)&Ac[((6 + i) * 16 + l16) * 64 +
                                          ((kk * 32 + quad * 8) ^ rx)];
      __builtin_amdgcn_s_setprio(1);
#pragma unroll
      for (int i = 0; i < 2; i++)
#pragma unroll
        for (int n = 0; n < 2; n++)
#pragma unroll
          for (int kk = 0; kk < 2; kk++)
            acc[6 + i][n] = __builtin_amdgcn_mfma_f32_16x16x32_bf16(
                af[i][kk], bf[n][kk], acc[6 + i][n], 0, 0, 0);
      __builtin_amdgcn_s_setprio(0);
    }
  }
#undef STG_A
#undef STG_B

#pragma unroll
  for (int f = 0; f < 8; f++) {
#pragma unroll
    for (int e = 0; e < 4; e++) {
      const int mrow = m0 + ah * 128 + f * 16 + quad * 4 + e;
#pragma unroll
      for (int n = 0; n < 2; n++) {
        const int ncol = n0 + wn + n * 16 + l16;
        const float val = acc[f][n][e];
        if (STORE_BF16) {
          ((unsigned short*)Cp)[(size_t)mrow * N + ncol] = f2bf(val);
        } else {
          ((float*)Cp)[(size_t)mrow * N + ncol] = val;
        }
      }
    }
  }
}

// ---------------------------------------------------------------------------
// Fallback MFMA GEMM (round-4): C[M][N] = A[M][K] @ B[K][N], B fp32 native.
// ---------------------------------------------------------------------------
template <int AF32, int STORE_BF16>
__global__ __launch_bounds__(256) void gemm_k(
    const void* __restrict__ Ap, const float* __restrict__ B,
    void* __restrict__ Cp, int M, int N, int K) {
  constexpr int LDP = 40;
  __shared__ __align__(16) unsigned short As[128 * LDP];
  __shared__ __align__(16) unsigned short Bs[128 * LDP];
  const int tid = threadIdx.x;
  const int wave = tid >> 6;
  const int lane = tid & 63;
  const int quad = lane >> 4;
  const int l16 = lane & 15;
  const int m0 = blockIdx.x * 128;
  const int n0 = blockIdx.y * 128;
  const int wm = (wave >> 1) * 64;
  const int wn = (wave & 1) * 64;
  f32x4 acc[4][4] = {};

  for (int kt = 0; kt < K; kt += 32) {
    __syncthreads();
    if (AF32) {
      const float* A = (const float*)Ap;
      for (int c = tid; c < 1024; c += 256) {
        const int r = c >> 3;
        const int cc = (c & 7) << 2;
        const float4 w = *(const float4*)&A[(size_t)(m0 + r) * K + kt + cc];
        union { unsigned short u[4]; uint2 v; } p;
        p.u[0] = f2bf(w.x); p.u[1] = f2bf(w.y);
        p.u[2] = f2bf(w.z); p.u[3] = f2bf(w.w);
        *(uint2*)&As[r * LDP + cc] = p.v;
      }
    } else {
      const unsigned short* A = (const unsigned short*)Ap;
      for (int c = tid; c < 512; c += 256) {
        const int r = c >> 2;
        const int cc = (c & 3) << 3;
        *(uint4*)&As[r * LDP + cc] =
            *(const uint4*)&A[(size_t)(m0 + r) * K + kt + cc];
      }
    }
    for (int c = tid; c < 1024; c += 256) {
      const int kr = c >> 5;
      const int nc = (c & 31) << 2;
      const float4 w = *(const float4*)&B[(size_t)(kt + kr) * N + n0 + nc];
      Bs[(nc + 0) * LDP + kr] = f2bf(w.x);
      Bs[(nc + 1) * LDP + kr] = f2bf(w.y);
      Bs[(nc + 2) * LDP + kr] = f2bf(w.z);
      Bs[(nc + 3) * LDP + kr] = f2bf(w.w);
    }
    __syncthreads();
    bf16x8 af[4], bfr[4];
#pragma unroll
    for (int i = 0; i < 4; i++)
      af[i] = *(const bf16x8*)&As[(wm + i * 16 + l16) * LDP + quad * 8];
#pragma unroll
    for (int j = 0; j < 4; j++)
      bfr[j] = *(const bf16x8*)&Bs[(wn + j * 16 + l16) * LDP + quad * 8];
#pragma unroll
    for (int i = 0; i < 4; i++)
#pragma unroll
      for (int j = 0; j < 4; j++)
        acc[i][j] =
            __builtin_amdgcn_mfma_f32_16x16x32_bf16(af[i], bfr[j], acc[i][j], 0, 0, 0);
  }
#pragma unroll
  for (int i = 0; i < 4; i++) {
#pragma unroll
    for (int e = 0; e < 4; e++) {
      const int mrow = m0 + wm + i * 16 + quad * 4 + e;
#pragma unroll
      for (int j = 0; j < 4; j++) {
        const int ncol = n0 + wn + j * 16 + l16;
        const float val = acc[i][j][e];
        if (STORE_BF16) {
          ((unsigned short*)Cp)[(size_t)mrow * N + ncol] = f2bf(val);
        } else {
          ((float*)Cp)[(size_t)mrow * N + ncol] = val;
        }
      }
    }
  }
}

// ---------------------------------------------------------------------------
// Fallback RoPE (separate q/k buffers)
// ---------------------------------------------------------------------------
__global__ __launch_bounds__(256) void rope_k(
    unsigned short* __restrict__ q, unsigned short* __restrict__ kk,
    const float* __restrict__ fc, const float* __restrict__ fs,
    int qstride, int kstride) {
  const int PQ = ROWS * N_H * (H_D / 2);
  const int PK = ROWS * N_KV * (H_D / 2);
  const int idx = blockIdx.x * 256 + threadIdx.x;
  if (idx >= PQ + PK) return;
  unsigned short* base;
  float c, sn;
  if (idx < PQ) {
    const int i = idx & 31;
    const int h = (idx >> 5) & 31;
    const int row = idx >> 10;
    const int s = row & (S_LEN - 1);
    c = fc[s * 32 + i];
    sn = fs[s * 32 + i];
    base = q + (size_t)row * qstride + h * H_D + 2 * i;
  } else {
    const int p = idx - PQ;
    const int i = p & 31;
    const int h = (p >> 5) & 7;
    const int row = p >> 8;
    const int s = row & (S_LEN - 1);
    c = fc[s * 32 + i];
    sn = fs[s * 32 + i];
    base = kk + (size_t)row * kstride + h * H_D + 2 * i;
  }
  const float x0 = bf2f(base[0]);
  const float x1 = bf2f(base[1]);
  base[0] = f2bf(x0 * c - x1 * sn);
  base[1] = f2bf(x0 * sn + x1 * c);
}

// ---------------------------------------------------------------------------
// attn v8 (round-2 verified, 79.5 us — best config). 8-wave (512-thr) paired
// flash attention, 16 q-rows/wave, swapped-operand S^T, XOR-swizzled LDS,
// packed b64 P stores, NON-ONLINE softmax, l row-sums via ones-MFMA.
// ---------------------------------------------------------------------------
__global__ __launch_bounds__(512, 4) void attn_mfma8_k(
    const unsigned short* __restrict__ qkv, const unsigned short* __restrict__ vT,
    unsigned short* __restrict__ ao) {
  const int pair = blockIdx.x, h = blockIdx.y, b = blockIdx.z;
  const int hk = h >> 2;
  const int tid = threadIdx.x;
  const int wave = tid >> 6;      // 0..7
  const int l16 = tid & 15;
  const int quad = (tid & 63) >> 4;
  const int rr = tid >> 3;        // 0..63 staging row
  const int dc = (tid & 7) * 8;   // staging 8-elem (16B) chunk
  const int rx = (l16 & 7) << 3;  // read/P-side XOR (elem units)
  const int sx = (rr & 7) << 3;   // stage-side XOR

  __shared__ __align__(16) unsigned short Ks[2][64 * 64];  // [key][d] swz
  __shared__ __align__(16) unsigned short Vt[2][64 * 64];  // [d][key] swz
  __shared__ __align__(16) unsigned short Ps[8][16 * 64];  // wave-private swz

  bf16x8 ones;
#pragma unroll
  for (int j = 0; j < 8; j++) ones[j] = (__bf16)1.0f;

  const size_t kbase =
      (size_t)(b * S_LEN) * QKV_LD + 2048 + hk * H_D + dc;  // k cols
  const size_t vbase = (size_t)(hk * H_D + rr) * ROWS + b * S_LEN + dc;

  for (int sel = 0; sel < 2; ++sel) {
    const int qb = sel ? (15 - pair) : pair;  // q-block of 128 rows
    const int row0 = qb * 128;
    const int ktiles = 2 * qb + 2;

    // Q fragments: A/B-frag layout lane holds [l16][quad*8+j]; 16 rows/wave
    bf16x8 af[2];
    {
      const size_t qrow = (size_t)(b * S_LEN + row0 + wave * 16 + l16);
#pragma unroll
      for (int c = 0; c < 2; c++)
        af[c] =
            *(const bf16x8*)&qkv[qrow * QKV_LD + h * H_D + c * 32 + quad * 8];
    }

    f32x4 o_acc[4] = {};
    f32x4 l_acc = {};

    // Prefetch tile 0 into registers, then stage into LDS buffer 0.
    uint4 rk, rv;
    {
      rk = *(const uint4*)&qkv[kbase + (size_t)rr * QKV_LD];
      rv = *(const uint4*)&vT[vbase];
    }
    __syncthreads();  // prior-sel readers of LDS done before overwrite
    *(uint4*)&Ks[0][rr * 64 + (dc ^ sx)] = rk;
    *(uint4*)&Vt[0][rr * 64 + (dc ^ sx)] = rv;

    int cur = 0;
    for (int kt = 0; kt < ktiles; ++kt) {
      // Prefetch next tile while this tile computes.
      if (kt + 1 < ktiles) {
        rk = *(const uint4*)&qkv[kbase + (size_t)((kt + 1) * 64 + rr) * QKV_LD];
        rv = *(const uint4*)&vT[vbase + (size_t)(kt + 1) * 64];
      }
      __syncthreads();  // LDS[cur] fully staged by all waves

      // S^T strips: D[row=k(quad*4+e), col=q(l16)] = mfma(K-frag, Q-frag).
      f32x4 sacc[4];
#pragma unroll
      for (int n = 0; n < 4; n++) {
        f32x4 z = {};
#pragma unroll
        for (int c = 0; c < 2; c++) {
          const bf16x8 bk = *(const bf16x8*)&Ks[cur][(n * 16 + l16) * 64 +
                                                     ((c * 32 + quad * 8) ^ rx)];
          z = __builtin_amdgcn_mfma_f32_16x16x32_bf16(bk, af[c], z, 0, 0, 0);
        }
        sacc[n] = z;
      }

      // pe = exp2(s); truncate to bf16; masked -> 0; packed b64 store to Ps.
      const bool maybe_mask = (kt >= 2 * qb);
      const int krel0 = (kt - 2 * qb) * 64;  // valid only when maybe_mask
      {
        const int qn = wave * 16 + l16;  // relative q row of this lane
        const int prow = l16 * 64;
#pragma unroll
        for (int n = 0; n < 4; n++) {
          const int kb0 = krel0 + n * 16 + quad * 4;  // relative k of e=0
          float pe[4];
#pragma unroll
          for (int e = 0; e < 4; e++) {
            float v = exp2f(sacc[n][e]);
            if (maybe_mask && (kb0 + e > qn)) v = 0.f;
            pe[e] = v;
          }
          uint2 u;
          u.x = (__float_as_uint(pe[0]) >> 16) |
                (__float_as_uint(pe[1]) & 0xFFFF0000u);
          u.y = (__float_as_uint(pe[2]) >> 16) |
                (__float_as_uint(pe[3]) & 0xFFFF0000u);
          *(uint2*)&Ps[wave][prow + ((n * 16 + quad * 4) ^ rx)] = u;
        }
      }
      // wave-private Ps: compiler inserts lgkmcnt wait; no barrier needed

      bf16x8 pf[2];
#pragma unroll
      for (int c = 0; c < 2; c++)
        pf[c] = *(const bf16x8*)&Ps[wave][l16 * 64 +
                                          ((c * 32 + quad * 8) ^ rx)];
      // l row-sums via MFMA against ones (replicated over cols).
#pragma unroll
      for (int c = 0; c < 2; c++)
        l_acc = __builtin_amdgcn_mfma_f32_16x16x32_bf16(pf[c], ones, l_acc,
                                                        0, 0, 0);
#pragma unroll
      for (int n = 0; n < 4; n++)
#pragma unroll
        for (int c = 0; c < 2; c++) {
          const bf16x8 bv = *(const bf16x8*)&Vt[cur][(n * 16 + l16) * 64 +
                                                     ((c * 32 + quad * 8) ^ rx)];
          o_acc[n] = __builtin_amdgcn_mfma_f32_16x16x32_bf16(pf[c], bv,
                                                             o_acc[n], 0, 0, 0);
        }

      // Stage prefetched tile into the other buffer (swizzled writes).
      if (kt + 1 < ktiles) {
        const int nxt = cur ^ 1;
        *(uint4*)&Ks[nxt][rr * 64 + (dc ^ sx)] = rk;
        *(uint4*)&Vt[nxt][rr * 64 + (dc ^ sx)] = rv;
      }
      cur ^= 1;
    }

    // Epilogue: l already reduced by MFMA; normalize, store bf16 (in-place q).
#pragma unroll
    for (int e = 0; e < 4; e++) {
      const float inv = 1.f / l_acc[e];
      const size_t row =
          (size_t)(b * S_LEN + row0 + wave * 16 + quad * 4 + e);
#pragma unroll
      for (int n = 0; n < 4; n++)
        ao[row * QKV_LD + h * H_D + n * 16 + l16] = f2bf(o_acc[n][e] * inv);
    }
  }
}

#define LK 72  // padded inner stride for fallback attention

// ---------------------------------------------------------------------------
// Round-4 attention (fallback path only): k/v separate buffers stride 512.
// ---------------------------------------------------------------------------
__global__ __launch_bounds__(256) void attn_mfma_k(
    const unsigned short* __restrict__ q, const unsigned short* __restrict__ k,
    const unsigned short* __restrict__ v, unsigned short* __restrict__ ao) {
  const int qt = blockIdx.x, h = blockIdx.y, b = blockIdx.z;
  const int hk = h >> 2;
  const int tid = threadIdx.x;
  const int wave = tid >> 6;
  const int l16 = tid & 15;
  const int quad = (tid & 63) >> 4;

  __shared__ __align__(16) unsigned short Ks[64 * LK];
  __shared__ __align__(16) unsigned short Vt[64 * LK];
  __shared__ __align__(16) unsigned short Ps[64 * LK];

  bf16x8 af[2];
  {
    const size_t qrow = (size_t)(b * S_LEN + qt * 64 + wave * 16 + l16);
#pragma unroll
    for (int c = 0; c < 2; c++)
      af[c] = *(const bf16x8*)&q[qrow * DMODEL + h * H_D + c * 32 + quad * 8];
  }

  f32x4 o_acc[4] = {};
  float m_i[4], l_i[4];
#pragma unroll
  for (int e = 0; e < 4; e++) { m_i[e] = -INFINITY; l_i[e] = 0.f; }

  for (int kt = 0; kt <= qt; ++kt) {
    const int kb = kt * 64;
    __syncthreads();
    {
      const int kr = tid >> 2;
      const int dc = (tid & 3) * 16;
      const size_t gro = (size_t)(b * S_LEN + kb + kr) * (N_KV * H_D) + hk * H_D + dc;
      *(uint4*)&Ks[kr * LK + dc] = *(const uint4*)&k[gro];
      *(uint4*)&Ks[kr * LK + dc + 8] = *(const uint4*)&k[gro + 8];
      union { unsigned short u[8]; uint4 v; } w0, w1;
      w0.v = *(const uint4*)&v[gro];
      w1.v = *(const uint4*)&v[gro + 8];
#pragma unroll
      for (int j = 0; j < 8; j++) Vt[(dc + j) * LK + kr] = w0.u[j];
#pragma unroll
      for (int j = 0; j < 8; j++) Vt[(dc + 8 + j) * LK + kr] = w1.u[j];
    }
    __syncthreads();

    f32x4 sacc[4];
#pragma unroll
    for (int n = 0; n < 4; n++) {
      f32x4 z = {};
#pragma unroll
      for (int c = 0; c < 2; c++) {
        const bf16x8 bk = *(const bf16x8*)&Ks[(n * 16 + l16) * LK + c * 32 + quad * 8];
        z = __builtin_amdgcn_mfma_f32_16x16x32_bf16(af[c], bk, z, 0, 0, 0);
      }
      sacc[n] = z;
    }

    float p[4][4], mnew[4];
#pragma unroll
    for (int e = 0; e < 4; e++) mnew[e] = m_i[e];
#pragma unroll
    for (int n = 0; n < 4; n++)
#pragma unroll
      for (int e = 0; e < 4; e++) {
        float s = sacc[n][e] * 0.125f;
        if (kt == qt && (n * 16 + l16) > (wave * 16 + quad * 4 + e))
          s = -INFINITY;
        p[n][e] = s;
        mnew[e] = fmaxf(mnew[e], s);
      }
#pragma unroll
    for (int e = 0; e < 4; e++) {
      mnew[e] = fmaxf(mnew[e], __shfl_xor(mnew[e], 1));
      mnew[e] = fmaxf(mnew[e], __shfl_xor(mnew[e], 2));
      mnew[e] = fmaxf(mnew[e], __shfl_xor(mnew[e], 4));
      mnew[e] = fmaxf(mnew[e], __shfl_xor(mnew[e], 8));
      const float alpha = __expf(m_i[e] - mnew[e]);
      m_i[e] = mnew[e];
      l_i[e] *= alpha;
#pragma unroll
      for (int n = 0; n < 4; n++) o_acc[n][e] *= alpha;
    }
#pragma unroll
    for (int n = 0; n < 4; n++)
#pragma unroll
      for (int e = 0; e < 4; e++) {
        const float pe = __expf(p[n][e] - m_i[e]);
        p[n][e] = pe;
        l_i[e] += pe;
      }

#pragma unroll
    for (int n = 0; n < 4; n++)
#pragma unroll
      for (int e = 0; e < 4; e++)
        Ps[(wave * 16 + quad * 4 + e) * LK + n * 16 + l16] = f2bf(p[n][e]);
    __syncthreads();

    bf16x8 pf[2];
#pragma unroll
    for (int c = 0; c < 2; c++)
      pf[c] = *(const bf16x8*)&Ps[(wave * 16 + l16) * LK + c * 32 + quad * 8];
#pragma unroll
    for (int n = 0; n < 4; n++)
#pragma unroll
      for (int c = 0; c < 2; c++) {
        const bf16x8 bv = *(const bf16x8*)&Vt[(n * 16 + l16) * LK + c * 32 + quad * 8];
        o_acc[n] = __builtin_amdgcn_mfma_f32_16x16x32_bf16(pf[c], bv, o_acc[n], 0, 0, 0);
      }
  }

#pragma unroll
  for (int e = 0; e < 4; e++) {
    l_i[e] += __shfl_xor(l_i[e], 1);
    l_i[e] += __shfl_xor(l_i[e], 2);
    l_i[e] += __shfl_xor(l_i[e], 4);
    l_i[e] += __shfl_xor(l_i[e], 8);
    const float inv = 1.f / l_i[e];
    const size_t row = (size_t)(b * S_LEN + qt * 64 + wave * 16 + quad * 4 + e);
#pragma unroll
    for (int n = 0; n < 4; n++)
      ao[row * DMODEL + h * H_D + n * 16 + l16] = f2bf(o_acc[n][e] * inv);
  }
}

// ---------------------------------------------------------------------------
extern "C" void kernel_launch(void* const* d_in, const int* in_sizes, int n_in,
                              void* d_out, int out_size, void* d_ws, size_t ws_size,
                              hipStream_t stream) {
  const float* x = (const float*)d_in[0];
  const float* fc = (const float*)d_in[1];
  const float* fs = (const float*)d_in[2];
  const float* wq = (const float*)d_in[3];
  const float* wk = (const float*)d_in[4];
  const float* wv = (const float*)d_in[5];
  const float* wo = (const float*)d_in[6];

  char* ws = (char*)d_ws;
  const dim3 b256(256);

  if (ws_size >= (64ull << 20)) {
    // Fast path (64 MB):
    //   qkv   bf16 [4096][3072] @ 0     (24 MB)  q|k|v fused; attn out in q cols
    //   xb    bf16 [4096][2048] @ 24 MB (16 MB)
    //   wqkvT bf16 [3072][2048] @ 40 MB (12 MB)
    //   woT   bf16 [2048][2048] @ 52 MB ( 8 MB)
    //   vT    bf16 [ 512][4096] @ 60 MB ( 4 MB)
    unsigned short* qkv = (unsigned short*)(ws);
    unsigned short* xb = (unsigned short*)(ws + (24ull << 20));
    unsigned short* wqkvT = (unsigned short*)(ws + (40ull << 20));
    unsigned short* woT = (unsigned short*)(ws + (52ull << 20));
    unsigned short* vT = (unsigned short*)(ws + (60ull << 20));

    prep_all_k<<<dim3(64, 64, 5), b256, 0, stream>>>(x, wq, wk, wv, wo, xb,
                                                     wqkvT, woT);

    // Fused QKV projection, 8-phase 256^2: [4096][2048]@[3072][2048]^T
    gemm8_bt_k<1><<<dim3(16, 12), dim3(512), 0, stream>>>(xb, wqkvT, qkv, 4096,
                                                          3072, 2048, 2048);

    // RoPE (q pre-scaled by log2e/8, k plain) + v -> vT transpose, fused
    rope_vt_k<<<dim3(20480 + 2048), b256, 0, stream>>>(qkv, vT, fc, fs);

    // Paired 8-wave attention (v8): 512 blocks x 512 thr, 2 blocks/CU.
    attn_mfma8_k<<<dim3(8, N_H, 2), dim3(512), 0, stream>>>(qkv, vT, qkv);

    // Output projection, 8-phase 256x128 (full 256-block grid = 1/CU):
    // A = qkv q-cols (lda=3072) -> fp32 d_out
    gemm8n_bt_k<0><<<dim3(16, 16), dim3(512), 0, stream>>>(qkv, woT, d_out,
                                                           4096, 2048, 2048,
                                                           QKV_LD);
  } else {
    // Round-4 fallback (<= 40 MB)
    unsigned short* q = (unsigned short*)(ws);
    unsigned short* k = (unsigned short*)(ws + (16ull << 20));
    unsigned short* v = (unsigned short*)(ws + (20ull << 20));
    unsigned short* xb = (unsigned short*)(ws + (24ull << 20));
    const bool have_xb = ws_size >= (40ull << 20);

    if (have_xb) {
      cvt_bf16_k<<<dim3(ROWS * DMODEL / (256 * 8)), b256, 0, stream>>>(x, xb);
      gemm_k<0, 1><<<dim3(32, 16), b256, 0, stream>>>(xb, wq, q, 4096, 2048, 2048);
      gemm_k<0, 1><<<dim3(32, 4), b256, 0, stream>>>(xb, wk, k, 4096, 512, 2048);
      gemm_k<0, 1><<<dim3(32, 4), b256, 0, stream>>>(xb, wv, v, 4096, 512, 2048);
    } else {
      gemm_k<1, 1><<<dim3(32, 16), b256, 0, stream>>>(x, wq, q, 4096, 2048, 2048);
      gemm_k<1, 1><<<dim3(32, 4), b256, 0, stream>>>(x, wk, k, 4096, 512, 2048);
      gemm_k<1, 1><<<dim3(32, 4), b256, 0, stream>>>(x, wv, v, 4096, 512, 2048);
    }

    rope_k<<<dim3(20480), b256, 0, stream>>>(q, k, fc, fs, N_H * H_D, N_KV * H_D);
    attn_mfma_k<<<dim3(S_LEN / 64, N_H, 2), b256, 0, stream>>>(q, k, v, q);
    gemm_k<0, 0><<<dim3(32, 16), b256, 0, stream>>>(q, wo, d_out, 4096, 2048, 2048);
  }
}

// Round 9
// 282.084 us; speedup vs baseline: 1.1995x; 1.0526x over previous
//
#include <hip/hip_runtime.h>
#include <hip/hip_bf16.h>

// Problem constants (B=2, S=2048, D=2048, NH=32, NKV=8, HD=64, NREP=4)
#define S_LEN 2048
#define DMODEL 2048
#define N_H 32
#define N_KV 8
#define H_D 64
#define ROWS 4096   // B*S
#define QKV_LD 3072 // fused qkv row stride: q[0:2048) k[2048:2560) v[2560:3072)

typedef __bf16 bf16x8 __attribute__((ext_vector_type(8)));
typedef float f32x4 __attribute__((ext_vector_type(4)));

// fp32 -> bf16 raw bits, round-to-nearest-even
static __device__ __forceinline__ unsigned short f2bf(float f) {
  unsigned int u = __float_as_uint(f);
  u += 0x7FFFu + ((u >> 16) & 1u);
  return (unsigned short)(u >> 16);
}
static __device__ __forceinline__ float bf2f(unsigned short s) {
  return __uint_as_float((unsigned int)s << 16);
}

// async global->LDS, 16 B per lane. LDS dest = wave-uniform base + lane*16.
static __device__ __forceinline__ void async16(const void* g, void* l) {
  __builtin_amdgcn_global_load_lds(
      (const __attribute__((address_space(1))) unsigned int*)g,
      (__attribute__((address_space(3))) unsigned int*)l, 16, 0, 0);
}

// counted vmcnt + raw barrier (T4): loads stay in flight across the barrier.
#define VMB(N)                                                    \
  do {                                                            \
    asm volatile("s_waitcnt vmcnt(" #N ")" ::: "memory");         \
    __builtin_amdgcn_s_barrier();                                 \
    asm volatile("" ::: "memory");                                \
  } while (0)

// ---------------------------------------------------------------------------
// fp32 -> bf16 bulk convert (8 elems/thread) — fallback path only
// ---------------------------------------------------------------------------
__global__ __launch_bounds__(256) void cvt_bf16_k(
    const float* __restrict__ in, unsigned short* __restrict__ out) {
  const size_t i = ((size_t)blockIdx.x * 256 + threadIdx.x) * 8;
  const float4 a = *(const float4*)&in[i];
  const float4 b = *(const float4*)&in[i + 4];
  union { unsigned short u[8]; uint4 v; } p;
  p.u[0] = f2bf(a.x); p.u[1] = f2bf(a.y); p.u[2] = f2bf(a.z); p.u[3] = f2bf(a.w);
  p.u[4] = f2bf(b.x); p.u[5] = f2bf(b.y); p.u[6] = f2bf(b.z); p.u[7] = f2bf(b.w);
  *(uint4*)&out[i] = p.v;
}

// ---------------------------------------------------------------------------
// Combined prep: z=0..3 transpose fp32 weights -> bf16 wqkvT/woT blocks;
// z=4: straight cvt x fp32 -> xb bf16 (64x64 blocks x 256 thr x 8 elems).
// ---------------------------------------------------------------------------
__global__ __launch_bounds__(256) void prep_all_k(
    const float* __restrict__ x, const float* __restrict__ wq,
    const float* __restrict__ wk, const float* __restrict__ wv,
    const float* __restrict__ wo, unsigned short* __restrict__ xb,
    unsigned short* __restrict__ wqkvT, unsigned short* __restrict__ woT) {
  const int z = blockIdx.z;
  if (z == 4) {
    const size_t i =
        (((size_t)blockIdx.y * 64 + blockIdx.x) * 256 + threadIdx.x) * 8;
    const float4 a = *(const float4*)&x[i];
    const float4 b = *(const float4*)&x[i + 4];
    union { unsigned short u[8]; uint4 v; } p;
    p.u[0] = f2bf(a.x); p.u[1] = f2bf(a.y); p.u[2] = f2bf(a.z); p.u[3] = f2bf(a.w);
    p.u[4] = f2bf(b.x); p.u[5] = f2bf(b.y); p.u[6] = f2bf(b.z); p.u[7] = f2bf(b.w);
    *(uint4*)&xb[i] = p.v;
    return;
  }
  const float* in;
  unsigned short* out;
  int C;
  if (z == 0)      { in = wq; out = wqkvT;                  C = 2048; }
  else if (z == 1) { in = wk; out = wqkvT + 2048ull * 2048; C = 512;  }
  else if (z == 2) { in = wv; out = wqkvT + 2560ull * 2048; C = 512;  }
  else             { in = wo; out = woT;                    C = 2048; }
  if (blockIdx.x * 32 >= C) return;

  __shared__ unsigned short tile[32][33];
  const int tx = threadIdx.x & 31;
  const int ty = threadIdx.x >> 5;
  const int r0 = blockIdx.y * 32;  // K rows of input
  const int c0 = blockIdx.x * 32;  // C cols of input
#pragma unroll
  for (int i = 0; i < 32; i += 8)
    tile[ty + i][tx] = f2bf(in[(size_t)(r0 + ty + i) * C + c0 + tx]);
  __syncthreads();
#pragma unroll
  for (int i = 0; i < 32; i += 8)
    out[(size_t)(c0 + ty + i) * 2048 + r0 + tx] = tile[tx][ty + i];
}

// log2(e) / sqrt(HD): softmax base-2 conversion + 1/sqrt(d), folded into q
#define SCALE_LOG2E 0.18033688011112042f

// ---------------------------------------------------------------------------
// Fused RoPE (blocks 0..20479) + v->vT transpose (blocks 20480..22527).
// ---------------------------------------------------------------------------
__global__ __launch_bounds__(256) void rope_vt_k(
    unsigned short* __restrict__ qkv, unsigned short* __restrict__ vT,
    const float* __restrict__ fc, const float* __restrict__ fs) {
  const int blk = blockIdx.x;
  if (blk < 20480) {
    const int PQ = ROWS * N_H * (H_D / 2);   // 4194304
    const int PK = ROWS * N_KV * (H_D / 2);  // 1048576
    const int idx = blk * 256 + threadIdx.x;
    if (idx >= PQ + PK) return;
    unsigned short* base;
    float c, sn;
    bool isq;
    if (idx < PQ) {
      const int i = idx & 31;
      const int h = (idx >> 5) & 31;
      const int row = idx >> 10;
      const int s = row & (S_LEN - 1);
      c = fc[s * 32 + i];
      sn = fs[s * 32 + i];
      base = qkv + (size_t)row * QKV_LD + h * H_D + 2 * i;
      isq = true;
    } else {
      const int p = idx - PQ;
      const int i = p & 31;
      const int h = (p >> 5) & 7;
      const int row = p >> 8;
      const int s = row & (S_LEN - 1);
      c = fc[s * 32 + i];
      sn = fs[s * 32 + i];
      base = qkv + (size_t)row * QKV_LD + 2048 + h * H_D + 2 * i;
      isq = false;
    }
    const float x0 = bf2f(base[0]);
    const float x1 = bf2f(base[1]);
    const float sc = isq ? SCALE_LOG2E : 1.0f;
    base[0] = f2bf((x0 * c - x1 * sn) * sc);
    base[1] = f2bf((x0 * sn + x1 * c) * sc);
  } else {
    __shared__ unsigned short tile[32][33];
    const int t = blk - 20480;        // 0..2047
    const int bx = t & 15;            // C/32 = 16
    const int by = t >> 4;            // R/32 = 128
    const unsigned short* in = qkv + 2560;
    const int tx = threadIdx.x & 31;
    const int ty = threadIdx.x >> 5;
    const int r0 = by * 32;
    const int c0 = bx * 32;
#pragma unroll
    for (int i = 0; i < 32; i += 8)
      tile[ty + i][tx] = in[(size_t)(r0 + ty + i) * QKV_LD + c0 + tx];
    __syncthreads();
#pragma unroll
    for (int i = 0; i < 32; i += 8)
      vT[(size_t)(c0 + ty + i) * ROWS + r0 + tx] = tile[tx][ty + i];
  }
}

// ---------------------------------------------------------------------------
// gemm8w: 8-phase deep-pipelined BM=256 x BN=192 MFMA GEMM (T2+T3+T4+T5).
// For QKV (M=4096, N=3072): grid (16,16) = 256 blocks = exactly 1/CU — fixes
// the 25% idle of the 256^2 grid (192 blocks). 12 MFMA/phase.
// Per wave, 7 issues/tile in order [B0,B1,B2,A0,A1,A2,A3]; A-instr j stages
// the 32 M-rows phase j consumes; B (192 rows) fully staged before ph0.
// Ledger (steady state; general rule ph0 wait = L - nb - 1 = 7-3-1 = 3):
//   ph0: outstanding 7, need B0..B2+A0  -> vmcnt(3); issues B0',B1'
//   ph1: outstanding 5, need A1         -> vmcnt(4); issues B2',A0'
//   ph2: outstanding 6, need A2         -> vmcnt(5); issues A1',A2'
//   ph3: outstanding 7, need A3         -> vmcnt(6); issues A3'
// Identical constants to the HW-verified gemm8/gemm8n ledger. Cross-wave
// safety: uniform per-wave ledger + shared barrier after each wait.
// LDS 112 KiB (A 2x2x128x64 + B 2x192x64). T2 swizzle identical.
// ---------------------------------------------------------------------------
template <int STORE_BF16>
__global__ __launch_bounds__(512, 2) void gemm8w_bt_k(
    const unsigned short* __restrict__ A, const unsigned short* __restrict__ BT,
    void* __restrict__ Cp, int M, int N, int K, int lda) {
  __shared__ __align__(16) unsigned short As[2][2][128 * 64];
  __shared__ __align__(16) unsigned short Bs[2][192 * 64];
  const int tid = threadIdx.x;
  const int wave = tid >> 6;
  const int lane = tid & 63;
  const int quad = lane >> 4;
  const int l16 = lane & 15;
  const int nwg = gridDim.x * gridDim.y;
  const int flat = blockIdx.y * gridDim.x + blockIdx.x;
  const int swz = (flat & 7) * (nwg >> 3) + (flat >> 3);
  const int m0 = (swz % gridDim.x) * 256;
  const int n0 = (swz / gridDim.x) * 192;
  const int ah = wave & 1;         // A half this wave computes on
  const int ag = wave >> 1;        // stage slot within A-group
  const int wn = (wave >> 1) * 48; // per-wave 48-col N strip
  const int rx = (l16 & 7) << 3;
  const int scol = ((lane & 7) * 8) ^ ((lane >> 3) << 3);
  const int srA = 8 * ag + (lane >> 3);
  const int srB = 8 * wave + (lane >> 3);
  const size_t abase = (size_t)(m0 + ah * 128) * lda;
  const size_t bbase = (size_t)n0 * K;
  f32x4 acc[8][3] = {};

#define STG_B(j, buf, kt)                                             \
  async16(&BT[bbase + (size_t)(64 * (j) + srB) * K + (kt) + scol],    \
          &Bs[buf][(64 * (j) + 8 * wave) * 64])
#define STG_A(j, buf, kt)                                             \
  async16(&A[abase + (size_t)(32 * (j) + srA) * lda + (kt) + scol],   \
          &As[buf][ah][(32 * (j) + 8 * ag) * 64])

  // prologue: stage tile 0 into buf 0 in ledger order
  STG_B(0, 0, 0); STG_B(1, 0, 0); STG_B(2, 0, 0);
  STG_A(0, 0, 0); STG_A(1, 0, 0); STG_A(2, 0, 0); STG_A(3, 0, 0);

  const int NT = K >> 6;
  for (int t = 0; t < NT; ++t) {
    const int cur = t & 1, nxt = cur ^ 1;
    const int ktn = (t + 1 < NT) ? ((t + 1) << 6) : 0;
    const unsigned short* Ac = &As[cur][ah][0];
    const unsigned short* Bc = &Bs[cur][0];
    bf16x8 bf[3][2];

    // ---- phase 0: B frags + A frags 0,1 ----
    VMB(3);
    {
      bf16x8 af[2][2];
#pragma unroll
      for (int n = 0; n < 3; n++)
#pragma unroll
        for (int kk = 0; kk < 2; kk++)
          bf[n][kk] = *(const bf16x8*)&Bc[(wn + n * 16 + l16) * 64 +
                                          ((kk * 32 + quad * 8) ^ rx)];
#pragma unroll
      for (int i = 0; i < 2; i++)
#pragma unroll
        for (int kk = 0; kk < 2; kk++)
          af[i][kk] = *(const bf16x8*)&Ac[((0 + i) * 16 + l16) * 64 +
                                          ((kk * 32 + quad * 8) ^ rx)];
      STG_B(0, nxt, ktn); STG_B(1, nxt, ktn);
      __builtin_amdgcn_s_setprio(1);
#pragma unroll
      for (int i = 0; i < 2; i++)
#pragma unroll
        for (int n = 0; n < 3; n++)
#pragma unroll
          for (int kk = 0; kk < 2; kk++)
            acc[0 + i][n] = __builtin_amdgcn_mfma_f32_16x16x32_bf16(
                af[i][kk], bf[n][kk], acc[0 + i][n], 0, 0, 0);
      __builtin_amdgcn_s_setprio(0);
    }

    // ---- phase 1: A frags 2,3 ----
    VMB(4);
    {
      bf16x8 af[2][2];
#pragma unroll
      for (int i = 0; i < 2; i++)
#pragma unroll
        for (int kk = 0; kk < 2; kk++)
          af[i][kk] = *(const bf16x8*)&Ac[((2 + i) * 16 + l16) * 64 +
                                          ((kk * 32 + quad * 8) ^ rx)];
      STG_B(2, nxt, ktn); STG_A(0, nxt, ktn);
      __builtin_amdgcn_s_setprio(1);
#pragma unroll
      for (int i = 0; i < 2; i++)
#pragma unroll
        for (int n = 0; n < 3; n++)
#pragma unroll
          for (int kk = 0; kk < 2; kk++)
            acc[2 + i][n] = __builtin_amdgcn_mfma_f32_16x16x32_bf16(
                af[i][kk], bf[n][kk], acc[2 + i][n], 0, 0, 0);
      __builtin_amdgcn_s_setprio(0);
    }

    // ---- phase 2: A frags 4,5 ----
    VMB(5);
    {
      bf16x8 af[2][2];
#pragma unroll
      for (int i = 0; i < 2; i++)
#pragma unroll
        for (int kk = 0; kk < 2; kk++)
          af[i][kk] = *(const bf16x8*)&Ac[((4 + i) * 16 + l16) * 64 +
                                          ((kk * 32 + quad * 8) ^ rx)];
      STG_A(1, nxt, ktn); STG_A(2, nxt, ktn);
      __builtin_amdgcn_s_setprio(1);
#pragma unroll
      for (int i = 0; i < 2; i++)
#pragma unroll
        for (int n = 0; n < 3; n++)
#pragma unroll
          for (int kk = 0; kk < 2; kk++)
            acc[4 + i][n] = __builtin_amdgcn_mfma_f32_16x16x32_bf16(
                af[i][kk], bf[n][kk], acc[4 + i][n], 0, 0, 0);
      __builtin_amdgcn_s_setprio(0);
    }

    // ---- phase 3: A frags 6,7 ----
    VMB(6);
    {
      bf16x8 af[2][2];
#pragma unroll
      for (int i = 0; i < 2; i++)
#pragma unroll
        for (int kk = 0; kk < 2; kk++)
          af[i][kk] = *(const bf16x8*)&Ac[((6 + i) * 16 + l16) * 64 +
                                          ((kk * 32 + quad * 8) ^ rx)];
      STG_A(3, nxt, ktn);
      __builtin_amdgcn_s_setprio(1);
#pragma unroll
      for (int i = 0; i < 2; i++)
#pragma unroll
        for (int n = 0; n < 3; n++)
#pragma unroll
          for (int kk = 0; kk < 2; kk++)
            acc[6 + i][n] = __builtin_amdgcn_mfma_f32_16x16x32_bf16(
                af[i][kk], bf[n][kk], acc[6 + i][n], 0, 0, 0);
      __builtin_amdgcn_s_setprio(0);
    }
  }
#undef STG_A
#undef STG_B

  // Epilogue: C/D layout col = lane&15, row = quad*4 + reg  [m89/m91]
#pragma unroll
  for (int f = 0; f < 8; f++) {
#pragma unroll
    for (int e = 0; e < 4; e++) {
      const int mrow = m0 + ah * 128 + f * 16 + quad * 4 + e;
#pragma unroll
      for (int n = 0; n < 3; n++) {
        const int ncol = n0 + wn + n * 16 + l16;
        const float val = acc[f][n][e];
        if (STORE_BF16) {
          ((unsigned short*)Cp)[(size_t)mrow * N + ncol] = f2bf(val);
        } else {
          ((float*)Cp)[(size_t)mrow * N + ncol] = val;
        }
      }
    }
  }
}

// ---------------------------------------------------------------------------
// gemm8n: 8-phase GEMM, BM=256 x BN=128 variant (verified round 8, WO path).
// Ledger identical constants; see round-7/8 derivations.
// ---------------------------------------------------------------------------
template <int STORE_BF16>
__global__ __launch_bounds__(512, 2) void gemm8n_bt_k(
    const unsigned short* __restrict__ A, const unsigned short* __restrict__ BT,
    void* __restrict__ Cp, int M, int N, int K, int lda) {
  __shared__ __align__(16) unsigned short As[2][2][128 * 64];
  __shared__ __align__(16) unsigned short Bs[2][128 * 64];
  const int tid = threadIdx.x;
  const int wave = tid >> 6;
  const int lane = tid & 63;
  const int quad = lane >> 4;
  const int l16 = lane & 15;
  const int nwg = gridDim.x * gridDim.y;
  const int flat = blockIdx.y * gridDim.x + blockIdx.x;
  const int swz = (flat & 7) * (nwg >> 3) + (flat >> 3);
  const int m0 = (swz % gridDim.x) * 256;
  const int n0 = (swz / gridDim.x) * 128;
  const int ah = wave & 1;
  const int ag = wave >> 1;
  const int wn = (wave >> 1) * 32;    // per-wave N strip (0,32,64,96)
  const int rx = (l16 & 7) << 3;
  const int scol = ((lane & 7) * 8) ^ ((lane >> 3) << 3);
  const int srA = 8 * ag + (lane >> 3);
  const int srB = 8 * wave + (lane >> 3);  // B row within 64-row group
  const size_t abase = (size_t)(m0 + ah * 128) * lda;
  const size_t bbase = (size_t)n0 * K;
  f32x4 acc[8][2] = {};

#define STG_B(j, buf, kt)                                             \
  async16(&BT[bbase + (size_t)(64 * (j) + srB) * K + (kt) + scol],    \
          &Bs[buf][(64 * (j) + 8 * wave) * 64])
#define STG_A(j, buf, kt)                                             \
  async16(&A[abase + (size_t)(32 * (j) + srA) * lda + (kt) + scol],   \
          &As[buf][ah][(32 * (j) + 8 * ag) * 64])

  STG_B(0, 0, 0); STG_B(1, 0, 0);
  STG_A(0, 0, 0); STG_A(1, 0, 0); STG_A(2, 0, 0); STG_A(3, 0, 0);

  const int NT = K >> 6;
  for (int t = 0; t < NT; ++t) {
    const int cur = t & 1, nxt = cur ^ 1;
    const int ktn = (t + 1 < NT) ? ((t + 1) << 6) : 0;
    const unsigned short* Ac = &As[cur][ah][0];
    const unsigned short* Bc = &Bs[cur][0];
    bf16x8 bf[2][2];

    VMB(3);
    {
      bf16x8 af[2][2];
#pragma unroll
      for (int n = 0; n < 2; n++)
#pragma unroll
        for (int kk = 0; kk < 2; kk++)
          bf[n][kk] = *(const bf16x8*)&Bc[(wn + n * 16 + l16) * 64 +
                                          ((kk * 32 + quad * 8) ^ rx)];
#pragma unroll
      for (int i = 0; i < 2; i++)
#pragma unroll
        for (int kk = 0; kk < 2; kk++)
          af[i][kk] = *(const bf16x8*)&Ac[((0 + i) * 16 + l16) * 64 +
                                          ((kk * 32 + quad * 8) ^ rx)];
      STG_B(0, nxt, ktn); STG_B(1, nxt, ktn);
      __builtin_amdgcn_s_setprio(1);
#pragma unroll
      for (int i = 0; i < 2; i++)
#pragma unroll
        for (int n = 0; n < 2; n++)
#pragma unroll
          for (int kk = 0; kk < 2; kk++)
            acc[0 + i][n] = __builtin_amdgcn_mfma_f32_16x16x32_bf16(
                af[i][kk], bf[n][kk], acc[0 + i][n], 0, 0, 0);
      __builtin_amdgcn_s_setprio(0);
    }

    VMB(4);
    {
      bf16x8 af[2][2];
#pragma unroll
      for (int i = 0; i < 2; i++)
#pragma unroll
        for (int kk = 0; kk < 2; kk++)
          af[i][kk] = *(const bf16x8*)&Ac[((2 + i) * 16 + l16) * 64 +
                                          ((kk * 32 + quad * 8) ^ rx)];
      STG_A(0, nxt, ktn); STG_A(1, nxt, ktn);
      __builtin_amdgcn_s_setprio(1);
#pragma unroll
      for (int i = 0; i < 2; i++)
#pragma unroll
        for (int n = 0; n < 2; n++)
#pragma unroll
          for (int kk = 0; kk < 2; kk++)
            acc[2 + i][n] = __builtin_amdgcn_mfma_f32_16x16x32_bf16(
                af[i][kk], bf[n][kk], acc[2 + i][n], 0, 0, 0);
      __builtin_amdgcn_s_setprio(0);
    }

    VMB(5);
    {
      bf16x8 af[2][2];
#pragma unroll
      for (int i = 0; i < 2; i++)
#pragma unroll
        for (int kk = 0; kk < 2; kk++)
          af[i][kk] = *(const bf16x8*)&Ac[((4 + i) * 16 + l16) * 64 +
                                          ((kk * 32 + quad * 8) ^ rx)];
      STG_A(2, nxt, ktn); STG_A(3, nxt, ktn);
      __builtin_amdgcn_s_setprio(1);
#pragma unroll
      for (int i = 0; i < 2; i++)
#pragma unroll
        for (int n = 0; n < 2; n++)
#pragma unroll
          for (int kk = 0; kk < 2; kk++)
            acc[4 + i][n] = __builtin_amdgcn_mfma_f32_16x16x32_bf16(
                af[i][kk], bf[n][kk], acc[4 + i][n], 0, 0, 0);
      __builtin_amdgcn_s_setprio(0);
    }

    VMB(6);
    {
      bf16x8 af[2][2];
#pragma unroll
      for (int i = 0; i < 2; i++)
#pragma unroll
        for (int kk = 0; kk < 2; kk++)
          af[i][kk] = *(const bf16x8*)&Ac[((6 + i) * 16 + l16) * 64 +
                                          ((kk * 32 + quad * 8) ^ rx)];
      __builtin_amdgcn_s_setprio(1);
#pragma unroll
      for (int i = 0; i < 2; i++)
#pragma unroll
        for (int n = 0; n < 2; n++)
#pragma unroll
          for (int kk = 0; kk < 2; kk++)
            acc[6 + i][n] = __builtin_amdgcn_mfma_f32_16x16x32_bf16(
                af[i][kk], bf[n][kk], acc[6 + i][n], 0, 0, 0);
      __builtin_amdgcn_s_setprio(0);
    }
  }
#undef STG_A
#undef STG_B

#pragma unroll
  for (int f = 0; f < 8; f++) {
#pragma unroll
    for (int e = 0; e < 4; e++) {
      const int mrow = m0 + ah * 128 + f * 16 + quad * 4 + e;
#pragma unroll
      for (int n = 0; n < 2; n++) {
        const int ncol = n0 + wn + n * 16 + l16;
        const float val = acc[f][n][e];
        if (STORE_BF16) {
          ((unsigned short*)Cp)[(size_t)mrow * N + ncol] = f2bf(val);
        } else {
          ((float*)Cp)[(size_t)mrow * N + ncol] = val;
        }
      }
    }
  }
}

// ---------------------------------------------------------------------------
// Fallback MFMA GEMM (round-4): C[M][N] = A[M][K] @ B[K][N], B fp32 native.
// ---------------------------------------------------------------------------
template <int AF32, int STORE_BF16>
__global__ __launch_bounds__(256) void gemm_k(
    const void* __restrict__ Ap, const float* __restrict__ B,
    void* __restrict__ Cp, int M, int N, int K) {
  constexpr int LDP = 40;
  __shared__ __align__(16) unsigned short As[128 * LDP];
  __shared__ __align__(16) unsigned short Bs[128 * LDP];
  const int tid = threadIdx.x;
  const int wave = tid >> 6;
  const int lane = tid & 63;
  const int quad = lane >> 4;
  const int l16 = lane & 15;
  const int m0 = blockIdx.x * 128;
  const int n0 = blockIdx.y * 128;
  const int wm = (wave >> 1) * 64;
  const int wn = (wave & 1) * 64;
  f32x4 acc[4][4] = {};

  for (int kt = 0; kt < K; kt += 32) {
    __syncthreads();
    if (AF32) {
      const float* A = (const float*)Ap;
      for (int c = tid; c < 1024; c += 256) {
        const int r = c >> 3;
        const int cc = (c & 7) << 2;
        const float4 w = *(const float4*)&A[(size_t)(m0 + r) * K + kt + cc];
        union { unsigned short u[4]; uint2 v; } p;
        p.u[0] = f2bf(w.x); p.u[1] = f2bf(w.y);
        p.u[2] = f2bf(w.z); p.u[3] = f2bf(w.w);
        *(uint2*)&As[r * LDP + cc] = p.v;
      }
    } else {
      const unsigned short* A = (const unsigned short*)Ap;
      for (int c = tid; c < 512; c += 256) {
        const int r = c >> 2;
        const int cc = (c & 3) << 3;
        *(uint4*)&As[r * LDP + cc] =
            *(const uint4*)&A[(size_t)(m0 + r) * K + kt + cc];
      }
    }
    for (int c = tid; c < 1024; c += 256) {
      const int kr = c >> 5;
      const int nc = (c & 31) << 2;
      const float4 w = *(const float4*)&B[(size_t)(kt + kr) * N + n0 + nc];
      Bs[(nc + 0) * LDP + kr] = f2bf(w.x);
      Bs[(nc + 1) * LDP + kr] = f2bf(w.y);
      Bs[(nc + 2) * LDP + kr] = f2bf(w.z);
      Bs[(nc + 3) * LDP + kr] = f2bf(w.w);
    }
    __syncthreads();
    bf16x8 af[4], bfr[4];
#pragma unroll
    for (int i = 0; i < 4; i++)
      af[i] = *(const bf16x8*)&As[(wm + i * 16 + l16) * LDP + quad * 8];
#pragma unroll
    for (int j = 0; j < 4; j++)
      bfr[j] = *(const bf16x8*)&Bs[(wn + j * 16 + l16) * LDP + quad * 8];
#pragma unroll
    for (int i = 0; i < 4; i++)
#pragma unroll
      for (int j = 0; j < 4; j++)
        acc[i][j] =
            __builtin_amdgcn_mfma_f32_16x16x32_bf16(af[i], bfr[j], acc[i][j], 0, 0, 0);
  }
#pragma unroll
  for (int i = 0; i < 4; i++) {
#pragma unroll
    for (int e = 0; e < 4; e++) {
      const int mrow = m0 + wm + i * 16 + quad * 4 + e;
#pragma unroll
      for (int j = 0; j < 4; j++) {
        const int ncol = n0 + wn + j * 16 + l16;
        const float val = acc[i][j][e];
        if (STORE_BF16) {
          ((unsigned short*)Cp)[(size_t)mrow * N + ncol] = f2bf(val);
        } else {
          ((float*)Cp)[(size_t)mrow * N + ncol] = val;
        }
      }
    }
  }
}

// ---------------------------------------------------------------------------
// Fallback RoPE (separate q/k buffers)
// ---------------------------------------------------------------------------
__global__ __launch_bounds__(256) void rope_k(
    unsigned short* __restrict__ q, unsigned short* __restrict__ kk,
    const float* __restrict__ fc, const float* __restrict__ fs,
    int qstride, int kstride) {
  const int PQ = ROWS * N_H * (H_D / 2);
  const int PK = ROWS * N_KV * (H_D / 2);
  const int idx = blockIdx.x * 256 + threadIdx.x;
  if (idx >= PQ + PK) return;
  unsigned short* base;
  float c, sn;
  if (idx < PQ) {
    const int i = idx & 31;
    const int h = (idx >> 5) & 31;
    const int row = idx >> 10;
    const int s = row & (S_LEN - 1);
    c = fc[s * 32 + i];
    sn = fs[s * 32 + i];
    base = q + (size_t)row * qstride + h * H_D + 2 * i;
  } else {
    const int p = idx - PQ;
    const int i = p & 31;
    const int h = (p >> 5) & 7;
    const int row = p >> 8;
    const int s = row & (S_LEN - 1);
    c = fc[s * 32 + i];
    sn = fs[s * 32 + i];
    base = kk + (size_t)row * kstride + h * H_D + 2 * i;
  }
  const float x0 = bf2f(base[0]);
  const float x1 = bf2f(base[1]);
  base[0] = f2bf(x0 * c - x1 * sn);
  base[1] = f2bf(x0 * sn + x1 * c);
}

// ---------------------------------------------------------------------------
// attn v8 (round-2 verified, best config). 8-wave (512-thr) paired flash
// attention, 16 q-rows/wave, swapped-operand S^T, XOR-swizzled LDS, packed
// b64 P stores, NON-ONLINE softmax, l row-sums via ones-MFMA. 2 blocks/CU.
// ---------------------------------------------------------------------------
__global__ __launch_bounds__(512, 4) void attn_mfma8_k(
    const unsigned short* __restrict__ qkv, const unsigned short* __restrict__ vT,
    unsigned short* __restrict__ ao) {
  const int pair = blockIdx.x, h = blockIdx.y, b = blockIdx.z;
  const int hk = h >> 2;
  const int tid = threadIdx.x;
  const int wave = tid >> 6;      // 0..7
  const int l16 = tid & 15;
  const int quad = (tid & 63) >> 4;
  const int rr = tid >> 3;        // 0..63 staging row
  const int dc = (tid & 7) * 8;   // staging 8-elem (16B) chunk
  const int rx = (l16 & 7) << 3;  // read/P-side XOR (elem units)
  const int sx = (rr & 7) << 3;   // stage-side XOR

  __shared__ __align__(16) unsigned short Ks[2][64 * 64];  // [key][d] swz
  __shared__ __align__(16) unsigned short Vt[2][64 * 64];  // [d][key] swz
  __shared__ __align__(16) unsigned short Ps[8][16 * 64];  // wave-private swz

  bf16x8 ones;
#pragma unroll
  for (int j = 0; j < 8; j++) ones[j] = (__bf16)1.0f;

  const size_t kbase =
      (size_t)(b * S_LEN) * QKV_LD + 2048 + hk * H_D + dc;  // k cols
  const size_t vbase = (size_t)(hk * H_D + rr) * ROWS + b * S_LEN + dc;

  for (int sel = 0; sel < 2; ++sel) {
    const int qb = sel ? (15 - pair) : pair;  // q-block of 128 rows
    const int row0 = qb * 128;
    const int ktiles = 2 * qb + 2;

    // Q fragments: A/B-frag layout lane holds [l16][quad*8+j]; 16 rows/wave
    bf16x8 af[2];
    {
      const size_t qrow = (size_t)(b * S_LEN + row0 + wave * 16 + l16);
#pragma unroll
      for (int c = 0; c < 2; c++)
        af[c] =
            *(const bf16x8*)&qkv[qrow * QKV_LD + h * H_D + c * 32 + quad * 8];
    }

    f32x4 o_acc[4] = {};
    f32x4 l_acc = {};

    // Prefetch tile 0 into registers, then stage into LDS buffer 0.
    uint4 rk, rv;
    {
      rk = *(const uint4*)&qkv[kbase + (size_t)rr * QKV_LD];
      rv = *(const uint4*)&vT[vbase];
    }
    __syncthreads();  // prior-sel readers of LDS done before overwrite
    *(uint4*)&Ks[0][rr * 64 + (dc ^ sx)] = rk;
    *(uint4*)&Vt[0][rr * 64 + (dc ^ sx)] = rv;

    int cur = 0;
    for (int kt = 0; kt < ktiles; ++kt) {
      // Prefetch next tile while this tile computes.
      if (kt + 1 < ktiles) {
        rk = *(const uint4*)&qkv[kbase + (size_t)((kt + 1) * 64 + rr) * QKV_LD];
        rv = *(const uint4*)&vT[vbase + (size_t)(kt + 1) * 64];
      }
      __syncthreads();  // LDS[cur] fully staged by all waves

      // S^T strips: D[row=k(quad*4+e), col=q(l16)] = mfma(K-frag, Q-frag).
      f32x4 sacc[4];
#pragma unroll
      for (int n = 0; n < 4; n++) {
        f32x4 z = {};
#pragma unroll
        for (int c = 0; c < 2; c++) {
          const bf16x8 bk = *(const bf16x8*)&Ks[cur][(n * 16 + l16) * 64 +
                                                     ((c * 32 + quad * 8) ^ rx)];
          z = __builtin_amdgcn_mfma_f32_16x16x32_bf16(bk, af[c], z, 0, 0, 0);
        }
        sacc[n] = z;
      }

      // pe = exp2(s); truncate to bf16; masked -> 0; packed b64 store to Ps.
      const bool maybe_mask = (kt >= 2 * qb);
      const int krel0 = (kt - 2 * qb) * 64;  // valid only when maybe_mask
      {
        const int qn = wave * 16 + l16;  // relative q row of this lane
        const int prow = l16 * 64;
#pragma unroll
        for (int n = 0; n < 4; n++) {
          const int kb0 = krel0 + n * 16 + quad * 4;  // relative k of e=0
          float pe[4];
#pragma unroll
          for (int e = 0; e < 4; e++) {
            float v = exp2f(sacc[n][e]);
            if (maybe_mask && (kb0 + e > qn)) v = 0.f;
            pe[e] = v;
          }
          uint2 u;
          u.x = (__float_as_uint(pe[0]) >> 16) |
                (__float_as_uint(pe[1]) & 0xFFFF0000u);
          u.y = (__float_as_uint(pe[2]) >> 16) |
                (__float_as_uint(pe[3]) & 0xFFFF0000u);
          *(uint2*)&Ps[wave][prow + ((n * 16 + quad * 4) ^ rx)] = u;
        }
      }
      // wave-private Ps: compiler inserts lgkmcnt wait; no barrier needed

      bf16x8 pf[2];
#pragma unroll
      for (int c = 0; c < 2; c++)
        pf[c] = *(const bf16x8*)&Ps[wave][l16 * 64 +
                                          ((c * 32 + quad * 8) ^ rx)];
      // l row-sums via MFMA against ones (replicated over cols).
#pragma unroll
      for (int c = 0; c < 2; c++)
        l_acc = __builtin_amdgcn_mfma_f32_16x16x32_bf16(pf[c], ones, l_acc,
                                                        0, 0, 0);
#pragma unroll
      for (int n = 0; n < 4; n++)
#pragma unroll
        for (int c = 0; c < 2; c++) {
          const bf16x8 bv = *(const bf16x8*)&Vt[cur][(n * 16 + l16) * 64 +
                                                     ((c * 32 + quad * 8) ^ rx)];
          o_acc[n] = __builtin_amdgcn_mfma_f32_16x16x32_bf16(pf[c], bv,
                                                             o_acc[n], 0, 0, 0);
        }

      // Stage prefetched tile into the other buffer (swizzled writes).
      if (kt + 1 < ktiles) {
        const int nxt = cur ^ 1;
        *(uint4*)&Ks[nxt][rr * 64 + (dc ^ sx)] = rk;
        *(uint4*)&Vt[nxt][rr * 64 + (dc ^ sx)] = rv;
      }
      cur ^= 1;
    }

    // Epilogue: l already reduced by MFMA; normalize, store bf16 (in-place q).
#pragma unroll
    for (int e = 0; e < 4; e++) {
      const float inv = 1.f / l_acc[e];
      const size_t row =
          (size_t)(b * S_LEN + row0 + wave * 16 + quad * 4 + e);
#pragma unroll
      for (int n = 0; n < 4; n++)
        ao[row * QKV_LD + h * H_D + n * 16 + l16] = f2bf(o_acc[n][e] * inv);
    }
  }
}

#define LK 72  // padded inner stride for fallback attention

// ---------------------------------------------------------------------------
// Round-4 attention (fallback path only): k/v separate buffers stride 512.
// ---------------------------------------------------------------------------
__global__ __launch_bounds__(256) void attn_mfma_k(
    const unsigned short* __restrict__ q, const unsigned short* __restrict__ k,
    const unsigned short* __restrict__ v, unsigned short* __restrict__ ao) {
  const int qt = blockIdx.x, h = blockIdx.y, b = blockIdx.z;
  const int hk = h >> 2;
  const int tid = threadIdx.x;
  const int wave = tid >> 6;
  const int l16 = tid & 15;
  const int quad = (tid & 63) >> 4;

  __shared__ __align__(16) unsigned short Ks[64 * LK];
  __shared__ __align__(16) unsigned short Vt[64 * LK];
  __shared__ __align__(16) unsigned short Ps[64 * LK];

  bf16x8 af[2];
  {
    const size_t qrow = (size_t)(b * S_LEN + qt * 64 + wave * 16 + l16);
#pragma unroll
    for (int c = 0; c < 2; c++)
      af[c] = *(const bf16x8*)&q[qrow * DMODEL + h * H_D + c * 32 + quad * 8];
  }

  f32x4 o_acc[4] = {};
  float m_i[4], l_i[4];
#pragma unroll
  for (int e = 0; e < 4; e++) { m_i[e] = -INFINITY; l_i[e] = 0.f; }

  for (int kt = 0; kt <= qt; ++kt) {
    const int kb = kt * 64;
    __syncthreads();
    {
      const int kr = tid >> 2;
      const int dc = (tid & 3) * 16;
      const size_t gro = (size_t)(b * S_LEN + kb + kr) * (N_KV * H_D) + hk * H_D + dc;
      *(uint4*)&Ks[kr * LK + dc] = *(const uint4*)&k[gro];
      *(uint4*)&Ks[kr * LK + dc + 8] = *(const uint4*)&k[gro + 8];
      union { unsigned short u[8]; uint4 v; } w0, w1;
      w0.v = *(const uint4*)&v[gro];
      w1.v = *(const uint4*)&v[gro + 8];
#pragma unroll
      for (int j = 0; j < 8; j++) Vt[(dc + j) * LK + kr] = w0.u[j];
#pragma unroll
      for (int j = 0; j < 8; j++) Vt[(dc + 8 + j) * LK + kr] = w1.u[j];
    }
    __syncthreads();

    f32x4 sacc[4];
#pragma unroll
    for (int n = 0; n < 4; n++) {
      f32x4 z = {};
#pragma unroll
      for (int c = 0; c < 2; c++) {
        const bf16x8 bk = *(const bf16x8*)&Ks[(n * 16 + l16) * LK + c * 32 + quad * 8];
        z = __builtin_amdgcn_mfma_f32_16x16x32_bf16(af[c], bk, z, 0, 0, 0);
      }
      sacc[n] = z;
    }

    float p[4][4], mnew[4];
#pragma unroll
    for (int e = 0; e < 4; e++) mnew[e] = m_i[e];
#pragma unroll
    for (int n = 0; n < 4; n++)
#pragma unroll
      for (int e = 0; e < 4; e++) {
        float s = sacc[n][e] * 0.125f;
        if (kt == qt && (n * 16 + l16) > (wave * 16 + quad * 4 + e))
          s = -INFINITY;
        p[n][e] = s;
        mnew[e] = fmaxf(mnew[e], s);
      }
#pragma unroll
    for (int e = 0; e < 4; e++) {
      mnew[e] = fmaxf(mnew[e], __shfl_xor(mnew[e], 1));
      mnew[e] = fmaxf(mnew[e], __shfl_xor(mnew[e], 2));
      mnew[e] = fmaxf(mnew[e], __shfl_xor(mnew[e], 4));
      mnew[e] = fmaxf(mnew[e], __shfl_xor(mnew[e], 8));
      const float alpha = __expf(m_i[e] - mnew[e]);
      m_i[e] = mnew[e];
      l_i[e] *= alpha;
#pragma unroll
      for (int n = 0; n < 4; n++) o_acc[n][e] *= alpha;
    }
#pragma unroll
    for (int n = 0; n < 4; n++)
#pragma unroll
      for (int e = 0; e < 4; e++) {
        const float pe = __expf(p[n][e] - m_i[e]);
        p[n][e] = pe;
        l_i[e] += pe;
      }

#pragma unroll
    for (int n = 0; n < 4; n++)
#pragma unroll
      for (int e = 0; e < 4; e++)
        Ps[(wave * 16 + quad * 4 + e) * LK + n * 16 + l16] = f2bf(p[n][e]);
    __syncthreads();

    bf16x8 pf[2];
#pragma unroll
    for (int c = 0; c < 2; c++)
      pf[c] = *(const bf16x8*)&Ps[(wave * 16 + l16) * LK + c * 32 + quad * 8];
#pragma unroll
    for (int n = 0; n < 4; n++)
#pragma unroll
      for (int c = 0; c < 2; c++) {
        const bf16x8 bv = *(const bf16x8*)&Vt[(n * 16 + l16) * LK + c * 32 + quad * 8];
        o_acc[n] = __builtin_amdgcn_mfma_f32_16x16x32_bf16(pf[c], bv, o_acc[n], 0, 0, 0);
      }
  }

#pragma unroll
  for (int e = 0; e < 4; e++) {
    l_i[e] += __shfl_xor(l_i[e], 1);
    l_i[e] += __shfl_xor(l_i[e], 2);
    l_i[e] += __shfl_xor(l_i[e], 4);
    l_i[e] += __shfl_xor(l_i[e], 8);
    const float inv = 1.f / l_i[e];
    const size_t row = (size_t)(b * S_LEN + qt * 64 + wave * 16 + quad * 4 + e);
#pragma unroll
    for (int n = 0; n < 4; n++)
      ao[row * DMODEL + h * H_D + n * 16 + l16] = f2bf(o_acc[n][e] * inv);
  }
}

// ---------------------------------------------------------------------------
extern "C" void kernel_launch(void* const* d_in, const int* in_sizes, int n_in,
                              void* d_out, int out_size, void* d_ws, size_t ws_size,
                              hipStream_t stream) {
  const float* x = (const float*)d_in[0];
  const float* fc = (const float*)d_in[1];
  const float* fs = (const float*)d_in[2];
  const float* wq = (const float*)d_in[3];
  const float* wk = (const float*)d_in[4];
  const float* wv = (const float*)d_in[5];
  const float* wo = (const float*)d_in[6];

  char* ws = (char*)d_ws;
  const dim3 b256(256);

  if (ws_size >= (64ull << 20)) {
    // Fast path (64 MB):
    //   qkv   bf16 [4096][3072] @ 0     (24 MB)  q|k|v fused; attn out in q cols
    //   xb    bf16 [4096][2048] @ 24 MB (16 MB)
    //   wqkvT bf16 [3072][2048] @ 40 MB (12 MB)
    //   woT   bf16 [2048][2048] @ 52 MB ( 8 MB)
    //   vT    bf16 [ 512][4096] @ 60 MB ( 4 MB)
    unsigned short* qkv = (unsigned short*)(ws);
    unsigned short* xb = (unsigned short*)(ws + (24ull << 20));
    unsigned short* wqkvT = (unsigned short*)(ws + (40ull << 20));
    unsigned short* woT = (unsigned short*)(ws + (52ull << 20));
    unsigned short* vT = (unsigned short*)(ws + (60ull << 20));

    prep_all_k<<<dim3(64, 64, 5), b256, 0, stream>>>(x, wq, wk, wv, wo, xb,
                                                     wqkvT, woT);

    // Fused QKV projection, 8-phase 256x192: grid (16,16) = 256 blocks = 1/CU
    gemm8w_bt_k<1><<<dim3(16, 16), dim3(512), 0, stream>>>(xb, wqkvT, qkv, 4096,
                                                           3072, 2048, 2048);

    // RoPE (q pre-scaled by log2e/8, k plain) + v -> vT transpose, fused
    rope_vt_k<<<dim3(20480 + 2048), b256, 0, stream>>>(qkv, vT, fc, fs);

    // Paired 8-wave attention (v8): 512 blocks x 512 thr, 2 blocks/CU.
    attn_mfma8_k<<<dim3(8, N_H, 2), dim3(512), 0, stream>>>(qkv, vT, qkv);

    // Output projection, 8-phase 256x128 (256 blocks = 1/CU): fp32 d_out
    gemm8n_bt_k<0><<<dim3(16, 16), dim3(512), 0, stream>>>(qkv, woT, d_out,
                                                           4096, 2048, 2048,
                                                           QKV_LD);
  } else {
    // Round-4 fallback (<= 40 MB)
    unsigned short* q = (unsigned short*)(ws);
    unsigned short* k = (unsigned short*)(ws + (16ull << 20));
    unsigned short* v = (unsigned short*)(ws + (20ull << 20));
    unsigned short* xb = (unsigned short*)(ws + (24ull << 20));
    const bool have_xb = ws_size >= (40ull << 20);

    if (have_xb) {
      cvt_bf16_k<<<dim3(ROWS * DMODEL / (256 * 8)), b256, 0, stream>>>(x, xb);
      gemm_k<0, 1><<<dim3(32, 16), b256, 0, stream>>>(xb, wq, q, 4096, 2048, 2048);
      gemm_k<0, 1><<<dim3(32, 4), b256, 0, stream>>>(xb, wk, k, 4096, 512, 2048);
      gemm_k<0, 1><<<dim3(32, 4), b256, 0, stream>>>(xb, wv, v, 4096, 512, 2048);
    } else {
      gemm_k<1, 1><<<dim3(32, 16), b256, 0, stream>>>(x, wq, q, 4096, 2048, 2048);
      gemm_k<1, 1><<<dim3(32, 4), b256, 0, stream>>>(x, wk, k, 4096, 512, 2048);
      gemm_k<1, 1><<<dim3(32, 4), b256, 0, stream>>>(x, wv, v, 4096, 512, 2048);
    }

    rope_k<<<dim3(20480), b256, 0, stream>>>(q, k, fc, fs, N_H * H_D, N_KV * H_D);
    attn_mfma_k<<<dim3(S_LEN / 64, N_H, 2), b256, 0, stream>>>(q, k, v, q);
    gemm_k<0, 0><<<dim3(32, 16), b256, 0, stream>>>(q, wo, d_out, 4096, 2048, 2048);
  }
}

// Round 10
// 275.923 us; speedup vs baseline: 1.2263x; 1.0223x over previous
//
#include <hip/hip_runtime.h>
#include <hip/hip_bf16.h>

// Problem constants (B=2, S=2048, D=2048, NH=32, NKV=8, HD=64, NREP=4)
#define S_LEN 2048
#define DMODEL 2048
#define N_H 32
#define N_KV 8
#define H_D 64
#define ROWS 4096   // B*S
#define QKV_LD 3072 // fused qkv row stride: q[0:2048) k[2048:2560) v[2560:3072)

typedef __bf16 bf16x8 __attribute__((ext_vector_type(8)));
typedef float f32x4 __attribute__((ext_vector_type(4)));

// fp32 -> bf16 raw bits, round-to-nearest-even
static __device__ __forceinline__ unsigned short f2bf(float f) {
  unsigned int u = __float_as_uint(f);
  u += 0x7FFFu + ((u >> 16) & 1u);
  return (unsigned short)(u >> 16);
}
static __device__ __forceinline__ float bf2f(unsigned short s) {
  return __uint_as_float((unsigned int)s << 16);
}

// async global->LDS, 16 B per lane. LDS dest = wave-uniform base + lane*16.
static __device__ __forceinline__ void async16(const void* g, void* l) {
  __builtin_amdgcn_global_load_lds(
      (const __attribute__((address_space(1))) unsigned int*)g,
      (__attribute__((address_space(3))) unsigned int*)l, 16, 0, 0);
}

// counted vmcnt + raw barrier (T4): loads stay in flight across the barrier.
#define VMB(N)                                                    \
  do {                                                            \
    asm volatile("s_waitcnt vmcnt(" #N ")" ::: "memory");         \
    __builtin_amdgcn_s_barrier();                                 \
    asm volatile("" ::: "memory");                                \
  } while (0)

// ---------------------------------------------------------------------------
// fp32 -> bf16 bulk convert (8 elems/thread) — fallback path only
// ---------------------------------------------------------------------------
__global__ __launch_bounds__(256) void cvt_bf16_k(
    const float* __restrict__ in, unsigned short* __restrict__ out) {
  const size_t i = ((size_t)blockIdx.x * 256 + threadIdx.x) * 8;
  const float4 a = *(const float4*)&in[i];
  const float4 b = *(const float4*)&in[i + 4];
  union { unsigned short u[8]; uint4 v; } p;
  p.u[0] = f2bf(a.x); p.u[1] = f2bf(a.y); p.u[2] = f2bf(a.z); p.u[3] = f2bf(a.w);
  p.u[4] = f2bf(b.x); p.u[5] = f2bf(b.y); p.u[6] = f2bf(b.z); p.u[7] = f2bf(b.w);
  *(uint4*)&out[i] = p.v;
}

// ---------------------------------------------------------------------------
// Combined prep: z=0..3 transpose fp32 weights -> bf16 wqkvT/woT blocks;
// z=4: straight cvt x fp32 -> xb bf16 (64x64 blocks x 256 thr x 8 elems).
// ---------------------------------------------------------------------------
__global__ __launch_bounds__(256) void prep_all_k(
    const float* __restrict__ x, const float* __restrict__ wq,
    const float* __restrict__ wk, const float* __restrict__ wv,
    const float* __restrict__ wo, unsigned short* __restrict__ xb,
    unsigned short* __restrict__ wqkvT, unsigned short* __restrict__ woT) {
  const int z = blockIdx.z;
  if (z == 4) {
    const size_t i =
        (((size_t)blockIdx.y * 64 + blockIdx.x) * 256 + threadIdx.x) * 8;
    const float4 a = *(const float4*)&x[i];
    const float4 b = *(const float4*)&x[i + 4];
    union { unsigned short u[8]; uint4 v; } p;
    p.u[0] = f2bf(a.x); p.u[1] = f2bf(a.y); p.u[2] = f2bf(a.z); p.u[3] = f2bf(a.w);
    p.u[4] = f2bf(b.x); p.u[5] = f2bf(b.y); p.u[6] = f2bf(b.z); p.u[7] = f2bf(b.w);
    *(uint4*)&xb[i] = p.v;
    return;
  }
  const float* in;
  unsigned short* out;
  int C;
  if (z == 0)      { in = wq; out = wqkvT;                  C = 2048; }
  else if (z == 1) { in = wk; out = wqkvT + 2048ull * 2048; C = 512;  }
  else if (z == 2) { in = wv; out = wqkvT + 2560ull * 2048; C = 512;  }
  else             { in = wo; out = woT;                    C = 2048; }
  if (blockIdx.x * 32 >= C) return;

  __shared__ unsigned short tile[32][33];
  const int tx = threadIdx.x & 31;
  const int ty = threadIdx.x >> 5;
  const int r0 = blockIdx.y * 32;  // K rows of input
  const int c0 = blockIdx.x * 32;  // C cols of input
#pragma unroll
  for (int i = 0; i < 32; i += 8)
    tile[ty + i][tx] = f2bf(in[(size_t)(r0 + ty + i) * C + c0 + tx]);
  __syncthreads();
#pragma unroll
  for (int i = 0; i < 32; i += 8)
    out[(size_t)(c0 + ty + i) * 2048 + r0 + tx] = tile[tx][ty + i];
}

// log2(e) / sqrt(HD): softmax base-2 conversion + 1/sqrt(d), folded into q
#define SCALE_LOG2E 0.18033688011112042f

// ---------------------------------------------------------------------------
// Fused RoPE (blocks 0..20479) + v->vT transpose (blocks 20480..22527).
// ---------------------------------------------------------------------------
__global__ __launch_bounds__(256) void rope_vt_k(
    unsigned short* __restrict__ qkv, unsigned short* __restrict__ vT,
    const float* __restrict__ fc, const float* __restrict__ fs) {
  const int blk = blockIdx.x;
  if (blk < 20480) {
    const int PQ = ROWS * N_H * (H_D / 2);   // 4194304
    const int PK = ROWS * N_KV * (H_D / 2);  // 1048576
    const int idx = blk * 256 + threadIdx.x;
    if (idx >= PQ + PK) return;
    unsigned short* base;
    float c, sn;
    bool isq;
    if (idx < PQ) {
      const int i = idx & 31;
      const int h = (idx >> 5) & 31;
      const int row = idx >> 10;
      const int s = row & (S_LEN - 1);
      c = fc[s * 32 + i];
      sn = fs[s * 32 + i];
      base = qkv + (size_t)row * QKV_LD + h * H_D + 2 * i;
      isq = true;
    } else {
      const int p = idx - PQ;
      const int i = p & 31;
      const int h = (p >> 5) & 7;
      const int row = p >> 8;
      const int s = row & (S_LEN - 1);
      c = fc[s * 32 + i];
      sn = fs[s * 32 + i];
      base = qkv + (size_t)row * QKV_LD + 2048 + h * H_D + 2 * i;
      isq = false;
    }
    const float x0 = bf2f(base[0]);
    const float x1 = bf2f(base[1]);
    const float sc = isq ? SCALE_LOG2E : 1.0f;
    base[0] = f2bf((x0 * c - x1 * sn) * sc);
    base[1] = f2bf((x0 * sn + x1 * c) * sc);
  } else {
    __shared__ unsigned short tile[32][33];
    const int t = blk - 20480;        // 0..2047
    const int bx = t & 15;            // C/32 = 16
    const int by = t >> 4;            // R/32 = 128
    const unsigned short* in = qkv + 2560;
    const int tx = threadIdx.x & 31;
    const int ty = threadIdx.x >> 5;
    const int r0 = by * 32;
    const int c0 = bx * 32;
#pragma unroll
    for (int i = 0; i < 32; i += 8)
      tile[ty + i][tx] = in[(size_t)(r0 + ty + i) * QKV_LD + c0 + tx];
    __syncthreads();
#pragma unroll
    for (int i = 0; i < 32; i += 8)
      vT[(size_t)(c0 + ty + i) * ROWS + r0 + tx] = tile[tx][ty + i];
  }
}

// ---------------------------------------------------------------------------
// gemm8w: 8-phase deep-pipelined BM=256 x BN=192 MFMA GEMM (T2+T3+T4+T5).
// Verified round 9 (QKV path, -14.8 us). Ledger in round-9 comments.
// ---------------------------------------------------------------------------
template <int STORE_BF16>
__global__ __launch_bounds__(512, 2) void gemm8w_bt_k(
    const unsigned short* __restrict__ A, const unsigned short* __restrict__ BT,
    void* __restrict__ Cp, int M, int N, int K, int lda) {
  __shared__ __align__(16) unsigned short As[2][2][128 * 64];
  __shared__ __align__(16) unsigned short Bs[2][192 * 64];
  const int tid = threadIdx.x;
  const int wave = tid >> 6;
  const int lane = tid & 63;
  const int quad = lane >> 4;
  const int l16 = lane & 15;
  const int nwg = gridDim.x * gridDim.y;
  const int flat = blockIdx.y * gridDim.x + blockIdx.x;
  const int swz = (flat & 7) * (nwg >> 3) + (flat >> 3);
  const int m0 = (swz % gridDim.x) * 256;
  const int n0 = (swz / gridDim.x) * 192;
  const int ah = wave & 1;         // A half this wave computes on
  const int ag = wave >> 1;        // stage slot within A-group
  const int wn = (wave >> 1) * 48; // per-wave 48-col N strip
  const int rx = (l16 & 7) << 3;
  const int scol = ((lane & 7) * 8) ^ ((lane >> 3) << 3);
  const int srA = 8 * ag + (lane >> 3);
  const int srB = 8 * wave + (lane >> 3);
  const size_t abase = (size_t)(m0 + ah * 128) * lda;
  const size_t bbase = (size_t)n0 * K;
  f32x4 acc[8][3] = {};

#define STG_B(j, buf, kt)                                             \
  async16(&BT[bbase + (size_t)(64 * (j) + srB) * K + (kt) + scol],    \
          &Bs[buf][(64 * (j) + 8 * wave) * 64])
#define STG_A(j, buf, kt)                                             \
  async16(&A[abase + (size_t)(32 * (j) + srA) * lda + (kt) + scol],   \
          &As[buf][ah][(32 * (j) + 8 * ag) * 64])

  // prologue: stage tile 0 into buf 0 in ledger order
  STG_B(0, 0, 0); STG_B(1, 0, 0); STG_B(2, 0, 0);
  STG_A(0, 0, 0); STG_A(1, 0, 0); STG_A(2, 0, 0); STG_A(3, 0, 0);

  const int NT = K >> 6;
  for (int t = 0; t < NT; ++t) {
    const int cur = t & 1, nxt = cur ^ 1;
    const int ktn = (t + 1 < NT) ? ((t + 1) << 6) : 0;
    const unsigned short* Ac = &As[cur][ah][0];
    const unsigned short* Bc = &Bs[cur][0];
    bf16x8 bf[3][2];

    // ---- phase 0: B frags + A frags 0,1 ----
    VMB(3);
    {
      bf16x8 af[2][2];
#pragma unroll
      for (int n = 0; n < 3; n++)
#pragma unroll
        for (int kk = 0; kk < 2; kk++)
          bf[n][kk] = *(const bf16x8*)&Bc[(wn + n * 16 + l16) * 64 +
                                          ((kk * 32 + quad * 8) ^ rx)];
#pragma unroll
      for (int i = 0; i < 2; i++)
#pragma unroll
        for (int kk = 0; kk < 2; kk++)
          af[i][kk] = *(const bf16x8*)&Ac[((0 + i) * 16 + l16) * 64 +
                                          ((kk * 32 + quad * 8) ^ rx)];
      STG_B(0, nxt, ktn); STG_B(1, nxt, ktn);
      __builtin_amdgcn_s_setprio(1);
#pragma unroll
      for (int i = 0; i < 2; i++)
#pragma unroll
        for (int n = 0; n < 3; n++)
#pragma unroll
          for (int kk = 0; kk < 2; kk++)
            acc[0 + i][n] = __builtin_amdgcn_mfma_f32_16x16x32_bf16(
                af[i][kk], bf[n][kk], acc[0 + i][n], 0, 0, 0);
      __builtin_amdgcn_s_setprio(0);
    }

    // ---- phase 1: A frags 2,3 ----
    VMB(4);
    {
      bf16x8 af[2][2];
#pragma unroll
      for (int i = 0; i < 2; i++)
#pragma unroll
        for (int kk = 0; kk < 2; kk++)
          af[i][kk] = *(const bf16x8*)&Ac[((2 + i) * 16 + l16) * 64 +
                                          ((kk * 32 + quad * 8) ^ rx)];
      STG_B(2, nxt, ktn); STG_A(0, nxt, ktn);
      __builtin_amdgcn_s_setprio(1);
#pragma unroll
      for (int i = 0; i < 2; i++)
#pragma unroll
        for (int n = 0; n < 3; n++)
#pragma unroll
          for (int kk = 0; kk < 2; kk++)
            acc[2 + i][n] = __builtin_amdgcn_mfma_f32_16x16x32_bf16(
                af[i][kk], bf[n][kk], acc[2 + i][n], 0, 0, 0);
      __builtin_amdgcn_s_setprio(0);
    }

    // ---- phase 2: A frags 4,5 ----
    VMB(5);
    {
      bf16x8 af[2][2];
#pragma unroll
      for (int i = 0; i < 2; i++)
#pragma unroll
        for (int kk = 0; kk < 2; kk++)
          af[i][kk] = *(const bf16x8*)&Ac[((4 + i) * 16 + l16) * 64 +
                                          ((kk * 32 + quad * 8) ^ rx)];
      STG_A(1, nxt, ktn); STG_A(2, nxt, ktn);
      __builtin_amdgcn_s_setprio(1);
#pragma unroll
      for (int i = 0; i < 2; i++)
#pragma unroll
        for (int n = 0; n < 3; n++)
#pragma unroll
          for (int kk = 0; kk < 2; kk++)
            acc[4 + i][n] = __builtin_amdgcn_mfma_f32_16x16x32_bf16(
                af[i][kk], bf[n][kk], acc[4 + i][n], 0, 0, 0);
      __builtin_amdgcn_s_setprio(0);
    }

    // ---- phase 3: A frags 6,7 ----
    VMB(6);
    {
      bf16x8 af[2][2];
#pragma unroll
      for (int i = 0; i < 2; i++)
#pragma unroll
        for (int kk = 0; kk < 2; kk++)
          af[i][kk] = *(const bf16x8*)&Ac[((6 + i) * 16 + l16) * 64 +
                                          ((kk * 32 + quad * 8) ^ rx)];
      STG_A(3, nxt, ktn);
      __builtin_amdgcn_s_setprio(1);
#pragma unroll
      for (int i = 0; i < 2; i++)
#pragma unroll
        for (int n = 0; n < 3; n++)
#pragma unroll
          for (int kk = 0; kk < 2; kk++)
            acc[6 + i][n] = __builtin_amdgcn_mfma_f32_16x16x32_bf16(
                af[i][kk], bf[n][kk], acc[6 + i][n], 0, 0, 0);
      __builtin_amdgcn_s_setprio(0);
    }
  }
#undef STG_A
#undef STG_B

  // Epilogue: C/D layout col = lane&15, row = quad*4 + reg  [m89/m91]
#pragma unroll
  for (int f = 0; f < 8; f++) {
#pragma unroll
    for (int e = 0; e < 4; e++) {
      const int mrow = m0 + ah * 128 + f * 16 + quad * 4 + e;
#pragma unroll
      for (int n = 0; n < 3; n++) {
        const int ncol = n0 + wn + n * 16 + l16;
        const float val = acc[f][n][e];
        if (STORE_BF16) {
          ((unsigned short*)Cp)[(size_t)mrow * N + ncol] = f2bf(val);
        } else {
          ((float*)Cp)[(size_t)mrow * N + ncol] = val;
        }
      }
    }
  }
}

// ---------------------------------------------------------------------------
// gemm8n: 8-phase GEMM, BM=256 x BN=128 variant (verified round 8, WO path).
// ---------------------------------------------------------------------------
template <int STORE_BF16>
__global__ __launch_bounds__(512, 2) void gemm8n_bt_k(
    const unsigned short* __restrict__ A, const unsigned short* __restrict__ BT,
    void* __restrict__ Cp, int M, int N, int K, int lda) {
  __shared__ __align__(16) unsigned short As[2][2][128 * 64];
  __shared__ __align__(16) unsigned short Bs[2][128 * 64];
  const int tid = threadIdx.x;
  const int wave = tid >> 6;
  const int lane = tid & 63;
  const int quad = lane >> 4;
  const int l16 = lane & 15;
  const int nwg = gridDim.x * gridDim.y;
  const int flat = blockIdx.y * gridDim.x + blockIdx.x;
  const int swz = (flat & 7) * (nwg >> 3) + (flat >> 3);
  const int m0 = (swz % gridDim.x) * 256;
  const int n0 = (swz / gridDim.x) * 128;
  const int ah = wave & 1;
  const int ag = wave >> 1;
  const int wn = (wave >> 1) * 32;    // per-wave N strip (0,32,64,96)
  const int rx = (l16 & 7) << 3;
  const int scol = ((lane & 7) * 8) ^ ((lane >> 3) << 3);
  const int srA = 8 * ag + (lane >> 3);
  const int srB = 8 * wave + (lane >> 3);  // B row within 64-row group
  const size_t abase = (size_t)(m0 + ah * 128) * lda;
  const size_t bbase = (size_t)n0 * K;
  f32x4 acc[8][2] = {};

#define STG_B(j, buf, kt)                                             \
  async16(&BT[bbase + (size_t)(64 * (j) + srB) * K + (kt) + scol],    \
          &Bs[buf][(64 * (j) + 8 * wave) * 64])
#define STG_A(j, buf, kt)                                             \
  async16(&A[abase + (size_t)(32 * (j) + srA) * lda + (kt) + scol],   \
          &As[buf][ah][(32 * (j) + 8 * ag) * 64])

  STG_B(0, 0, 0); STG_B(1, 0, 0);
  STG_A(0, 0, 0); STG_A(1, 0, 0); STG_A(2, 0, 0); STG_A(3, 0, 0);

  const int NT = K >> 6;
  for (int t = 0; t < NT; ++t) {
    const int cur = t & 1, nxt = cur ^ 1;
    const int ktn = (t + 1 < NT) ? ((t + 1) << 6) : 0;
    const unsigned short* Ac = &As[cur][ah][0];
    const unsigned short* Bc = &Bs[cur][0];
    bf16x8 bf[2][2];

    VMB(3);
    {
      bf16x8 af[2][2];
#pragma unroll
      for (int n = 0; n < 2; n++)
#pragma unroll
        for (int kk = 0; kk < 2; kk++)
          bf[n][kk] = *(const bf16x8*)&Bc[(wn + n * 16 + l16) * 64 +
                                          ((kk * 32 + quad * 8) ^ rx)];
#pragma unroll
      for (int i = 0; i < 2; i++)
#pragma unroll
        for (int kk = 0; kk < 2; kk++)
          af[i][kk] = *(const bf16x8*)&Ac[((0 + i) * 16 + l16) * 64 +
                                          ((kk * 32 + quad * 8) ^ rx)];
      STG_B(0, nxt, ktn); STG_B(1, nxt, ktn);
      __builtin_amdgcn_s_setprio(1);
#pragma unroll
      for (int i = 0; i < 2; i++)
#pragma unroll
        for (int n = 0; n < 2; n++)
#pragma unroll
          for (int kk = 0; kk < 2; kk++)
            acc[0 + i][n] = __builtin_amdgcn_mfma_f32_16x16x32_bf16(
                af[i][kk], bf[n][kk], acc[0 + i][n], 0, 0, 0);
      __builtin_amdgcn_s_setprio(0);
    }

    VMB(4);
    {
      bf16x8 af[2][2];
#pragma unroll
      for (int i = 0; i < 2; i++)
#pragma unroll
        for (int kk = 0; kk < 2; kk++)
          af[i][kk] = *(const bf16x8*)&Ac[((2 + i) * 16 + l16) * 64 +
                                          ((kk * 32 + quad * 8) ^ rx)];
      STG_A(0, nxt, ktn); STG_A(1, nxt, ktn);
      __builtin_amdgcn_s_setprio(1);
#pragma unroll
      for (int i = 0; i < 2; i++)
#pragma unroll
        for (int n = 0; n < 2; n++)
#pragma unroll
          for (int kk = 0; kk < 2; kk++)
            acc[2 + i][n] = __builtin_amdgcn_mfma_f32_16x16x32_bf16(
                af[i][kk], bf[n][kk], acc[2 + i][n], 0, 0, 0);
      __builtin_amdgcn_s_setprio(0);
    }

    VMB(5);
    {
      bf16x8 af[2][2];
#pragma unroll
      for (int i = 0; i < 2; i++)
#pragma unroll
        for (int kk = 0; kk < 2; kk++)
          af[i][kk] = *(const bf16x8*)&Ac[((4 + i) * 16 + l16) * 64 +
                                          ((kk * 32 + quad * 8) ^ rx)];
      STG_A(2, nxt, ktn); STG_A(3, nxt, ktn);
      __builtin_amdgcn_s_setprio(1);
#pragma unroll
      for (int i = 0; i < 2; i++)
#pragma unroll
        for (int n = 0; n < 2; n++)
#pragma unroll
          for (int kk = 0; kk < 2; kk++)
            acc[4 + i][n] = __builtin_amdgcn_mfma_f32_16x16x32_bf16(
                af[i][kk], bf[n][kk], acc[4 + i][n], 0, 0, 0);
      __builtin_amdgcn_s_setprio(0);
    }

    VMB(6);
    {
      bf16x8 af[2][2];
#pragma unroll
      for (int i = 0; i < 2; i++)
#pragma unroll
        for (int kk = 0; kk < 2; kk++)
          af[i][kk] = *(const bf16x8*)&Ac[((6 + i) * 16 + l16) * 64 +
                                          ((kk * 32 + quad * 8) ^ rx)];
      __builtin_amdgcn_s_setprio(1);
#pragma unroll
      for (int i = 0; i < 2; i++)
#pragma unroll
        for (int n = 0; n < 2; n++)
#pragma unroll
          for (int kk = 0; kk < 2; kk++)
            acc[6 + i][n] = __builtin_amdgcn_mfma_f32_16x16x32_bf16(
                af[i][kk], bf[n][kk], acc[6 + i][n], 0, 0, 0);
      __builtin_amdgcn_s_setprio(0);
    }
  }
#undef STG_A
#undef STG_B

#pragma unroll
  for (int f = 0; f < 8; f++) {
#pragma unroll
    for (int e = 0; e < 4; e++) {
      const int mrow = m0 + ah * 128 + f * 16 + quad * 4 + e;
#pragma unroll
      for (int n = 0; n < 2; n++) {
        const int ncol = n0 + wn + n * 16 + l16;
        const float val = acc[f][n][e];
        if (STORE_BF16) {
          ((unsigned short*)Cp)[(size_t)mrow * N + ncol] = f2bf(val);
        } else {
          ((float*)Cp)[(size_t)mrow * N + ncol] = val;
        }
      }
    }
  }
}

// ---------------------------------------------------------------------------
// Fallback MFMA GEMM (round-4): C[M][N] = A[M][K] @ B[K][N], B fp32 native.
// ---------------------------------------------------------------------------
template <int AF32, int STORE_BF16>
__global__ __launch_bounds__(256) void gemm_k(
    const void* __restrict__ Ap, const float* __restrict__ B,
    void* __restrict__ Cp, int M, int N, int K) {
  constexpr int LDP = 40;
  __shared__ __align__(16) unsigned short As[128 * LDP];
  __shared__ __align__(16) unsigned short Bs[128 * LDP];
  const int tid = threadIdx.x;
  const int wave = tid >> 6;
  const int lane = tid & 63;
  const int quad = lane >> 4;
  const int l16 = lane & 15;
  const int m0 = blockIdx.x * 128;
  const int n0 = blockIdx.y * 128;
  const int wm = (wave >> 1) * 64;
  const int wn = (wave & 1) * 64;
  f32x4 acc[4][4] = {};

  for (int kt = 0; kt < K; kt += 32) {
    __syncthreads();
    if (AF32) {
      const float* A = (const float*)Ap;
      for (int c = tid; c < 1024; c += 256) {
        const int r = c >> 3;
        const int cc = (c & 7) << 2;
        const float4 w = *(const float4*)&A[(size_t)(m0 + r) * K + kt + cc];
        union { unsigned short u[4]; uint2 v; } p;
        p.u[0] = f2bf(w.x); p.u[1] = f2bf(w.y);
        p.u[2] = f2bf(w.z); p.u[3] = f2bf(w.w);
        *(uint2*)&As[r * LDP + cc] = p.v;
      }
    } else {
      const unsigned short* A = (const unsigned short*)Ap;
      for (int c = tid; c < 512; c += 256) {
        const int r = c >> 2;
        const int cc = (c & 3) << 3;
        *(uint4*)&As[r * LDP + cc] =
            *(const uint4*)&A[(size_t)(m0 + r) * K + kt + cc];
      }
    }
    for (int c = tid; c < 1024; c += 256) {
      const int kr = c >> 5;
      const int nc = (c & 31) << 2;
      const float4 w = *(const float4*)&B[(size_t)(kt + kr) * N + n0 + nc];
      Bs[(nc + 0) * LDP + kr] = f2bf(w.x);
      Bs[(nc + 1) * LDP + kr] = f2bf(w.y);
      Bs[(nc + 2) * LDP + kr] = f2bf(w.z);
      Bs[(nc + 3) * LDP + kr] = f2bf(w.w);
    }
    __syncthreads();
    bf16x8 af[4], bfr[4];
#pragma unroll
    for (int i = 0; i < 4; i++)
      af[i] = *(const bf16x8*)&As[(wm + i * 16 + l16) * LDP + quad * 8];
#pragma unroll
    for (int j = 0; j < 4; j++)
      bfr[j] = *(const bf16x8*)&Bs[(wn + j * 16 + l16) * LDP + quad * 8];
#pragma unroll
    for (int i = 0; i < 4; i++)
#pragma unroll
      for (int j = 0; j < 4; j++)
        acc[i][j] =
            __builtin_amdgcn_mfma_f32_16x16x32_bf16(af[i], bfr[j], acc[i][j], 0, 0, 0);
  }
#pragma unroll
  for (int i = 0; i < 4; i++) {
#pragma unroll
    for (int e = 0; e < 4; e++) {
      const int mrow = m0 + wm + i * 16 + quad * 4 + e;
#pragma unroll
      for (int j = 0; j < 4; j++) {
        const int ncol = n0 + wn + j * 16 + l16;
        const float val = acc[i][j][e];
        if (STORE_BF16) {
          ((unsigned short*)Cp)[(size_t)mrow * N + ncol] = f2bf(val);
        } else {
          ((float*)Cp)[(size_t)mrow * N + ncol] = val;
        }
      }
    }
  }
}

// ---------------------------------------------------------------------------
// Fallback RoPE (separate q/k buffers)
// ---------------------------------------------------------------------------
__global__ __launch_bounds__(256) void rope_k(
    unsigned short* __restrict__ q, unsigned short* __restrict__ kk,
    const float* __restrict__ fc, const float* __restrict__ fs,
    int qstride, int kstride) {
  const int PQ = ROWS * N_H * (H_D / 2);
  const int PK = ROWS * N_KV * (H_D / 2);
  const int idx = blockIdx.x * 256 + threadIdx.x;
  if (idx >= PQ + PK) return;
  unsigned short* base;
  float c, sn;
  if (idx < PQ) {
    const int i = idx & 31;
    const int h = (idx >> 5) & 31;
    const int row = idx >> 10;
    const int s = row & (S_LEN - 1);
    c = fc[s * 32 + i];
    sn = fs[s * 32 + i];
    base = q + (size_t)row * qstride + h * H_D + 2 * i;
  } else {
    const int p = idx - PQ;
    const int i = p & 31;
    const int h = (p >> 5) & 7;
    const int row = p >> 8;
    const int s = row & (S_LEN - 1);
    c = fc[s * 32 + i];
    sn = fs[s * 32 + i];
    base = kk + (size_t)row * kstride + h * H_D + 2 * i;
  }
  const float x0 = bf2f(base[0]);
  const float x1 = bf2f(base[1]);
  base[0] = f2bf(x0 * c - x1 * sn);
  base[1] = f2bf(x0 * sn + x1 * c);
}

// ---------------------------------------------------------------------------
// attn v13 = v8 (verified best structure) with two VALU cuts:
//  - P pack via v_perm_b32 (1 inst/u32 vs 3 for shift/and/or; identical
//    truncation semantics — this exact perm code passed in round 3).
//  - causal-mask branch made wave-uniform: the clean path (32 of 36 tiles
//    per pair) emits zero cmp/cndmask ops.
// Everything else byte-identical to v8: 8-wave paired, 16 q-rows/wave,
// swapped-operand S^T, XOR-swizzled LDS, NON-ONLINE softmax, ones-MFMA l.
// ---------------------------------------------------------------------------
__global__ __launch_bounds__(512, 4) void attn_mfma13_k(
    const unsigned short* __restrict__ qkv, const unsigned short* __restrict__ vT,
    unsigned short* __restrict__ ao) {
  const int pair = blockIdx.x, h = blockIdx.y, b = blockIdx.z;
  const int hk = h >> 2;
  const int tid = threadIdx.x;
  const int wave = tid >> 6;      // 0..7
  const int l16 = tid & 15;
  const int quad = (tid & 63) >> 4;
  const int rr = tid >> 3;        // 0..63 staging row
  const int dc = (tid & 7) * 8;   // staging 8-elem (16B) chunk
  const int rx = (l16 & 7) << 3;  // read/P-side XOR (elem units)
  const int sx = (rr & 7) << 3;   // stage-side XOR

  __shared__ __align__(16) unsigned short Ks[2][64 * 64];  // [key][d] swz
  __shared__ __align__(16) unsigned short Vt[2][64 * 64];  // [d][key] swz
  __shared__ __align__(16) unsigned short Ps[8][16 * 64];  // wave-private swz

  bf16x8 ones;
#pragma unroll
  for (int j = 0; j < 8; j++) ones[j] = (__bf16)1.0f;

  const size_t kbase =
      (size_t)(b * S_LEN) * QKV_LD + 2048 + hk * H_D + dc;  // k cols
  const size_t vbase = (size_t)(hk * H_D + rr) * ROWS + b * S_LEN + dc;

  for (int sel = 0; sel < 2; ++sel) {
    const int qb = sel ? (15 - pair) : pair;  // q-block of 128 rows
    const int row0 = qb * 128;
    const int ktiles = 2 * qb + 2;

    // Q fragments: A/B-frag layout lane holds [l16][quad*8+j]; 16 rows/wave
    bf16x8 af[2];
    {
      const size_t qrow = (size_t)(b * S_LEN + row0 + wave * 16 + l16);
#pragma unroll
      for (int c = 0; c < 2; c++)
        af[c] =
            *(const bf16x8*)&qkv[qrow * QKV_LD + h * H_D + c * 32 + quad * 8];
    }

    f32x4 o_acc[4] = {};
    f32x4 l_acc = {};

    // Prefetch tile 0 into registers, then stage into LDS buffer 0.
    uint4 rk, rv;
    {
      rk = *(const uint4*)&qkv[kbase + (size_t)rr * QKV_LD];
      rv = *(const uint4*)&vT[vbase];
    }
    __syncthreads();  // prior-sel readers of LDS done before overwrite
    *(uint4*)&Ks[0][rr * 64 + (dc ^ sx)] = rk;
    *(uint4*)&Vt[0][rr * 64 + (dc ^ sx)] = rv;

    int cur = 0;
    for (int kt = 0; kt < ktiles; ++kt) {
      // Prefetch next tile while this tile computes.
      if (kt + 1 < ktiles) {
        rk = *(const uint4*)&qkv[kbase + (size_t)((kt + 1) * 64 + rr) * QKV_LD];
        rv = *(const uint4*)&vT[vbase + (size_t)(kt + 1) * 64];
      }
      __syncthreads();  // LDS[cur] fully staged by all waves

      // S^T strips: D[row=k(quad*4+e), col=q(l16)] = mfma(K-frag, Q-frag).
      f32x4 sacc[4];
#pragma unroll
      for (int n = 0; n < 4; n++) {
        f32x4 z = {};
#pragma unroll
        for (int c = 0; c < 2; c++) {
          const bf16x8 bk = *(const bf16x8*)&Ks[cur][(n * 16 + l16) * 64 +
                                                     ((c * 32 + quad * 8) ^ rx)];
          z = __builtin_amdgcn_mfma_f32_16x16x32_bf16(bk, af[c], z, 0, 0, 0);
        }
        sacc[n] = z;
      }

      // pe = exp2(s); truncate to bf16 (v_perm pack); masked -> 0.
      // Wave-uniform branch: only the last 2 tiles of a q-block can mask.
      const bool maybe_mask = (kt >= 2 * qb);
      {
        const int prow = l16 * 64;
        if (maybe_mask) {
          const int krel0 = (kt - 2 * qb) * 64;
          const int qn = wave * 16 + l16;  // relative q row of this lane
#pragma unroll
          for (int n = 0; n < 4; n++) {
            const int kb0 = krel0 + n * 16 + quad * 4;  // relative k of e=0
            float pe[4];
#pragma unroll
            for (int e = 0; e < 4; e++) {
              float v = exp2f(sacc[n][e]);
              if (kb0 + e > qn) v = 0.f;
              pe[e] = v;
            }
            uint2 u;
            u.x = __builtin_amdgcn_perm(__float_as_uint(pe[1]),
                                        __float_as_uint(pe[0]), 0x07060302u);
            u.y = __builtin_amdgcn_perm(__float_as_uint(pe[3]),
                                        __float_as_uint(pe[2]), 0x07060302u);
            *(uint2*)&Ps[wave][prow + ((n * 16 + quad * 4) ^ rx)] = u;
          }
        } else {
#pragma unroll
          for (int n = 0; n < 4; n++) {
            float pe[4];
#pragma unroll
            for (int e = 0; e < 4; e++) pe[e] = exp2f(sacc[n][e]);
            uint2 u;
            u.x = __builtin_amdgcn_perm(__float_as_uint(pe[1]),
                                        __float_as_uint(pe[0]), 0x07060302u);
            u.y = __builtin_amdgcn_perm(__float_as_uint(pe[3]),
                                        __float_as_uint(pe[2]), 0x07060302u);
            *(uint2*)&Ps[wave][prow + ((n * 16 + quad * 4) ^ rx)] = u;
          }
        }
      }
      // wave-private Ps: compiler inserts lgkmcnt wait; no barrier needed

      bf16x8 pf[2];
#pragma unroll
      for (int c = 0; c < 2; c++)
        pf[c] = *(const bf16x8*)&Ps[wave][l16 * 64 +
                                          ((c * 32 + quad * 8) ^ rx)];
      // l row-sums via MFMA against ones (replicated over cols).
#pragma unroll
      for (int c = 0; c < 2; c++)
        l_acc = __builtin_amdgcn_mfma_f32_16x16x32_bf16(pf[c], ones, l_acc,
                                                        0, 0, 0);
#pragma unroll
      for (int n = 0; n < 4; n++)
#pragma unroll
        for (int c = 0; c < 2; c++) {
          const bf16x8 bv = *(const bf16x8*)&Vt[cur][(n * 16 + l16) * 64 +
                                                     ((c * 32 + quad * 8) ^ rx)];
          o_acc[n] = __builtin_amdgcn_mfma_f32_16x16x32_bf16(pf[c], bv,
                                                             o_acc[n], 0, 0, 0);
        }

      // Stage prefetched tile into the other buffer (swizzled writes).
      if (kt + 1 < ktiles) {
        const int nxt = cur ^ 1;
        *(uint4*)&Ks[nxt][rr * 64 + (dc ^ sx)] = rk;
        *(uint4*)&Vt[nxt][rr * 64 + (dc ^ sx)] = rv;
      }
      cur ^= 1;
    }

    // Epilogue: l already reduced by MFMA; normalize, store bf16 (in-place q).
#pragma unroll
    for (int e = 0; e < 4; e++) {
      const float inv = 1.f / l_acc[e];
      const size_t row =
          (size_t)(b * S_LEN + row0 + wave * 16 + quad * 4 + e);
#pragma unroll
      for (int n = 0; n < 4; n++)
        ao[row * QKV_LD + h * H_D + n * 16 + l16] = f2bf(o_acc[n][e] * inv);
    }
  }
}

#define LK 72  // padded inner stride for fallback attention

// ---------------------------------------------------------------------------
// Round-4 attention (fallback path only): k/v separate buffers stride 512.
// ---------------------------------------------------------------------------
__global__ __launch_bounds__(256) void attn_mfma_k(
    const unsigned short* __restrict__ q, const unsigned short* __restrict__ k,
    const unsigned short* __restrict__ v, unsigned short* __restrict__ ao) {
  const int qt = blockIdx.x, h = blockIdx.y, b = blockIdx.z;
  const int hk = h >> 2;
  const int tid = threadIdx.x;
  const int wave = tid >> 6;
  const int l16 = tid & 15;
  const int quad = (tid & 63) >> 4;

  __shared__ __align__(16) unsigned short Ks[64 * LK];
  __shared__ __align__(16) unsigned short Vt[64 * LK];
  __shared__ __align__(16) unsigned short Ps[64 * LK];

  bf16x8 af[2];
  {
    const size_t qrow = (size_t)(b * S_LEN + qt * 64 + wave * 16 + l16);
#pragma unroll
    for (int c = 0; c < 2; c++)
      af[c] = *(const bf16x8*)&q[qrow * DMODEL + h * H_D + c * 32 + quad * 8];
  }

  f32x4 o_acc[4] = {};
  float m_i[4], l_i[4];
#pragma unroll
  for (int e = 0; e < 4; e++) { m_i[e] = -INFINITY; l_i[e] = 0.f; }

  for (int kt = 0; kt <= qt; ++kt) {
    const int kb = kt * 64;
    __syncthreads();
    {
      const int kr = tid >> 2;
      const int dc = (tid & 3) * 16;
      const size_t gro = (size_t)(b * S_LEN + kb + kr) * (N_KV * H_D) + hk * H_D + dc;
      *(uint4*)&Ks[kr * LK + dc] = *(const uint4*)&k[gro];
      *(uint4*)&Ks[kr * LK + dc + 8] = *(const uint4*)&k[gro + 8];
      union { unsigned short u[8]; uint4 v; } w0, w1;
      w0.v = *(const uint4*)&v[gro];
      w1.v = *(const uint4*)&v[gro + 8];
#pragma unroll
      for (int j = 0; j < 8; j++) Vt[(dc + j) * LK + kr] = w0.u[j];
#pragma unroll
      for (int j = 0; j < 8; j++) Vt[(dc + 8 + j) * LK + kr] = w1.u[j];
    }
    __syncthreads();

    f32x4 sacc[4];
#pragma unroll
    for (int n = 0; n < 4; n++) {
      f32x4 z = {};
#pragma unroll
      for (int c = 0; c < 2; c++) {
        const bf16x8 bk = *(const bf16x8*)&Ks[(n * 16 + l16) * LK + c * 32 + quad * 8];
        z = __builtin_amdgcn_mfma_f32_16x16x32_bf16(af[c], bk, z, 0, 0, 0);
      }
      sacc[n] = z;
    }

    float p[4][4], mnew[4];
#pragma unroll
    for (int e = 0; e < 4; e++) mnew[e] = m_i[e];
#pragma unroll
    for (int n = 0; n < 4; n++)
#pragma unroll
      for (int e = 0; e < 4; e++) {
        float s = sacc[n][e] * 0.125f;
        if (kt == qt && (n * 16 + l16) > (wave * 16 + quad * 4 + e))
          s = -INFINITY;
        p[n][e] = s;
        mnew[e] = fmaxf(mnew[e], s);
      }
#pragma unroll
    for (int e = 0; e < 4; e++) {
      mnew[e] = fmaxf(mnew[e], __shfl_xor(mnew[e], 1));
      mnew[e] = fmaxf(mnew[e], __shfl_xor(mnew[e], 2));
      mnew[e] = fmaxf(mnew[e], __shfl_xor(mnew[e], 4));
      mnew[e] = fmaxf(mnew[e], __shfl_xor(mnew[e], 8));
      const float alpha = __expf(m_i[e] - mnew[e]);
      m_i[e] = mnew[e];
      l_i[e] *= alpha;
#pragma unroll
      for (int n = 0; n < 4; n++) o_acc[n][e] *= alpha;
    }
#pragma unroll
    for (int n = 0; n < 4; n++)
#pragma unroll
      for (int e = 0; e < 4; e++) {
        const float pe = __expf(p[n][e] - m_i[e]);
        p[n][e] = pe;
        l_i[e] += pe;
      }

#pragma unroll
    for (int n = 0; n < 4; n++)
#pragma unroll
      for (int e = 0; e < 4; e++)
        Ps[(wave * 16 + quad * 4 + e) * LK + n * 16 + l16] = f2bf(p[n][e]);
    __syncthreads();

    bf16x8 pf[2];
#pragma unroll
    for (int c = 0; c < 2; c++)
      pf[c] = *(const bf16x8*)&Ps[(wave * 16 + l16) * LK + c * 32 + quad * 8];
#pragma unroll
    for (int n = 0; n < 4; n++)
#pragma unroll
      for (int c = 0; c < 2; c++) {
        const bf16x8 bv = *(const bf16x8*)&Vt[(n * 16 + l16) * LK + c * 32 + quad * 8];
        o_acc[n] = __builtin_amdgcn_mfma_f32_16x16x32_bf16(pf[c], bv, o_acc[n], 0, 0, 0);
      }
  }

#pragma unroll
  for (int e = 0; e < 4; e++) {
    l_i[e] += __shfl_xor(l_i[e], 1);
    l_i[e] += __shfl_xor(l_i[e], 2);
    l_i[e] += __shfl_xor(l_i[e], 4);
    l_i[e] += __shfl_xor(l_i[e], 8);
    const float inv = 1.f / l_i[e];
    const size_t row = (size_t)(b * S_LEN + qt * 64 + wave * 16 + quad * 4 + e);
#pragma unroll
    for (int n = 0; n < 4; n++)
      ao[row * DMODEL + h * H_D + n * 16 + l16] = f2bf(o_acc[n][e] * inv);
  }
}

// ---------------------------------------------------------------------------
extern "C" void kernel_launch(void* const* d_in, const int* in_sizes, int n_in,
                              void* d_out, int out_size, void* d_ws, size_t ws_size,
                              hipStream_t stream) {
  const float* x = (const float*)d_in[0];
  const float* fc = (const float*)d_in[1];
  const float* fs = (const float*)d_in[2];
  const float* wq = (const float*)d_in[3];
  const float* wk = (const float*)d_in[4];
  const float* wv = (const float*)d_in[5];
  const float* wo = (const float*)d_in[6];

  char* ws = (char*)d_ws;
  const dim3 b256(256);

  if (ws_size >= (64ull << 20)) {
    // Fast path (64 MB):
    //   qkv   bf16 [4096][3072] @ 0     (24 MB)  q|k|v fused; attn out in q cols
    //   xb    bf16 [4096][2048] @ 24 MB (16 MB)
    //   wqkvT bf16 [3072][2048] @ 40 MB (12 MB)
    //   woT   bf16 [2048][2048] @ 52 MB ( 8 MB)
    //   vT    bf16 [ 512][4096] @ 60 MB ( 4 MB)
    unsigned short* qkv = (unsigned short*)(ws);
    unsigned short* xb = (unsigned short*)(ws + (24ull << 20));
    unsigned short* wqkvT = (unsigned short*)(ws + (40ull << 20));
    unsigned short* woT = (unsigned short*)(ws + (52ull << 20));
    unsigned short* vT = (unsigned short*)(ws + (60ull << 20));

    prep_all_k<<<dim3(64, 64, 5), b256, 0, stream>>>(x, wq, wk, wv, wo, xb,
                                                     wqkvT, woT);

    // Fused QKV projection, 8-phase 256x192: grid (16,16) = 256 blocks = 1/CU
    gemm8w_bt_k<1><<<dim3(16, 16), dim3(512), 0, stream>>>(xb, wqkvT, qkv, 4096,
                                                           3072, 2048, 2048);

    // RoPE (q pre-scaled by log2e/8, k plain) + v -> vT transpose, fused
    rope_vt_k<<<dim3(20480 + 2048), b256, 0, stream>>>(qkv, vT, fc, fs);

    // Paired 8-wave attention (v13 = v8 + perm-pack + uniform mask branch).
    attn_mfma13_k<<<dim3(8, N_H, 2), dim3(512), 0, stream>>>(qkv, vT, qkv);

    // Output projection, 8-phase 256x128 (256 blocks = 1/CU): fp32 d_out
    gemm8n_bt_k<0><<<dim3(16, 16), dim3(512), 0, stream>>>(qkv, woT, d_out,
                                                           4096, 2048, 2048,
                                                           QKV_LD);
  } else {
    // Round-4 fallback (<= 40 MB)
    unsigned short* q = (unsigned short*)(ws);
    unsigned short* k = (unsigned short*)(ws + (16ull << 20));
    unsigned short* v = (unsigned short*)(ws + (20ull << 20));
    unsigned short* xb = (unsigned short*)(ws + (24ull << 20));
    const bool have_xb = ws_size >= (40ull << 20);

    if (have_xb) {
      cvt_bf16_k<<<dim3(ROWS * DMODEL / (256 * 8)), b256, 0, stream>>>(x, xb);
      gemm_k<0, 1><<<dim3(32, 16), b256, 0, stream>>>(xb, wq, q, 4096, 2048, 2048);
      gemm_k<0, 1><<<dim3(32, 4), b256, 0, stream>>>(xb, wk, k, 4096, 512, 2048);
      gemm_k<0, 1><<<dim3(32, 4), b256, 0, stream>>>(xb, wv, v, 4096, 512, 2048);
    } else {
      gemm_k<1, 1><<<dim3(32, 16), b256, 0, stream>>>(x, wq, q, 4096, 2048, 2048);
      gemm_k<1, 1><<<dim3(32, 4), b256, 0, stream>>>(x, wk, k, 4096, 512, 2048);
      gemm_k<1, 1><<<dim3(32, 4), b256, 0, stream>>>(x, wv, v, 4096, 512, 2048);
    }

    rope_k<<<dim3(20480), b256, 0, stream>>>(q, k, fc, fs, N_H * H_D, N_KV * H_D);
    attn_mfma_k<<<dim3(S_LEN / 64, N_H, 2), b256, 0, stream>>>(q, k, v, q);
    gemm_k<0, 0><<<dim3(32, 16), b256, 0, stream>>>(q, wo, d_out, 4096, 2048, 2048);
  }
}